// Round 10
// baseline (456.268 us; speedup 1.0000x reference)
//
#include <hip/hip_runtime.h>
#include <hip/hip_bf16.h>

// Workspace layout (4B units):
// [btot:256][bbase:256][bcur:256][csr_src:E][dst_of:E][A:N*32][B:N*32][h1:N*32][h2:N*32][gbuf:G*32]
// csr_tmp (E ints) ALIASES A (CSR build completes before pre1 writes A).
// h1/h2/gbuf hold non-negative float bit patterns (global atomicMax on uint).

#define NEG_BIG (-3.0e38f)
#define BSHIFT 9
#define BDSTS (1 << BSHIFT)      // 512 dsts per bucket
#define NBMAX 256
#define CHUNK 16384              // edges per block in count/scatter passes

typedef __attribute__((ext_vector_type(8))) short short8;
typedef __attribute__((ext_vector_type(4))) float f32x4;

__device__ __forceinline__ short bf16r(float f) {
    unsigned u = __float_as_uint(f);
    unsigned r = (u + 0x7FFFu + ((u >> 16) & 1u)) >> 16;
    return (short)r;
}

__global__ __launch_bounds__(256) void pre1_kernel(
    const float* __restrict__ pos, const float* __restrict__ w1a,
    const float* __restrict__ b1a, float* __restrict__ A, float* __restrict__ B,
    float* __restrict__ h1, int N)
{
    int t = blockIdx.x * 256 + threadIdx.x;
    if (t >= N * 32) return;
    int n = t >> 5, c = t & 31;
    float px = pos[2 * n], py = pos[2 * n + 1];
    float w0 = w1a[c], w1 = w1a[32 + c], w2 = w1a[64 + c], w3 = w1a[96 + c];
    A[t] = fmaf(px, w0 + w2, fmaf(py, w1 + w3, b1a[c]));
    B[t] = -(px * w2 + py * w3);
    h1[t] = 0.0f;
}

__global__ __launch_bounds__(256) void pre2_kernel(
    const float* __restrict__ pos, const float* __restrict__ h1,
    const float* __restrict__ w2a, const float* __restrict__ b2a,
    float* __restrict__ A, float* __restrict__ B, float* __restrict__ h2, int N)
{
    int t = blockIdx.x * 256 + threadIdx.x;
    if (t >= N * 32) return;
    int n = t >> 5, c = t & 31;
    float px = pos[2 * n], py = pos[2 * n + 1];
    float wx = w2a[32 * 32 + c], wy = w2a[33 * 32 + c];
    float s = fmaf(px, wx, fmaf(py, wy, b2a[c]));
    const float* hrow = h1 + (size_t)n * 32;
#pragma unroll
    for (int k = 0; k < 32; ++k) s = fmaf(hrow[k], w2a[k * 32 + c], s);
    A[t] = s;
    B[t] = -(px * wx + py * wy);
    h2[t] = 0.0f;
}

__global__ __launch_bounds__(256) void bucket_count_kernel(
    const int* __restrict__ ei, int* __restrict__ btot, int E, int NB)
{
    __shared__ int bh[NBMAX];
    int tid = threadIdx.x;
    for (int i = tid; i < NB; i += 256) bh[i] = 0;
    __syncthreads();
    const int* dsts = ei + E;
    int base0 = blockIdx.x * CHUNK;
    for (int i = tid * 4; i < CHUNK; i += 1024) {
        int e = base0 + i;
        if (e + 3 < E) {
            int4 d = *(const int4*)(dsts + e);
            atomicAdd(&bh[d.x >> BSHIFT], 1);
            atomicAdd(&bh[d.y >> BSHIFT], 1);
            atomicAdd(&bh[d.z >> BSHIFT], 1);
            atomicAdd(&bh[d.w >> BSHIFT], 1);
        } else {
            for (int k = e; k < E && k < e + 4; ++k)
                atomicAdd(&bh[dsts[k] >> BSHIFT], 1);
        }
    }
    __syncthreads();
    for (int i = tid; i < NB; i += 256)
        if (bh[i]) atomicAdd(btot + i, bh[i]);
}

__global__ __launch_bounds__(256) void scan_bucket_kernel(
    const int* __restrict__ btot, int* __restrict__ bbase,
    int* __restrict__ bcur, int NB)
{
    __shared__ int ws_[4], wo[4];
    int tid = threadIdx.x, lane = tid & 63, wv = tid >> 6;
    int v = (tid < NB) ? btot[tid] : 0;
    int x = v;
#pragma unroll
    for (int d = 1; d < 64; d <<= 1) {
        int t = __shfl_up(x, d, 64);
        if (lane >= d) x += t;
    }
    if (lane == 63) ws_[wv] = x;
    __syncthreads();
    if (tid == 0) { int r = 0; for (int w = 0; w < 4; ++w) { wo[w] = r; r += ws_[w]; } }
    __syncthreads();
    int ex = wo[wv] + x - v;
    if (tid < NB) { bbase[tid] = ex; bcur[tid] = ex; }
}

__global__ __launch_bounds__(256) void bucket_scatter_kernel(
    const int* __restrict__ ei, int* __restrict__ bcur,
    int* __restrict__ csr_tmp, int E, int NB)
{
    __shared__ int lh[NBMAX];
    __shared__ int lb[NBMAX];
    int tid = threadIdx.x;
    for (int i = tid; i < NB; i += 256) lh[i] = 0;
    __syncthreads();
    const int* dsts = ei + E;
    int base0 = blockIdx.x * CHUNK;
    for (int i = tid * 4; i < CHUNK; i += 1024) {
        int e = base0 + i;
        if (e + 3 < E) {
            int4 d = *(const int4*)(dsts + e);
            atomicAdd(&lh[d.x >> BSHIFT], 1);
            atomicAdd(&lh[d.y >> BSHIFT], 1);
            atomicAdd(&lh[d.z >> BSHIFT], 1);
            atomicAdd(&lh[d.w >> BSHIFT], 1);
        } else {
            for (int k = e; k < E && k < e + 4; ++k)
                atomicAdd(&lh[dsts[k] >> BSHIFT], 1);
        }
    }
    __syncthreads();
    for (int i = tid; i < NB; i += 256) {
        int c = lh[i];
        lb[i] = c ? atomicAdd(bcur + i, c) : 0;
    }
    __syncthreads();
    for (int i = tid; i < NB; i += 256) lh[i] = 0;
    __syncthreads();
    for (int i = tid * 4; i < CHUNK; i += 1024) {
        int e = base0 + i;
        if (e + 3 < E) {
            int4 s = *(const int4*)(ei + e);
            int4 d = *(const int4*)(dsts + e);
            int b, o;
            b = d.x >> BSHIFT; o = atomicAdd(&lh[b], 1);
            csr_tmp[lb[b] + o] = s.x | ((d.x & (BDSTS - 1)) << 20);
            b = d.y >> BSHIFT; o = atomicAdd(&lh[b], 1);
            csr_tmp[lb[b] + o] = s.y | ((d.y & (BDSTS - 1)) << 20);
            b = d.z >> BSHIFT; o = atomicAdd(&lh[b], 1);
            csr_tmp[lb[b] + o] = s.z | ((d.z & (BDSTS - 1)) << 20);
            b = d.w >> BSHIFT; o = atomicAdd(&lh[b], 1);
            csr_tmp[lb[b] + o] = s.w | ((d.w & (BDSTS - 1)) << 20);
        } else {
            for (int k = e; k < E && k < e + 4; ++k) {
                int dd = dsts[k];
                int b = dd >> BSHIFT;
                int o = atomicAdd(&lh[b], 1);
                csr_tmp[lb[b] + o] = ei[k] | ((dd & (BDSTS - 1)) << 20);
            }
        }
    }
}

__global__ __launch_bounds__(256) void bucket_place_kernel(
    const int* __restrict__ csr_tmp, const int* __restrict__ bbase,
    const int* __restrict__ bcur, int* __restrict__ csr_src,
    int* __restrict__ dst_of, int N)
{
    __shared__ int cnt[BDSTS], pre[BDSTS], cur[BDSTS];
    __shared__ int ws_[4], wo[4];
    int b = blockIdx.x, tid = threadIdx.x;
    int d0 = b << BSHIFT;
    int start = bbase[b], end = bcur[b];
    for (int i = tid; i < BDSTS; i += 256) cnt[i] = 0;
    __syncthreads();
    for (int i = start + tid; i < end; i += 256)
        atomicAdd(&cnt[csr_tmp[i] >> 20], 1);
    __syncthreads();
    int lane = tid & 63, wv = tid >> 6;
    int a0 = cnt[2 * tid], a1 = cnt[2 * tid + 1];
    int s = a0 + a1;
    int x = s;
#pragma unroll
    for (int d = 1; d < 64; d <<= 1) {
        int t = __shfl_up(x, d, 64);
        if (lane >= d) x += t;
    }
    if (lane == 63) ws_[wv] = x;
    __syncthreads();
    if (tid == 0) { int r = 0; for (int w = 0; w < 4; ++w) { wo[w] = r; r += ws_[w]; } }
    __syncthreads();
    int ex = wo[wv] + x - s;
    pre[2 * tid] = ex;       pre[2 * tid + 1] = ex + a0;
    cur[2 * tid] = ex;       cur[2 * tid + 1] = ex + a0;
    __syncthreads();
    for (int i = start + tid; i < end; i += 256) {
        int rec = csr_tmp[i];
        int p = atomicAdd(&cur[rec >> 20], 1);
        csr_src[start + p] = rec & 0xFFFFF;
    }
    for (int t = tid; t < BDSTS; t += 256) {
        int d = d0 + t;
        if (d >= N) break;
        int p = start + pre[t], c = cnt[t];
        for (int k = 0; k < c; ++k) dst_of[p + k] = d;
    }
}

// MFMA edge layer: block = 256 threads = 256 edges. Per wave, 64 edges:
// each lane gathers the 32-B k-chunk [quad*8, quad*8+8) of A[src]/B[dst] for
// edge eg*16+(lane&15) (A-frag layout A[m=lane&15][k=quad*8+j], verified),
// h = relu(a+b) -> bf16, 8 MFMAs (4 edge-groups x 2 ch-groups) produce
// 64 edges x 32 ch. D (col=lane&15=ch, row=quad*4+reg=edge) scatters to
// padded sM; phase 2 (strided per-(c,g) chunk scan + filtered atomicMax
// with fp32 bias) unchanged.
__global__ __launch_bounds__(256, 4) void edge_layer_kernel(
    const int* __restrict__ csr_src, const int* __restrict__ dst_of,
    const float* __restrict__ A, const float* __restrict__ B,
    const float* __restrict__ w, const float* __restrict__ bias,
    unsigned int* __restrict__ hout, int E)
{
    __shared__ float sM[256 * 36];
    __shared__ int sdst[256];

    int tid = threadIdx.x;
    int lane = tid & 63;
    int wv = tid >> 6;
    int tileb = blockIdx.x * 256;
    int wbase = tileb + wv * 64;

    // own-edge dst for phase 2
    int e0 = tileb + tid;
    sdst[tid] = (e0 < E) ? dst_of[e0] : -1;

    int m16 = lane & 15;          // row/col within 16-tile
    int kq = (lane >> 4) * 8;     // k-chunk base for this quad

    // B-frags: W[k = kq+j][n = cg*16 + m16] in bf16 (built once)
    short8 bfrag0, bfrag1;
#pragma unroll
    for (int j = 0; j < 8; ++j) {
        bfrag0[j] = bf16r(w[(kq + j) * 32 + m16]);
        bfrag1[j] = bf16r(w[(kq + j) * 32 + 16 + m16]);
    }

    // gather srcs/dsts for the 4 edge-groups
    int sv[4], dv[4];
#pragma unroll
    for (int eg = 0; eg < 4; ++eg) {
        int er = wbase + eg * 16 + m16;
        bool v = er < E;
        sv[eg] = v ? csr_src[er] : 0;
        dv[eg] = v ? dst_of[er] : 0;
    }
    // gather feature chunks (independent loads)
    float4  га0[4], ga1[4], gb0[4], gb1[4];
#pragma unroll
    for (int eg = 0; eg < 4; ++eg) {
        const float4* Ap = (const float4*)(A + (size_t)sv[eg] * 32 + kq);
        const float4* Bp = (const float4*)(B + (size_t)dv[eg] * 32 + kq);
        га0[eg] = Ap[0]; ga1[eg] = Ap[1];
        gb0[eg] = Bp[0]; gb1[eg] = Bp[1];
    }

    f32x4 zero = {0.0f, 0.0f, 0.0f, 0.0f};
#pragma unroll
    for (int eg = 0; eg < 4; ++eg) {
        short8 af;
        af[0] = bf16r(fmaxf(га0[eg].x + gb0[eg].x, 0.0f));
        af[1] = bf16r(fmaxf(га0[eg].y + gb0[eg].y, 0.0f));
        af[2] = bf16r(fmaxf(га0[eg].z + gb0[eg].z, 0.0f));
        af[3] = bf16r(fmaxf(га0[eg].w + gb0[eg].w, 0.0f));
        af[4] = bf16r(fmaxf(ga1[eg].x + gb1[eg].x, 0.0f));
        af[5] = bf16r(fmaxf(ga1[eg].y + gb1[eg].y, 0.0f));
        af[6] = bf16r(fmaxf(ga1[eg].z + gb1[eg].z, 0.0f));
        af[7] = bf16r(fmaxf(ga1[eg].w + gb1[eg].w, 0.0f));
        f32x4 d0 = __builtin_amdgcn_mfma_f32_16x16x32_bf16(af, bfrag0, zero, 0, 0, 0);
        f32x4 d1 = __builtin_amdgcn_mfma_f32_16x16x32_bf16(af, bfrag1, zero, 0, 0, 0);
        int erow = wv * 64 + eg * 16 + (lane >> 4) * 4;
#pragma unroll
        for (int r = 0; r < 4; ++r) {
            sM[(erow + r) * 36 + m16]      = d0[r];
            sM[(erow + r) * 36 + 16 + m16] = d1[r];
        }
    }
    __syncthreads();

    // Phase 2: strided chunk scan (statically addressed), unchanged.
    int c = tid & 31;
    int g = tid >> 5;
    int s0 = g * 32;
    float bc_ = bias[c];
    float run = NEG_BIG;
    int cur = -2;
#pragma unroll 8
    for (int i = 0; i < 32; ++i) {
        int s = s0 + i;
        int d = sdst[s];
        float v = sM[s * 36 + c];
        if (d != cur) {
            if (cur >= 0) {
                float x = run + bc_;
                if (x > 0.0f)
                    atomicMax(hout + (size_t)cur * 32 + c, __float_as_uint(x));
            }
            cur = d;
            run = v;
        } else {
            run = fmaxf(run, v);
        }
    }
    if (cur >= 0) {
        float x = run + bc_;
        if (x > 0.0f) atomicMax(hout + (size_t)cur * 32 + c, __float_as_uint(x));
    }
}

__global__ __launch_bounds__(256) void pool_kernel(
    const float* __restrict__ h2, const int* __restrict__ batch,
    unsigned int* __restrict__ gbuf, int N)
{
    int g = blockIdx.x, p = blockIdx.y;
    __shared__ int sbound[2];
    __shared__ float red[256];
    if (threadIdx.x < 2) {
        int target = g + (int)threadIdx.x;
        int lo = 0, hi = N;
        while (lo < hi) {
            int mid = (lo + hi) >> 1;
            if (batch[mid] < target) lo = mid + 1; else hi = mid;
        }
        sbound[threadIdx.x] = lo;
    }
    __syncthreads();
    int start = sbound[0], end = sbound[1];
    int c = threadIdx.x & 31, r = threadIdx.x >> 5;
    float mx = 0.0f;
    for (int n = start + p * 8 + r; n < end; n += 128)
        mx = fmaxf(mx, h2[(size_t)n * 32 + c]);
    red[threadIdx.x] = mx;
    __syncthreads();
    if (r < 4) red[threadIdx.x] = fmaxf(red[threadIdx.x], red[threadIdx.x + 128]);
    __syncthreads();
    if (r < 2) red[threadIdx.x] = fmaxf(red[threadIdx.x], red[threadIdx.x + 64]);
    __syncthreads();
    if (r == 0) {
        float v = fmaxf(red[threadIdx.x], red[threadIdx.x + 32]);
        if (v > 0.0f) atomicMax(gbuf + g * 32 + c, __float_as_uint(v));
    }
}

__global__ __launch_bounds__(192) void out_kernel(
    const float* __restrict__ gbuf, const float* __restrict__ wc,
    const float* __restrict__ bc, float* __restrict__ out, int G)
{
    int t = threadIdx.x;
    if (t >= G * 3) return;
    int g = t / 3, j = t % 3;
    float s = bc[j];
#pragma unroll
    for (int c = 0; c < 32; ++c)
        s = fmaf(gbuf[g * 32 + c], wc[c * 3 + j], s);
    out[t] = s;
}

extern "C" void kernel_launch(void* const* d_in, const int* in_sizes, int n_in,
                              void* d_out, int out_size, void* d_ws, size_t ws_size,
                              hipStream_t stream) {
    const float* pos = (const float*)d_in[0];
    const float* w1a = (const float*)d_in[1];
    const float* b1a = (const float*)d_in[2];
    const float* w1b = (const float*)d_in[3];
    const float* b1b = (const float*)d_in[4];
    const float* w2a = (const float*)d_in[5];
    const float* b2a = (const float*)d_in[6];
    const float* w2b = (const float*)d_in[7];
    const float* b2b = (const float*)d_in[8];
    const float* wc  = (const float*)d_in[9];
    const float* bc  = (const float*)d_in[10];
    const int* ei    = (const int*)d_in[11];
    const int* batch = (const int*)d_in[12];

    const int N = in_sizes[12];
    const int E = in_sizes[11] / 2;
    const int G = out_size / 3;
    const size_t NC = (size_t)N * 32;
    const int NB = (N + BDSTS - 1) >> BSHIFT;

    int* btot    = (int*)d_ws;          // 256
    int* bbase   = btot + 256;          // 256
    int* bcur    = bbase + 256;         // 256
    int* csr_src = bcur + 256;          // E
    int* dst_of  = csr_src + E;         // E
    float* A     = (float*)(dst_of + E);
    float* B     = A + NC;
    float* h1    = B + NC;
    float* h2    = h1 + NC;
    float* gbuf  = h2 + NC;
    int* csr_tmp = (int*)A;             // aliases A: CSR build precedes pre1

    int ncBlocks = ((int)NC + 255) / 256;
    int ebBlocks = (E + CHUNK - 1) / CHUNK;
    int edBlocks = (E + 255) / 256;

    hipMemsetAsync(btot, 0, 256 * sizeof(int), stream);
    hipMemsetAsync(gbuf, 0, (size_t)G * 32 * sizeof(float), stream);

    bucket_count_kernel<<<ebBlocks, 256, 0, stream>>>(ei, btot, E, NB);
    scan_bucket_kernel<<<1, 256, 0, stream>>>(btot, bbase, bcur, NB);
    bucket_scatter_kernel<<<ebBlocks, 256, 0, stream>>>(ei, bcur, csr_tmp, E, NB);
    bucket_place_kernel<<<NB, 256, 0, stream>>>(csr_tmp, bbase, bcur,
                                                csr_src, dst_of, N);

    pre1_kernel<<<ncBlocks, 256, 0, stream>>>(pos, w1a, b1a, A, B, h1, N);
    edge_layer_kernel<<<edBlocks, 256, 0, stream>>>(csr_src, dst_of, A, B,
                                                    w1b, b1b,
                                                    (unsigned int*)h1, E);
    pre2_kernel<<<ncBlocks, 256, 0, stream>>>(pos, h1, w2a, b2a, A, B, h2, N);
    edge_layer_kernel<<<edBlocks, 256, 0, stream>>>(csr_src, dst_of, A, B,
                                                    w2b, b2b,
                                                    (unsigned int*)h2, E);
    pool_kernel<<<dim3(G, 16), 256, 0, stream>>>(h2, batch,
                                                 (unsigned int*)gbuf, N);
    out_kernel<<<1, 192, 0, stream>>>(gbuf, wc, bc, (float*)d_out, G);
}

// Round 12
// 393.265 us; speedup vs baseline: 1.1602x; 1.1602x over previous
//
#include <hip/hip_runtime.h>
#include <hip/hip_bf16.h>

// Workspace layout (4B units):
// [btot:256][bbase:256][bcur:256][pbtot:256][pbase:256][pcur:256]
// [csr_src:SMAX][tile_dst:SMAX/16][A:N*32][B:N*32][h1:N*32][h2:N*32][gbuf:G*32]
// csr_tmp (E ints) ALIASES A (CSR build completes before pre1 writes A).
// SMAX = padded-edge-list worst bound. csr_src pads = -1; unused tiles dst = -1.
// h1/h2/gbuf hold non-negative float bit patterns (global atomicMax on uint).

#define NEG_BIG (-3.0e38f)
#define BSHIFT 9
#define BDSTS (1 << BSHIFT)      // 512 dsts per bucket
#define NBMAX 256
#define CHUNK 16384              // edges per block in count/scatter passes

typedef __attribute__((ext_vector_type(8))) short short8;
typedef __attribute__((ext_vector_type(4))) float f32x4;

__device__ __forceinline__ short bf16r(float f) {
    unsigned u = __float_as_uint(f);
    unsigned r = (u + 0x7FFFu + ((u >> 16) & 1u)) >> 16;
    return (short)r;
}

__global__ __launch_bounds__(256) void pre1_kernel(
    const float* __restrict__ pos, const float* __restrict__ w1a,
    const float* __restrict__ b1a, float* __restrict__ A, float* __restrict__ B,
    float* __restrict__ h1, int N)
{
    int t = blockIdx.x * 256 + threadIdx.x;
    if (t >= N * 32) return;
    int n = t >> 5, c = t & 31;
    float px = pos[2 * n], py = pos[2 * n + 1];
    float w0 = w1a[c], w1 = w1a[32 + c], w2 = w1a[64 + c], w3 = w1a[96 + c];
    A[t] = fmaf(px, w0 + w2, fmaf(py, w1 + w3, b1a[c]));
    B[t] = -(px * w2 + py * w3);
    h1[t] = 0.0f;
}

__global__ __launch_bounds__(256) void pre2_kernel(
    const float* __restrict__ pos, const float* __restrict__ h1,
    const float* __restrict__ w2a, const float* __restrict__ b2a,
    float* __restrict__ A, float* __restrict__ B, float* __restrict__ h2, int N)
{
    int t = blockIdx.x * 256 + threadIdx.x;
    if (t >= N * 32) return;
    int n = t >> 5, c = t & 31;
    float px = pos[2 * n], py = pos[2 * n + 1];
    float wx = w2a[32 * 32 + c], wy = w2a[33 * 32 + c];
    float s = fmaf(px, wx, fmaf(py, wy, b2a[c]));
    const float* hrow = h1 + (size_t)n * 32;
#pragma unroll
    for (int k = 0; k < 32; ++k) s = fmaf(hrow[k], w2a[k * 32 + c], s);
    A[t] = s;
    B[t] = -(px * wx + py * wy);
    h2[t] = 0.0f;
}

__global__ __launch_bounds__(256) void bucket_count_kernel(
    const int* __restrict__ ei, int* __restrict__ btot, int E, int NB)
{
    __shared__ int bh[NBMAX];
    int tid = threadIdx.x;
    for (int i = tid; i < NB; i += 256) bh[i] = 0;
    __syncthreads();
    const int* dsts = ei + E;
    int base0 = blockIdx.x * CHUNK;
    for (int i = tid * 4; i < CHUNK; i += 1024) {
        int e = base0 + i;
        if (e + 3 < E) {
            int4 d = *(const int4*)(dsts + e);
            atomicAdd(&bh[d.x >> BSHIFT], 1);
            atomicAdd(&bh[d.y >> BSHIFT], 1);
            atomicAdd(&bh[d.z >> BSHIFT], 1);
            atomicAdd(&bh[d.w >> BSHIFT], 1);
        } else {
            for (int k = e; k < E && k < e + 4; ++k)
                atomicAdd(&bh[dsts[k] >> BSHIFT], 1);
        }
    }
    __syncthreads();
    for (int i = tid; i < NB; i += 256)
        if (bh[i]) atomicAdd(btot + i, bh[i]);
}

// exclusive scan of a <=256-entry array -> base & cursor copies. Single block.
__global__ __launch_bounds__(256) void scan_bucket_kernel(
    const int* __restrict__ tot, int* __restrict__ base_,
    int* __restrict__ cur_, int NB)
{
    __shared__ int ws_[4], wo[4];
    int tid = threadIdx.x, lane = tid & 63, wv = tid >> 6;
    int v = (tid < NB) ? tot[tid] : 0;
    int x = v;
#pragma unroll
    for (int d = 1; d < 64; d <<= 1) {
        int t = __shfl_up(x, d, 64);
        if (lane >= d) x += t;
    }
    if (lane == 63) ws_[wv] = x;
    __syncthreads();
    if (tid == 0) { int r = 0; for (int w = 0; w < 4; ++w) { wo[w] = r; r += ws_[w]; } }
    __syncthreads();
    int ex = wo[wv] + x - v;
    if (tid < NB) { base_[tid] = ex; cur_[tid] = ex; }
}

__global__ __launch_bounds__(256) void bucket_scatter_kernel(
    const int* __restrict__ ei, int* __restrict__ bcur,
    int* __restrict__ csr_tmp, int E, int NB)
{
    __shared__ int lh[NBMAX];
    __shared__ int lb[NBMAX];
    int tid = threadIdx.x;
    for (int i = tid; i < NB; i += 256) lh[i] = 0;
    __syncthreads();
    const int* dsts = ei + E;
    int base0 = blockIdx.x * CHUNK;
    for (int i = tid * 4; i < CHUNK; i += 1024) {
        int e = base0 + i;
        if (e + 3 < E) {
            int4 d = *(const int4*)(dsts + e);
            atomicAdd(&lh[d.x >> BSHIFT], 1);
            atomicAdd(&lh[d.y >> BSHIFT], 1);
            atomicAdd(&lh[d.z >> BSHIFT], 1);
            atomicAdd(&lh[d.w >> BSHIFT], 1);
        } else {
            for (int k = e; k < E && k < e + 4; ++k)
                atomicAdd(&lh[dsts[k] >> BSHIFT], 1);
        }
    }
    __syncthreads();
    for (int i = tid; i < NB; i += 256) {
        int c = lh[i];
        lb[i] = c ? atomicAdd(bcur + i, c) : 0;
    }
    __syncthreads();
    for (int i = tid; i < NB; i += 256) lh[i] = 0;
    __syncthreads();
    for (int i = tid * 4; i < CHUNK; i += 1024) {
        int e = base0 + i;
        if (e + 3 < E) {
            int4 s = *(const int4*)(ei + e);
            int4 d = *(const int4*)(dsts + e);
            int b, o;
            b = d.x >> BSHIFT; o = atomicAdd(&lh[b], 1);
            csr_tmp[lb[b] + o] = s.x | ((d.x & (BDSTS - 1)) << 20);
            b = d.y >> BSHIFT; o = atomicAdd(&lh[b], 1);
            csr_tmp[lb[b] + o] = s.y | ((d.y & (BDSTS - 1)) << 20);
            b = d.z >> BSHIFT; o = atomicAdd(&lh[b], 1);
            csr_tmp[lb[b] + o] = s.z | ((d.z & (BDSTS - 1)) << 20);
            b = d.w >> BSHIFT; o = atomicAdd(&lh[b], 1);
            csr_tmp[lb[b] + o] = s.w | ((d.w & (BDSTS - 1)) << 20);
        } else {
            for (int k = e; k < E && k < e + 4; ++k) {
                int dd = dsts[k];
                int b = dd >> BSHIFT;
                int o = atomicAdd(&lh[b], 1);
                csr_tmp[lb[b] + o] = ei[k] | ((dd & (BDSTS - 1)) << 20);
            }
        }
    }
}

// padded bucket totals: sum over dsts of ceil(cnt/16)*16
__global__ __launch_bounds__(256) void place_a_kernel(
    const int* __restrict__ csr_tmp, const int* __restrict__ bbase,
    const int* __restrict__ bcur, int* __restrict__ pbtot)
{
    __shared__ int cnt[BDSTS];
    __shared__ int ws_[4];
    int b = blockIdx.x, tid = threadIdx.x;
    int start = bbase[b], end = bcur[b];
    for (int i = tid; i < BDSTS; i += 256) cnt[i] = 0;
    __syncthreads();
    for (int i = start + tid; i < end; i += 256)
        atomicAdd(&cnt[csr_tmp[i] >> 20], 1);
    __syncthreads();
    int s = ((cnt[2 * tid] + 15) & ~15) + ((cnt[2 * tid + 1] + 15) & ~15);
    int lane = tid & 63, wv = tid >> 6;
#pragma unroll
    for (int d = 1; d < 64; d <<= 1) s += __shfl_down(s, d, 64);
    if (lane == 0) ws_[wv] = s;
    __syncthreads();
    if (tid == 0) pbtot[b] = ws_[0] + ws_[1] + ws_[2] + ws_[3];
}

// place into padded layout; fill pads with -1; emit tile_dst.
__global__ __launch_bounds__(256) void place_b_kernel(
    const int* __restrict__ csr_tmp, const int* __restrict__ bbase,
    const int* __restrict__ bcur, const int* __restrict__ pbase,
    int* __restrict__ csr_src, int* __restrict__ tile_dst, int N)
{
    __shared__ int cnt[BDSTS], pre[BDSTS], cur[BDSTS];
    __shared__ int ws_[4], wo[4];
    int b = blockIdx.x, tid = threadIdx.x;
    int d0 = b << BSHIFT;
    int start = bbase[b], end = bcur[b];
    int pstart = pbase[b];
    for (int i = tid; i < BDSTS; i += 256) cnt[i] = 0;
    __syncthreads();
    for (int i = start + tid; i < end; i += 256)
        atomicAdd(&cnt[csr_tmp[i] >> 20], 1);
    __syncthreads();
    int lane = tid & 63, wv = tid >> 6;
    int a0 = (cnt[2 * tid] + 15) & ~15;
    int a1 = (cnt[2 * tid + 1] + 15) & ~15;
    int s = a0 + a1;
    int x = s;
#pragma unroll
    for (int d = 1; d < 64; d <<= 1) {
        int t = __shfl_up(x, d, 64);
        if (lane >= d) x += t;
    }
    if (lane == 63) ws_[wv] = x;
    __syncthreads();
    if (tid == 0) { int r = 0; for (int w = 0; w < 4; ++w) { wo[w] = r; r += ws_[w]; } }
    __syncthreads();
    int ex = wo[wv] + x - s;
    pre[2 * tid] = ex;       pre[2 * tid + 1] = ex + a0;
    cur[2 * tid] = ex;       cur[2 * tid + 1] = ex + a0;
    __syncthreads();
    for (int i = start + tid; i < end; i += 256) {
        int rec = csr_tmp[i];
        int p = atomicAdd(&cur[rec >> 20], 1);
        csr_src[pstart + p] = rec & 0xFFFFF;
    }
    for (int t = tid; t < BDSTS; t += 256) {
        int d = d0 + t;
        if (d >= N) break;
        int c = cnt[t], pc = (c + 15) & ~15;
        int base = pstart + pre[t];
        for (int k = c; k < pc; ++k) csr_src[base + k] = -1;
        int tb = base >> 4, nt = pc >> 4;
        for (int k = 0; k < nt; ++k) tile_dst[tb + k] = d;
    }
}

// MFMA edge layer over the PADDED slot list. Block = 256 slots = 16 tiles;
// wave = 4 tiles of 16 edges, each tile has ONE dst (tile_dst), pads src=-1.
// A-frag: lane(q,m16) holds k-chunk [q*8,q*8+8) of edge m16's h row;
// B rows are tile-uniform (L1 broadcast). D (col=ch,row=edge) reduced fully
// in registers: ballot-mask pads to NEG_BIG, 3 in-lane fmax + shfl_xor(16,32);
// same-dst neighbor tiles merged in registers; filtered atomicMax at flush
// (bias added fp32 at flush). No LDS, no __syncthreads.
__global__ __launch_bounds__(256, 4) void edge_layer_kernel(
    const int* __restrict__ csr_src, const int* __restrict__ tile_dst,
    const float* __restrict__ A, const float* __restrict__ B,
    const float* __restrict__ w, const float* __restrict__ bias,
    unsigned int* __restrict__ hout)
{
    int tid = threadIdx.x;
    int lane = tid & 63;
    int wv = tid >> 6;
    int wbase = blockIdx.x * 256 + wv * 64;   // slot base of this wave
    int m16 = lane & 15;
    int q = lane >> 4;
    int kq = q * 8;
    int ch = (lane < 16) ? m16 : (16 + m16);  // channel owned by lanes 0..31

    int td[4];
#pragma unroll
    for (int eg = 0; eg < 4; ++eg) td[eg] = tile_dst[(wbase >> 4) + eg];
    if (td[0] < 0 && td[1] < 0 && td[2] < 0 && td[3] < 0) return;

    // W fragments (wave-uniform)
    short8 bf0, bf1;
#pragma unroll
    for (int j = 0; j < 8; ++j) {
        bf0[j] = bf16r(w[(kq + j) * 32 + m16]);
        bf1[j] = bf16r(w[(kq + j) * 32 + 16 + m16]);
    }
    float myb = bias[ch];                     // used by lanes 0..31

    int src[4];
#pragma unroll
    for (int eg = 0; eg < 4; ++eg) {
        int sidx = wbase + eg * 16 + m16;
        src[eg] = (td[eg] >= 0) ? csr_src[sidx] : -1;
    }

    float4 av0[4], av1[4], bv0[4], bv1[4];
#pragma unroll
    for (int eg = 0; eg < 4; ++eg) {
        int brow = (td[eg] >= 0) ? td[eg] : 0;
        int arow = (src[eg] >= 0) ? src[eg] : brow;     // pad lanes reuse B line
        const float4* Ap = (const float4*)(A + (size_t)arow * 32 + kq);
        const float4* Bp = (const float4*)(B + (size_t)brow * 32 + kq);
        av0[eg] = Ap[0]; av1[eg] = Ap[1];
        bv0[eg] = Bp[0]; bv1[eg] = Bp[1];
    }

    f32x4 zero = {0.0f, 0.0f, 0.0f, 0.0f};
    float cv0 = NEG_BIG, cv1 = NEG_BIG;
    int cdst = -1;
#pragma unroll
    for (int eg = 0; eg < 4; ++eg) {
        unsigned long long bal = __ballot(src[eg] >= 0);
        short8 af;
        af[0] = bf16r(fmaxf(av0[eg].x + bv0[eg].x, 0.0f));
        af[1] = bf16r(fmaxf(av0[eg].y + bv0[eg].y, 0.0f));
        af[2] = bf16r(fmaxf(av0[eg].z + bv0[eg].z, 0.0f));
        af[3] = bf16r(fmaxf(av0[eg].w + bv0[eg].w, 0.0f));
        af[4] = bf16r(fmaxf(av1[eg].x + bv1[eg].x, 0.0f));
        af[5] = bf16r(fmaxf(av1[eg].y + bv1[eg].y, 0.0f));
        af[6] = bf16r(fmaxf(av1[eg].z + bv1[eg].z, 0.0f));
        af[7] = bf16r(fmaxf(av1[eg].w + bv1[eg].w, 0.0f));
        f32x4 d0 = __builtin_amdgcn_mfma_f32_16x16x32_bf16(af, bf0, zero, 0, 0, 0);
        f32x4 d1 = __builtin_amdgcn_mfma_f32_16x16x32_bf16(af, bf1, zero, 0, 0, 0);
        float v0 = NEG_BIG, v1 = NEG_BIG;
#pragma unroll
        for (int r = 0; r < 4; ++r) {
            bool ok = (bal >> (q * 4 + r)) & 1ull;
            v0 = fmaxf(v0, ok ? d0[r] : NEG_BIG);
            v1 = fmaxf(v1, ok ? d1[r] : NEG_BIG);
        }
        v0 = fmaxf(v0, __shfl_xor(v0, 16, 64));
        v0 = fmaxf(v0, __shfl_xor(v0, 32, 64));
        v1 = fmaxf(v1, __shfl_xor(v1, 16, 64));
        v1 = fmaxf(v1, __shfl_xor(v1, 32, 64));
        int d = td[eg];                   // wave-uniform
        if (d != cdst) {
            if (cdst >= 0 && lane < 32) {
                float x = ((lane < 16) ? cv0 : cv1) + myb;
                if (x > 0.0f)
                    atomicMax(hout + (size_t)cdst * 32 + ch, __float_as_uint(x));
            }
            cdst = d; cv0 = v0; cv1 = v1;
        } else {
            cv0 = fmaxf(cv0, v0); cv1 = fmaxf(cv1, v1);
        }
    }
    if (cdst >= 0 && lane < 32) {
        float x = ((lane < 16) ? cv0 : cv1) + myb;
        if (x > 0.0f)
            atomicMax(hout + (size_t)cdst * 32 + ch, __float_as_uint(x));
    }
}

__global__ __launch_bounds__(256) void pool_kernel(
    const float* __restrict__ h2, const int* __restrict__ batch,
    unsigned int* __restrict__ gbuf, int N)
{
    int g = blockIdx.x, p = blockIdx.y;
    __shared__ int sbound[2];
    __shared__ float red[256];
    if (threadIdx.x < 2) {
        int target = g + (int)threadIdx.x;
        int lo = 0, hi = N;
        while (lo < hi) {
            int mid = (lo + hi) >> 1;
            if (batch[mid] < target) lo = mid + 1; else hi = mid;
        }
        sbound[threadIdx.x] = lo;
    }
    __syncthreads();
    int start = sbound[0], end = sbound[1];
    int c = threadIdx.x & 31, r = threadIdx.x >> 5;
    float mx = 0.0f;
    for (int n = start + p * 8 + r; n < end; n += 128)
        mx = fmaxf(mx, h2[(size_t)n * 32 + c]);
    red[threadIdx.x] = mx;
    __syncthreads();
    if (r < 4) red[threadIdx.x] = fmaxf(red[threadIdx.x], red[threadIdx.x + 128]);
    __syncthreads();
    if (r < 2) red[threadIdx.x] = fmaxf(red[threadIdx.x], red[threadIdx.x + 64]);
    __syncthreads();
    if (r == 0) {
        float v = fmaxf(red[threadIdx.x], red[threadIdx.x + 32]);
        if (v > 0.0f) atomicMax(gbuf + g * 32 + c, __float_as_uint(v));
    }
}

__global__ __launch_bounds__(192) void out_kernel(
    const float* __restrict__ gbuf, const float* __restrict__ wc,
    const float* __restrict__ bc, float* __restrict__ out, int G)
{
    int t = threadIdx.x;
    if (t >= G * 3) return;
    int g = t / 3, j = t % 3;
    float s = bc[j];
#pragma unroll
    for (int c = 0; c < 32; ++c)
        s = fmaf(gbuf[g * 32 + c], wc[c * 3 + j], s);
    out[t] = s;
}

extern "C" void kernel_launch(void* const* d_in, const int* in_sizes, int n_in,
                              void* d_out, int out_size, void* d_ws, size_t ws_size,
                              hipStream_t stream) {
    const float* pos = (const float*)d_in[0];
    const float* w1a = (const float*)d_in[1];
    const float* b1a = (const float*)d_in[2];
    const float* w1b = (const float*)d_in[3];
    const float* b1b = (const float*)d_in[4];
    const float* w2a = (const float*)d_in[5];
    const float* b2a = (const float*)d_in[6];
    const float* w2b = (const float*)d_in[7];
    const float* b2b = (const float*)d_in[8];
    const float* wc  = (const float*)d_in[9];
    const float* bc  = (const float*)d_in[10];
    const int* ei    = (const int*)d_in[11];
    const int* batch = (const int*)d_in[12];

    const int N = in_sizes[12];
    const int E = in_sizes[11] / 2;
    const int G = out_size / 3;
    const size_t NC = (size_t)N * 32;
    const int NB = (N + BDSTS - 1) >> BSHIFT;
    const int SMAX = (E + 15 * ((N < E) ? N : E) + 255) & ~255;  // padded bound
    const int TMAX = SMAX >> 4;

    int* btot    = (int*)d_ws;          // 256
    int* bbase   = btot + 256;
    int* bcur    = bbase + 256;
    int* pbtot   = bcur + 256;
    int* pbase   = pbtot + 256;
    int* pcur    = pbase + 256;
    int* csr_src = pcur + 256;          // SMAX
    int* tile_dst = csr_src + SMAX;     // TMAX
    float* A     = (float*)(tile_dst + TMAX);
    float* B     = A + NC;
    float* h1    = B + NC;
    float* h2    = h1 + NC;
    float* gbuf  = h2 + NC;
    int* csr_tmp = (int*)A;             // aliases A: CSR build precedes pre1

    int ncBlocks = ((int)NC + 255) / 256;
    int ebBlocks = (E + CHUNK - 1) / CHUNK;
    int edBlocks = (SMAX + 255) / 256;

    hipMemsetAsync(btot, 0, 256 * sizeof(int), stream);
    hipMemsetAsync(gbuf, 0, (size_t)G * 32 * sizeof(float), stream);
    hipMemsetAsync(csr_src, 0xFF, (size_t)SMAX * sizeof(int), stream);
    hipMemsetAsync(tile_dst, 0xFF, (size_t)TMAX * sizeof(int), stream);

    bucket_count_kernel<<<ebBlocks, 256, 0, stream>>>(ei, btot, E, NB);
    scan_bucket_kernel<<<1, 256, 0, stream>>>(btot, bbase, bcur, NB);
    bucket_scatter_kernel<<<ebBlocks, 256, 0, stream>>>(ei, bcur, csr_tmp, E, NB);
    place_a_kernel<<<NB, 256, 0, stream>>>(csr_tmp, bbase, bcur, pbtot);
    scan_bucket_kernel<<<1, 256, 0, stream>>>(pbtot, pbase, pcur, NB);
    place_b_kernel<<<NB, 256, 0, stream>>>(csr_tmp, bbase, bcur, pbase,
                                           csr_src, tile_dst, N);

    pre1_kernel<<<ncBlocks, 256, 0, stream>>>(pos, w1a, b1a, A, B, h1, N);
    edge_layer_kernel<<<edBlocks, 256, 0, stream>>>(csr_src, tile_dst, A, B,
                                                    w1b, b1b, (unsigned int*)h1);
    pre2_kernel<<<ncBlocks, 256, 0, stream>>>(pos, h1, w2a, b2a, A, B, h2, N);
    edge_layer_kernel<<<edBlocks, 256, 0, stream>>>(csr_src, tile_dst, A, B,
                                                    w2b, b2b, (unsigned int*)h2);
    pool_kernel<<<dim3(G, 16), 256, 0, stream>>>(h2, batch,
                                                 (unsigned int*)gbuf, N);
    out_kernel<<<1, 192, 0, stream>>>(gbuf, wc, bc, (float*)d_out, G);
}

// Round 13
// 378.417 us; speedup vs baseline: 1.2057x; 1.0392x over previous
//
#include <hip/hip_runtime.h>
#include <hip/hip_bf16.h>

// Workspace layout (4B units):
// [btot:256][bbase:256][bcur:256][pbtot:256][pbase:256][pcur:256]
// [csr_src:SMAX][tile_dst:SMAX/16][Abf:N*16][Bbf:N*16][h1:N*32][h2:N*32][gbuf:G*32]
// A/B stored as packed bf16 (2 channels per uint). csr_tmp (E ints) ALIASES
// Abf+Bbf (N*32 ints = E; CSR build completes before pre1 writes them).
// csr_src pads = -1; unused tiles dst = -1. h1/h2/gbuf hold non-negative float
// bit patterns (global atomicMax on uint).

#define NEG_BIG (-3.0e38f)
#define BSHIFT 9
#define BDSTS (1 << BSHIFT)      // 512 dsts per bucket
#define NBMAX 256
#define CHUNK 16384              // edges per block in count/scatter passes

typedef __attribute__((ext_vector_type(8))) short short8;
typedef __attribute__((ext_vector_type(4))) float f32x4;

__device__ __forceinline__ short bf16r(float f) {
    unsigned u = __float_as_uint(f);
    unsigned r = (u + 0x7FFFu + ((u >> 16) & 1u)) >> 16;
    return (short)r;
}
__device__ __forceinline__ unsigned pack_bf16(float lo, float hi) {
    return ((unsigned)(unsigned short)bf16r(lo)) |
           (((unsigned)(unsigned short)bf16r(hi)) << 16);
}

// thread t in [0,N*16): n = t>>4, channels c0=2*(t&15), c1=c0+1.
__global__ __launch_bounds__(256) void pre1_kernel(
    const float* __restrict__ pos, const float* __restrict__ w1a,
    const float* __restrict__ b1a, unsigned* __restrict__ Abf,
    unsigned* __restrict__ Bbf, float* __restrict__ h1, int N)
{
    int t = blockIdx.x * 256 + threadIdx.x;
    if (t >= N * 16) return;
    int n = t >> 4, c0 = (t & 15) * 2;
    float px = pos[2 * n], py = pos[2 * n + 1];
    float a[2], b[2];
#pragma unroll
    for (int i = 0; i < 2; ++i) {
        int c = c0 + i;
        float w0 = w1a[c], w1 = w1a[32 + c], w2 = w1a[64 + c], w3 = w1a[96 + c];
        a[i] = fmaf(px, w0 + w2, fmaf(py, w1 + w3, b1a[c]));
        b[i] = -(px * w2 + py * w3);
    }
    Abf[t] = pack_bf16(a[0], a[1]);
    Bbf[t] = pack_bf16(b[0], b[1]);
    *(float2*)(h1 + 2 * (size_t)t) = make_float2(0.0f, 0.0f);
}

__global__ __launch_bounds__(256) void pre2_kernel(
    const float* __restrict__ pos, const float* __restrict__ h1,
    const float* __restrict__ w2a, const float* __restrict__ b2a,
    unsigned* __restrict__ Abf, unsigned* __restrict__ Bbf,
    float* __restrict__ h2, int N)
{
    int t = blockIdx.x * 256 + threadIdx.x;
    if (t >= N * 16) return;
    int n = t >> 4, c0 = (t & 15) * 2;
    float px = pos[2 * n], py = pos[2 * n + 1];
    const float* hrow = h1 + (size_t)n * 32;
    float a[2], b[2];
#pragma unroll
    for (int i = 0; i < 2; ++i) {
        int c = c0 + i;
        float wx = w2a[32 * 32 + c], wy = w2a[33 * 32 + c];
        float s = fmaf(px, wx, fmaf(py, wy, b2a[c]));
#pragma unroll
        for (int k = 0; k < 32; ++k) s = fmaf(hrow[k], w2a[k * 32 + c], s);
        a[i] = s;
        b[i] = -(px * wx + py * wy);
    }
    Abf[t] = pack_bf16(a[0], a[1]);
    Bbf[t] = pack_bf16(b[0], b[1]);
    *(float2*)(h2 + 2 * (size_t)t) = make_float2(0.0f, 0.0f);
}

__global__ __launch_bounds__(256) void bucket_count_kernel(
    const int* __restrict__ ei, int* __restrict__ btot, int E, int NB)
{
    __shared__ int bh[NBMAX];
    int tid = threadIdx.x;
    for (int i = tid; i < NB; i += 256) bh[i] = 0;
    __syncthreads();
    const int* dsts = ei + E;
    int base0 = blockIdx.x * CHUNK;
    for (int i = tid * 4; i < CHUNK; i += 1024) {
        int e = base0 + i;
        if (e + 3 < E) {
            int4 d = *(const int4*)(dsts + e);
            atomicAdd(&bh[d.x >> BSHIFT], 1);
            atomicAdd(&bh[d.y >> BSHIFT], 1);
            atomicAdd(&bh[d.z >> BSHIFT], 1);
            atomicAdd(&bh[d.w >> BSHIFT], 1);
        } else {
            for (int k = e; k < E && k < e + 4; ++k)
                atomicAdd(&bh[dsts[k] >> BSHIFT], 1);
        }
    }
    __syncthreads();
    for (int i = tid; i < NB; i += 256)
        if (bh[i]) atomicAdd(btot + i, bh[i]);
}

__global__ __launch_bounds__(256) void scan_bucket_kernel(
    const int* __restrict__ tot, int* __restrict__ base_,
    int* __restrict__ cur_, int NB)
{
    __shared__ int ws_[4], wo[4];
    int tid = threadIdx.x, lane = tid & 63, wv = tid >> 6;
    int v = (tid < NB) ? tot[tid] : 0;
    int x = v;
#pragma unroll
    for (int d = 1; d < 64; d <<= 1) {
        int t = __shfl_up(x, d, 64);
        if (lane >= d) x += t;
    }
    if (lane == 63) ws_[wv] = x;
    __syncthreads();
    if (tid == 0) { int r = 0; for (int w = 0; w < 4; ++w) { wo[w] = r; r += ws_[w]; } }
    __syncthreads();
    int ex = wo[wv] + x - v;
    if (tid < NB) { base_[tid] = ex; cur_[tid] = ex; }
}

__global__ __launch_bounds__(256) void bucket_scatter_kernel(
    const int* __restrict__ ei, int* __restrict__ bcur,
    int* __restrict__ csr_tmp, int E, int NB)
{
    __shared__ int lh[NBMAX];
    __shared__ int lb[NBMAX];
    int tid = threadIdx.x;
    for (int i = tid; i < NB; i += 256) lh[i] = 0;
    __syncthreads();
    const int* dsts = ei + E;
    int base0 = blockIdx.x * CHUNK;
    for (int i = tid * 4; i < CHUNK; i += 1024) {
        int e = base0 + i;
        if (e + 3 < E) {
            int4 d = *(const int4*)(dsts + e);
            atomicAdd(&lh[d.x >> BSHIFT], 1);
            atomicAdd(&lh[d.y >> BSHIFT], 1);
            atomicAdd(&lh[d.z >> BSHIFT], 1);
            atomicAdd(&lh[d.w >> BSHIFT], 1);
        } else {
            for (int k = e; k < E && k < e + 4; ++k)
                atomicAdd(&lh[dsts[k] >> BSHIFT], 1);
        }
    }
    __syncthreads();
    for (int i = tid; i < NB; i += 256) {
        int c = lh[i];
        lb[i] = c ? atomicAdd(bcur + i, c) : 0;
    }
    __syncthreads();
    for (int i = tid; i < NB; i += 256) lh[i] = 0;
    __syncthreads();
    for (int i = tid * 4; i < CHUNK; i += 1024) {
        int e = base0 + i;
        if (e + 3 < E) {
            int4 s = *(const int4*)(ei + e);
            int4 d = *(const int4*)(dsts + e);
            int b, o;
            b = d.x >> BSHIFT; o = atomicAdd(&lh[b], 1);
            csr_tmp[lb[b] + o] = s.x | ((d.x & (BDSTS - 1)) << 20);
            b = d.y >> BSHIFT; o = atomicAdd(&lh[b], 1);
            csr_tmp[lb[b] + o] = s.y | ((d.y & (BDSTS - 1)) << 20);
            b = d.z >> BSHIFT; o = atomicAdd(&lh[b], 1);
            csr_tmp[lb[b] + o] = s.z | ((d.z & (BDSTS - 1)) << 20);
            b = d.w >> BSHIFT; o = atomicAdd(&lh[b], 1);
            csr_tmp[lb[b] + o] = s.w | ((d.w & (BDSTS - 1)) << 20);
        } else {
            for (int k = e; k < E && k < e + 4; ++k) {
                int dd = dsts[k];
                int b = dd >> BSHIFT;
                int o = atomicAdd(&lh[b], 1);
                csr_tmp[lb[b] + o] = ei[k] | ((dd & (BDSTS - 1)) << 20);
            }
        }
    }
}

__global__ __launch_bounds__(256) void place_a_kernel(
    const int* __restrict__ csr_tmp, const int* __restrict__ bbase,
    const int* __restrict__ bcur, int* __restrict__ pbtot)
{
    __shared__ int cnt[BDSTS];
    __shared__ int ws_[4];
    int b = blockIdx.x, tid = threadIdx.x;
    int start = bbase[b], end = bcur[b];
    for (int i = tid; i < BDSTS; i += 256) cnt[i] = 0;
    __syncthreads();
    for (int i = start + tid; i < end; i += 256)
        atomicAdd(&cnt[csr_tmp[i] >> 20], 1);
    __syncthreads();
    int s = ((cnt[2 * tid] + 15) & ~15) + ((cnt[2 * tid + 1] + 15) & ~15);
    int lane = tid & 63, wv = tid >> 6;
#pragma unroll
    for (int d = 1; d < 64; d <<= 1) s += __shfl_down(s, d, 64);
    if (lane == 0) ws_[wv] = s;
    __syncthreads();
    if (tid == 0) pbtot[b] = ws_[0] + ws_[1] + ws_[2] + ws_[3];
}

__global__ __launch_bounds__(256) void place_b_kernel(
    const int* __restrict__ csr_tmp, const int* __restrict__ bbase,
    const int* __restrict__ bcur, const int* __restrict__ pbase,
    int* __restrict__ csr_src, int* __restrict__ tile_dst, int N)
{
    __shared__ int cnt[BDSTS], pre[BDSTS], cur[BDSTS];
    __shared__ int ws_[4], wo[4];
    int b = blockIdx.x, tid = threadIdx.x;
    int d0 = b << BSHIFT;
    int start = bbase[b], end = bcur[b];
    int pstart = pbase[b];
    for (int i = tid; i < BDSTS; i += 256) cnt[i] = 0;
    __syncthreads();
    for (int i = start + tid; i < end; i += 256)
        atomicAdd(&cnt[csr_tmp[i] >> 20], 1);
    __syncthreads();
    int lane = tid & 63, wv = tid >> 6;
    int a0 = (cnt[2 * tid] + 15) & ~15;
    int a1 = (cnt[2 * tid + 1] + 15) & ~15;
    int s = a0 + a1;
    int x = s;
#pragma unroll
    for (int d = 1; d < 64; d <<= 1) {
        int t = __shfl_up(x, d, 64);
        if (lane >= d) x += t;
    }
    if (lane == 63) ws_[wv] = x;
    __syncthreads();
    if (tid == 0) { int r = 0; for (int w = 0; w < 4; ++w) { wo[w] = r; r += ws_[w]; } }
    __syncthreads();
    int ex = wo[wv] + x - s;
    pre[2 * tid] = ex;       pre[2 * tid + 1] = ex + a0;
    cur[2 * tid] = ex;       cur[2 * tid + 1] = ex + a0;
    __syncthreads();
    for (int i = start + tid; i < end; i += 256) {
        int rec = csr_tmp[i];
        int p = atomicAdd(&cur[rec >> 20], 1);
        csr_src[pstart + p] = rec & 0xFFFFF;
    }
    for (int t = tid; t < BDSTS; t += 256) {
        int d = d0 + t;
        if (d >= N) break;
        int c = cnt[t], pc = (c + 15) & ~15;
        int base = pstart + pre[t];
        for (int k = c; k < pc; ++k) csr_src[base + k] = -1;
        int tb = base >> 4, nt = pc >> 4;
        for (int k = 0; k < nt; ++k) tile_dst[tb + k] = d;
    }
}

// MFMA edge layer over the PADDED slot list, bf16 A/B (8-B gathers/lane).
// Wave = 4 tiles of 16 edges, each tile one dst; pads src=-1. Register-only
// reduce (ballot mask + shfl_xor); filtered atomicMax at flush (fp32 bias).
__global__ __launch_bounds__(256, 4) void edge_layer_kernel(
    const int* __restrict__ csr_src, const int* __restrict__ tile_dst,
    const unsigned* __restrict__ Abf, const unsigned* __restrict__ Bbf,
    const float* __restrict__ w, const float* __restrict__ bias,
    unsigned int* __restrict__ hout)
{
    int tid = threadIdx.x;
    int lane = tid & 63;
    int wv = tid >> 6;
    int wbase = blockIdx.x * 256 + wv * 64;
    int m16 = lane & 15;
    int q = lane >> 4;
    int kq = q * 8;
    int ch = (lane < 16) ? m16 : (16 + m16);

    int td[4];
#pragma unroll
    for (int eg = 0; eg < 4; ++eg) td[eg] = tile_dst[(wbase >> 4) + eg];
    if (td[0] < 0 && td[1] < 0 && td[2] < 0 && td[3] < 0) return;

    short8 bf0, bf1;
#pragma unroll
    for (int j = 0; j < 8; ++j) {
        bf0[j] = bf16r(w[(kq + j) * 32 + m16]);
        bf1[j] = bf16r(w[(kq + j) * 32 + 16 + m16]);
    }
    float myb = bias[ch];

    int src[4];
#pragma unroll
    for (int eg = 0; eg < 4; ++eg) {
        int sidx = wbase + eg * 16 + m16;
        src[eg] = (td[eg] >= 0) ? csr_src[sidx] : -1;
    }

    uint2 av[4], bv[4];   // 4 bf16 pairs = 8 elems per row chunk
#pragma unroll
    for (int eg = 0; eg < 4; ++eg) {
        int brow = (td[eg] >= 0) ? td[eg] : 0;
        int arow = (src[eg] >= 0) ? src[eg] : brow;
        // row = 16 uints; k-chunk kq..kq+7 = uints [kq/2, kq/2+4)
        const uint2* Ap = (const uint2*)(Abf + (size_t)arow * 16 + (kq >> 1));
        const uint2* Bp = (const uint2*)(Bbf + (size_t)brow * 16 + (kq >> 1));
        av[eg] = Ap[0]; bv[eg] = Bp[0];
    }
    uint2 av2[4], bv2[4];
#pragma unroll
    for (int eg = 0; eg < 4; ++eg) {
        int brow = (td[eg] >= 0) ? td[eg] : 0;
        int arow = (src[eg] >= 0) ? src[eg] : brow;
        const uint2* Ap = (const uint2*)(Abf + (size_t)arow * 16 + (kq >> 1));
        const uint2* Bp = (const uint2*)(Bbf + (size_t)brow * 16 + (kq >> 1));
        av2[eg] = Ap[1]; bv2[eg] = Bp[1];
    }

    f32x4 zero = {0.0f, 0.0f, 0.0f, 0.0f};
    float cv0 = NEG_BIG, cv1 = NEG_BIG;
    int cdst = -1;
#pragma unroll
    for (int eg = 0; eg < 4; ++eg) {
        unsigned long long bal = __ballot(src[eg] >= 0);
        unsigned ua[4] = {av[eg].x, av[eg].y, av2[eg].x, av2[eg].y};
        unsigned ub[4] = {bv[eg].x, bv[eg].y, bv2[eg].x, bv2[eg].y};
        short8 af;
#pragma unroll
        for (int d = 0; d < 4; ++d) {
            float a0 = __uint_as_float(ua[d] << 16);
            float a1 = __uint_as_float(ua[d] & 0xFFFF0000u);
            float b0 = __uint_as_float(ub[d] << 16);
            float b1 = __uint_as_float(ub[d] & 0xFFFF0000u);
            af[2 * d]     = bf16r(fmaxf(a0 + b0, 0.0f));
            af[2 * d + 1] = bf16r(fmaxf(a1 + b1, 0.0f));
        }
        f32x4 d0 = __builtin_amdgcn_mfma_f32_16x16x32_bf16(af, bf0, zero, 0, 0, 0);
        f32x4 d1 = __builtin_amdgcn_mfma_f32_16x16x32_bf16(af, bf1, zero, 0, 0, 0);
        float v0 = NEG_BIG, v1 = NEG_BIG;
#pragma unroll
        for (int r = 0; r < 4; ++r) {
            bool ok = (bal >> (q * 4 + r)) & 1ull;
            v0 = fmaxf(v0, ok ? d0[r] : NEG_BIG);
            v1 = fmaxf(v1, ok ? d1[r] : NEG_BIG);
        }
        v0 = fmaxf(v0, __shfl_xor(v0, 16, 64));
        v0 = fmaxf(v0, __shfl_xor(v0, 32, 64));
        v1 = fmaxf(v1, __shfl_xor(v1, 16, 64));
        v1 = fmaxf(v1, __shfl_xor(v1, 32, 64));
        int d = td[eg];
        if (d != cdst) {
            if (cdst >= 0 && lane < 32) {
                float x = ((lane < 16) ? cv0 : cv1) + myb;
                if (x > 0.0f)
                    atomicMax(hout + (size_t)cdst * 32 + ch, __float_as_uint(x));
            }
            cdst = d; cv0 = v0; cv1 = v1;
        } else {
            cv0 = fmaxf(cv0, v0); cv1 = fmaxf(cv1, v1);
        }
    }
    if (cdst >= 0 && lane < 32) {
        float x = ((lane < 16) ? cv0 : cv1) + myb;
        if (x > 0.0f)
            atomicMax(hout + (size_t)cdst * 32 + ch, __float_as_uint(x));
    }
}

__global__ __launch_bounds__(256) void pool_kernel(
    const float* __restrict__ h2, const int* __restrict__ batch,
    unsigned int* __restrict__ gbuf, int N)
{
    int g = blockIdx.x, p = blockIdx.y;
    __shared__ int sbound[2];
    __shared__ float red[256];
    if (threadIdx.x < 2) {
        int target = g + (int)threadIdx.x;
        int lo = 0, hi = N;
        while (lo < hi) {
            int mid = (lo + hi) >> 1;
            if (batch[mid] < target) lo = mid + 1; else hi = mid;
        }
        sbound[threadIdx.x] = lo;
    }
    __syncthreads();
    int start = sbound[0], end = sbound[1];
    int c = threadIdx.x & 31, r = threadIdx.x >> 5;
    float mx = 0.0f;
    for (int n = start + p * 8 + r; n < end; n += 128)
        mx = fmaxf(mx, h2[(size_t)n * 32 + c]);
    red[threadIdx.x] = mx;
    __syncthreads();
    if (r < 4) red[threadIdx.x] = fmaxf(red[threadIdx.x], red[threadIdx.x + 128]);
    __syncthreads();
    if (r < 2) red[threadIdx.x] = fmaxf(red[threadIdx.x], red[threadIdx.x + 64]);
    __syncthreads();
    if (r == 0) {
        float v = fmaxf(red[threadIdx.x], red[threadIdx.x + 32]);
        if (v > 0.0f) atomicMax(gbuf + g * 32 + c, __float_as_uint(v));
    }
}

__global__ __launch_bounds__(192) void out_kernel(
    const float* __restrict__ gbuf, const float* __restrict__ wc,
    const float* __restrict__ bc, float* __restrict__ out, int G)
{
    int t = threadIdx.x;
    if (t >= G * 3) return;
    int g = t / 3, j = t % 3;
    float s = bc[j];
#pragma unroll
    for (int c = 0; c < 32; ++c)
        s = fmaf(gbuf[g * 32 + c], wc[c * 3 + j], s);
    out[t] = s;
}

extern "C" void kernel_launch(void* const* d_in, const int* in_sizes, int n_in,
                              void* d_out, int out_size, void* d_ws, size_t ws_size,
                              hipStream_t stream) {
    const float* pos = (const float*)d_in[0];
    const float* w1a = (const float*)d_in[1];
    const float* b1a = (const float*)d_in[2];
    const float* w1b = (const float*)d_in[3];
    const float* b1b = (const float*)d_in[4];
    const float* w2a = (const float*)d_in[5];
    const float* b2a = (const float*)d_in[6];
    const float* w2b = (const float*)d_in[7];
    const float* b2b = (const float*)d_in[8];
    const float* wc  = (const float*)d_in[9];
    const float* bc  = (const float*)d_in[10];
    const int* ei    = (const int*)d_in[11];
    const int* batch = (const int*)d_in[12];

    const int N = in_sizes[12];
    const int E = in_sizes[11] / 2;
    const int G = out_size / 3;
    const size_t NC = (size_t)N * 32;
    const int NB = (N + BDSTS - 1) >> BSHIFT;
    const int SMAX = (E + 15 * ((N < E) ? N : E) + 255) & ~255;  // padded bound
    const int TMAX = SMAX >> 4;

    int* btot    = (int*)d_ws;          // 256
    int* bbase   = btot + 256;
    int* bcur    = bbase + 256;
    int* pbtot   = bcur + 256;
    int* pbase   = pbtot + 256;
    int* pcur    = pbase + 256;
    int* csr_src = pcur + 256;          // SMAX
    int* tile_dst = csr_src + SMAX;     // TMAX
    unsigned* Abf = (unsigned*)(tile_dst + TMAX);   // N*16
    unsigned* Bbf = Abf + (size_t)N * 16;           // N*16
    float* h1    = (float*)(Bbf + (size_t)N * 16);
    float* h2    = h1 + NC;
    float* gbuf  = h2 + NC;
    int* csr_tmp = (int*)Abf;           // aliases Abf+Bbf (N*32 ints >= E)

    int npBlocks = ((int)(N * 16) + 255) / 256;
    int ebBlocks = (E + CHUNK - 1) / CHUNK;
    int edBlocks = (SMAX + 255) / 256;

    hipMemsetAsync(btot, 0, 256 * sizeof(int), stream);
    hipMemsetAsync(gbuf, 0, (size_t)G * 32 * sizeof(float), stream);
    hipMemsetAsync(tile_dst, 0xFF, (size_t)TMAX * sizeof(int), stream);

    bucket_count_kernel<<<ebBlocks, 256, 0, stream>>>(ei, btot, E, NB);
    scan_bucket_kernel<<<1, 256, 0, stream>>>(btot, bbase, bcur, NB);
    bucket_scatter_kernel<<<ebBlocks, 256, 0, stream>>>(ei, bcur, csr_tmp, E, NB);
    place_a_kernel<<<NB, 256, 0, stream>>>(csr_tmp, bbase, bcur, pbtot);
    scan_bucket_kernel<<<1, 256, 0, stream>>>(pbtot, pbase, pcur, NB);
    place_b_kernel<<<NB, 256, 0, stream>>>(csr_tmp, bbase, bcur, pbase,
                                           csr_src, tile_dst, N);

    pre1_kernel<<<npBlocks, 256, 0, stream>>>(pos, w1a, b1a, Abf, Bbf, h1, N);
    edge_layer_kernel<<<edBlocks, 256, 0, stream>>>(csr_src, tile_dst, Abf, Bbf,
                                                    w1b, b1b, (unsigned int*)h1);
    pre2_kernel<<<npBlocks, 256, 0, stream>>>(pos, h1, w2a, b2a, Abf, Bbf, h2, N);
    edge_layer_kernel<<<edBlocks, 256, 0, stream>>>(csr_src, tile_dst, Abf, Bbf,
                                                    w2b, b2b, (unsigned int*)h2);
    pool_kernel<<<dim3(G, 16), 256, 0, stream>>>(h2, batch,
                                                 (unsigned int*)gbuf, N);
    out_kernel<<<1, 192, 0, stream>>>(gbuf, wc, bc, (float*)d_out, G);
}

// Round 14
// 370.333 us; speedup vs baseline: 1.2320x; 1.0218x over previous
//
#include <hip/hip_runtime.h>
#include <hip/hip_bf16.h>

// Workspace layout (4B units):
// [btot:256][bbase:256][bcur:256][pcur:256]
// [csr_src:SMAX][tile_dst:SMAX/16][Abf:N*16][Bbf:N*16][h1:N*32][h2:N*32][gbuf:G*32]
// A/B stored as packed bf16 (2 channels per uint). csr_tmp (E ints) ALIASES
// Abf+Bbf (N*32 ints = E; CSR build completes before pre1 writes them).
// csr_src pads = -1; unused tiles dst = -1. h1/h2/gbuf hold non-negative float
// bit patterns (global atomicMax on uint).

#define NEG_BIG (-3.0e38f)
#define BSHIFT 9
#define BDSTS (1 << BSHIFT)      // 512 dsts per bucket
#define NBMAX 256
#define CHUNK 4096               // edges per block in count/scatter passes

typedef __attribute__((ext_vector_type(8))) short short8;
typedef __attribute__((ext_vector_type(4))) float f32x4;
typedef __attribute__((ext_vector_type(4))) unsigned uint4v;

__device__ __forceinline__ short bf16r(float f) {
    unsigned u = __float_as_uint(f);
    unsigned r = (u + 0x7FFFu + ((u >> 16) & 1u)) >> 16;
    return (short)r;
}
__device__ __forceinline__ unsigned pack_bf16(float lo, float hi) {
    return ((unsigned)(unsigned short)bf16r(lo)) |
           (((unsigned)(unsigned short)bf16r(hi)) << 16);
}

// thread t in [0,N*16): n = t>>4, channels c0=2*(t&15), c1=c0+1.
__global__ __launch_bounds__(256) void pre1_kernel(
    const float* __restrict__ pos, const float* __restrict__ w1a,
    const float* __restrict__ b1a, unsigned* __restrict__ Abf,
    unsigned* __restrict__ Bbf, float* __restrict__ h1, int N)
{
    int t = blockIdx.x * 256 + threadIdx.x;
    if (t >= N * 16) return;
    int n = t >> 4, c0 = (t & 15) * 2;
    float px = pos[2 * n], py = pos[2 * n + 1];
    float a[2], b[2];
#pragma unroll
    for (int i = 0; i < 2; ++i) {
        int c = c0 + i;
        float w0 = w1a[c], w1 = w1a[32 + c], w2 = w1a[64 + c], w3 = w1a[96 + c];
        a[i] = fmaf(px, w0 + w2, fmaf(py, w1 + w3, b1a[c]));
        b[i] = -(px * w2 + py * w3);
    }
    Abf[t] = pack_bf16(a[0], a[1]);
    Bbf[t] = pack_bf16(b[0], b[1]);
    *(float2*)(h1 + 2 * (size_t)t) = make_float2(0.0f, 0.0f);
}

__global__ __launch_bounds__(256) void pre2_kernel(
    const float* __restrict__ pos, const float* __restrict__ h1,
    const float* __restrict__ w2a, const float* __restrict__ b2a,
    unsigned* __restrict__ Abf, unsigned* __restrict__ Bbf,
    float* __restrict__ h2, int N)
{
    int t = blockIdx.x * 256 + threadIdx.x;
    if (t >= N * 16) return;
    int n = t >> 4, c0 = (t & 15) * 2;
    float px = pos[2 * n], py = pos[2 * n + 1];
    const float* hrow = h1 + (size_t)n * 32;
    float a[2], b[2];
#pragma unroll
    for (int i = 0; i < 2; ++i) {
        int c = c0 + i;
        float wx = w2a[32 * 32 + c], wy = w2a[33 * 32 + c];
        float s = fmaf(px, wx, fmaf(py, wy, b2a[c]));
#pragma unroll
        for (int k = 0; k < 32; ++k) s = fmaf(hrow[k], w2a[k * 32 + c], s);
        a[i] = s;
        b[i] = -(px * wx + py * wy);
    }
    Abf[t] = pack_bf16(a[0], a[1]);
    Bbf[t] = pack_bf16(b[0], b[1]);
    *(float2*)(h2 + 2 * (size_t)t) = make_float2(0.0f, 0.0f);
}

__global__ __launch_bounds__(256) void bucket_count_kernel(
    const int* __restrict__ ei, int* __restrict__ btot, int E, int NB)
{
    __shared__ int bh[NBMAX];
    int tid = threadIdx.x;
    for (int i = tid; i < NB; i += 256) bh[i] = 0;
    __syncthreads();
    const int* dsts = ei + E;
    int base0 = blockIdx.x * CHUNK;
    for (int i = tid * 4; i < CHUNK; i += 1024) {
        int e = base0 + i;
        if (e + 3 < E) {
            int4 d = *(const int4*)(dsts + e);
            atomicAdd(&bh[d.x >> BSHIFT], 1);
            atomicAdd(&bh[d.y >> BSHIFT], 1);
            atomicAdd(&bh[d.z >> BSHIFT], 1);
            atomicAdd(&bh[d.w >> BSHIFT], 1);
        } else {
            for (int k = e; k < E && k < e + 4; ++k)
                atomicAdd(&bh[dsts[k] >> BSHIFT], 1);
        }
    }
    __syncthreads();
    for (int i = tid; i < NB; i += 256)
        if (bh[i]) atomicAdd(btot + i, bh[i]);
}

__global__ __launch_bounds__(256) void scan_bucket_kernel(
    const int* __restrict__ tot, int* __restrict__ base_,
    int* __restrict__ cur_, int NB)
{
    __shared__ int ws_[4], wo[4];
    int tid = threadIdx.x, lane = tid & 63, wv = tid >> 6;
    int v = (tid < NB) ? tot[tid] : 0;
    int x = v;
#pragma unroll
    for (int d = 1; d < 64; d <<= 1) {
        int t = __shfl_up(x, d, 64);
        if (lane >= d) x += t;
    }
    if (lane == 63) ws_[wv] = x;
    __syncthreads();
    if (tid == 0) { int r = 0; for (int w = 0; w < 4; ++w) { wo[w] = r; r += ws_[w]; } }
    __syncthreads();
    int ex = wo[wv] + x - v;
    if (tid < NB) { base_[tid] = ex; cur_[tid] = ex; }
}

__global__ __launch_bounds__(256) void bucket_scatter_kernel(
    const int* __restrict__ ei, int* __restrict__ bcur,
    int* __restrict__ csr_tmp, int E, int NB)
{
    __shared__ int lh[NBMAX];
    __shared__ int lb[NBMAX];
    int tid = threadIdx.x;
    for (int i = tid; i < NB; i += 256) lh[i] = 0;
    __syncthreads();
    const int* dsts = ei + E;
    int base0 = blockIdx.x * CHUNK;
    for (int i = tid * 4; i < CHUNK; i += 1024) {
        int e = base0 + i;
        if (e + 3 < E) {
            int4 d = *(const int4*)(dsts + e);
            atomicAdd(&lh[d.x >> BSHIFT], 1);
            atomicAdd(&lh[d.y >> BSHIFT], 1);
            atomicAdd(&lh[d.z >> BSHIFT], 1);
            atomicAdd(&lh[d.w >> BSHIFT], 1);
        } else {
            for (int k = e; k < E && k < e + 4; ++k)
                atomicAdd(&lh[dsts[k] >> BSHIFT], 1);
        }
    }
    __syncthreads();
    for (int i = tid; i < NB; i += 256) {
        int c = lh[i];
        lb[i] = c ? atomicAdd(bcur + i, c) : 0;
    }
    __syncthreads();
    for (int i = tid; i < NB; i += 256) lh[i] = 0;
    __syncthreads();
    for (int i = tid * 4; i < CHUNK; i += 1024) {
        int e = base0 + i;
        if (e + 3 < E) {
            int4 s = *(const int4*)(ei + e);
            int4 d = *(const int4*)(dsts + e);
            int b, o;
            b = d.x >> BSHIFT; o = atomicAdd(&lh[b], 1);
            csr_tmp[lb[b] + o] = s.x | ((d.x & (BDSTS - 1)) << 20);
            b = d.y >> BSHIFT; o = atomicAdd(&lh[b], 1);
            csr_tmp[lb[b] + o] = s.y | ((d.y & (BDSTS - 1)) << 20);
            b = d.z >> BSHIFT; o = atomicAdd(&lh[b], 1);
            csr_tmp[lb[b] + o] = s.z | ((d.z & (BDSTS - 1)) << 20);
            b = d.w >> BSHIFT; o = atomicAdd(&lh[b], 1);
            csr_tmp[lb[b] + o] = s.w | ((d.w & (BDSTS - 1)) << 20);
        } else {
            for (int k = e; k < E && k < e + 4; ++k) {
                int dd = dsts[k];
                int b = dd >> BSHIFT;
                int o = atomicAdd(&lh[b], 1);
                csr_tmp[lb[b] + o] = ei[k] | ((dd & (BDSTS - 1)) << 20);
            }
        }
    }
}

// Count per-dst, pad to x16, self-reserve padded window via global cursor
// (cross-bucket order irrelevant), place csr_src, emit tile_dst, fill pads.
__global__ __launch_bounds__(256) void place_kernel(
    const int* __restrict__ csr_tmp, const int* __restrict__ bbase,
    const int* __restrict__ bcur, int* __restrict__ pcur,
    int* __restrict__ csr_src, int* __restrict__ tile_dst, int N)
{
    __shared__ int cnt[BDSTS], pre[BDSTS], cur[BDSTS];
    __shared__ int ws_[4], wo[4];
    __shared__ int pstart_s;
    int b = blockIdx.x, tid = threadIdx.x;
    int d0 = b << BSHIFT;
    int start = bbase[b], end = bcur[b];
    for (int i = tid; i < BDSTS; i += 256) cnt[i] = 0;
    __syncthreads();
    for (int i = start + tid; i < end; i += 256)
        atomicAdd(&cnt[csr_tmp[i] >> 20], 1);
    __syncthreads();
    int lane = tid & 63, wv = tid >> 6;
    int a0 = (cnt[2 * tid] + 15) & ~15;
    int a1 = (cnt[2 * tid + 1] + 15) & ~15;
    int s = a0 + a1;
    int x = s;
#pragma unroll
    for (int d = 1; d < 64; d <<= 1) {
        int t = __shfl_up(x, d, 64);
        if (lane >= d) x += t;
    }
    if (lane == 63) ws_[wv] = x;
    __syncthreads();
    if (tid == 0) {
        int r = 0;
        for (int w = 0; w < 4; ++w) { wo[w] = r; r += ws_[w]; }
        pstart_s = r ? atomicAdd(pcur, r) : 0;
    }
    __syncthreads();
    int pstart = pstart_s;
    int ex = wo[wv] + x - s;
    pre[2 * tid] = ex;       pre[2 * tid + 1] = ex + a0;
    cur[2 * tid] = ex;       cur[2 * tid + 1] = ex + a0;
    __syncthreads();
    for (int i = start + tid; i < end; i += 256) {
        int rec = csr_tmp[i];
        int p = atomicAdd(&cur[rec >> 20], 1);
        csr_src[pstart + p] = rec & 0xFFFFF;
    }
    for (int t = tid; t < BDSTS; t += 256) {
        int d = d0 + t;
        if (d >= N) break;
        int c = cnt[t], pc = (c + 15) & ~15;
        int base = pstart + pre[t];
        for (int k = c; k < pc; ++k) csr_src[base + k] = -1;
        int tb = base >> 4, nt = pc >> 4;
        for (int k = 0; k < nt; ++k) tile_dst[tb + k] = d;
    }
}

// MFMA edge layer over the PADDED slot list, bf16 A/B (one uint4 gather per
// operand). h repack via v_perm (truncation). Register-only reduce (ballot
// mask + shfl_xor); filtered atomicMax at flush (fp32 bias).
__global__ __launch_bounds__(256, 4) void edge_layer_kernel(
    const int* __restrict__ csr_src, const int* __restrict__ tile_dst,
    const unsigned* __restrict__ Abf, const unsigned* __restrict__ Bbf,
    const float* __restrict__ w, const float* __restrict__ bias,
    unsigned int* __restrict__ hout)
{
    int tid = threadIdx.x;
    int lane = tid & 63;
    int wv = tid >> 6;
    int wbase = blockIdx.x * 256 + wv * 64;
    int m16 = lane & 15;
    int q = lane >> 4;
    int kq = q * 8;
    int ch = (lane < 16) ? m16 : (16 + m16);

    int td[4];
#pragma unroll
    for (int eg = 0; eg < 4; ++eg) td[eg] = tile_dst[(wbase >> 4) + eg];
    if (td[0] < 0 && td[1] < 0 && td[2] < 0 && td[3] < 0) return;

    short8 bf0, bf1;
#pragma unroll
    for (int j = 0; j < 8; ++j) {
        bf0[j] = bf16r(w[(kq + j) * 32 + m16]);
        bf1[j] = bf16r(w[(kq + j) * 32 + 16 + m16]);
    }
    float myb = bias[ch];

    int src[4];
#pragma unroll
    for (int eg = 0; eg < 4; ++eg) {
        int sidx = wbase + eg * 16 + m16;
        src[eg] = (td[eg] >= 0) ? csr_src[sidx] : -1;
    }

    uint4 ua4[4], ub4[4];    // 8 bf16 = full k-chunk per operand, one load each
#pragma unroll
    for (int eg = 0; eg < 4; ++eg) {
        int brow = (td[eg] >= 0) ? td[eg] : 0;
        int arow = (src[eg] >= 0) ? src[eg] : brow;
        ua4[eg] = *(const uint4*)(Abf + (size_t)arow * 16 + (kq >> 1));
        ub4[eg] = *(const uint4*)(Bbf + (size_t)brow * 16 + (kq >> 1));
    }

    f32x4 zero = {0.0f, 0.0f, 0.0f, 0.0f};
    float cv0 = NEG_BIG, cv1 = NEG_BIG;
    int cdst = -1;
#pragma unroll
    for (int eg = 0; eg < 4; ++eg) {
        unsigned long long bal = __ballot(src[eg] >= 0);
        unsigned ua[4] = {ua4[eg].x, ua4[eg].y, ua4[eg].z, ua4[eg].w};
        unsigned ub[4] = {ub4[eg].x, ub4[eg].y, ub4[eg].z, ub4[eg].w};
        uint4v pk;
#pragma unroll
        for (int d = 0; d < 4; ++d) {
            float a0 = __uint_as_float(ua[d] << 16);
            float a1 = __uint_as_float(ua[d] & 0xFFFF0000u);
            float b0 = __uint_as_float(ub[d] << 16);
            float b1 = __uint_as_float(ub[d] & 0xFFFF0000u);
            float r0 = fmaxf(a0 + b0, 0.0f);
            float r1 = fmaxf(a1 + b1, 0.0f);
            // pack hi16(r0), hi16(r1) -> one uint (truncation; relu >= 0)
            pk[d] = __builtin_amdgcn_perm(__float_as_uint(r1),
                                          __float_as_uint(r0), 0x07060302u);
        }
        short8 af = __builtin_bit_cast(short8, pk);
        f32x4 d0 = __builtin_amdgcn_mfma_f32_16x16x32_bf16(af, bf0, zero, 0, 0, 0);
        f32x4 d1 = __builtin_amdgcn_mfma_f32_16x16x32_bf16(af, bf1, zero, 0, 0, 0);
        float v0 = NEG_BIG, v1 = NEG_BIG;
#pragma unroll
        for (int r = 0; r < 4; ++r) {
            bool ok = (bal >> (q * 4 + r)) & 1ull;
            v0 = fmaxf(v0, ok ? d0[r] : NEG_BIG);
            v1 = fmaxf(v1, ok ? d1[r] : NEG_BIG);
        }
        v0 = fmaxf(v0, __shfl_xor(v0, 16, 64));
        v0 = fmaxf(v0, __shfl_xor(v0, 32, 64));
        v1 = fmaxf(v1, __shfl_xor(v1, 16, 64));
        v1 = fmaxf(v1, __shfl_xor(v1, 32, 64));
        int d = td[eg];
        if (d != cdst) {
            if (cdst >= 0 && lane < 32) {
                float x = ((lane < 16) ? cv0 : cv1) + myb;
                if (x > 0.0f)
                    atomicMax(hout + (size_t)cdst * 32 + ch, __float_as_uint(x));
            }
            cdst = d; cv0 = v0; cv1 = v1;
        } else {
            cv0 = fmaxf(cv0, v0); cv1 = fmaxf(cv1, v1);
        }
    }
    if (cdst >= 0 && lane < 32) {
        float x = ((lane < 16) ? cv0 : cv1) + myb;
        if (x > 0.0f)
            atomicMax(hout + (size_t)cdst * 32 + ch, __float_as_uint(x));
    }
}

__global__ __launch_bounds__(256) void pool_kernel(
    const float* __restrict__ h2, const int* __restrict__ batch,
    unsigned int* __restrict__ gbuf, int N)
{
    int g = blockIdx.x, p = blockIdx.y;
    __shared__ int sbound[2];
    __shared__ float red[256];
    if (threadIdx.x < 2) {
        int target = g + (int)threadIdx.x;
        int lo = 0, hi = N;
        while (lo < hi) {
            int mid = (lo + hi) >> 1;
            if (batch[mid] < target) lo = mid + 1; else hi = mid;
        }
        sbound[threadIdx.x] = lo;
    }
    __syncthreads();
    int start = sbound[0], end = sbound[1];
    int c = threadIdx.x & 31, r = threadIdx.x >> 5;
    float mx = 0.0f;
    for (int n = start + p * 8 + r; n < end; n += 128)
        mx = fmaxf(mx, h2[(size_t)n * 32 + c]);
    red[threadIdx.x] = mx;
    __syncthreads();
    if (r < 4) red[threadIdx.x] = fmaxf(red[threadIdx.x], red[threadIdx.x + 128]);
    __syncthreads();
    if (r < 2) red[threadIdx.x] = fmaxf(red[threadIdx.x], red[threadIdx.x + 64]);
    __syncthreads();
    if (r == 0) {
        float v = fmaxf(red[threadIdx.x], red[threadIdx.x + 32]);
        if (v > 0.0f) atomicMax(gbuf + g * 32 + c, __float_as_uint(v));
    }
}

__global__ __launch_bounds__(192) void out_kernel(
    const float* __restrict__ gbuf, const float* __restrict__ wc,
    const float* __restrict__ bc, float* __restrict__ out, int G)
{
    int t = threadIdx.x;
    if (t >= G * 3) return;
    int g = t / 3, j = t % 3;
    float s = bc[j];
#pragma unroll
    for (int c = 0; c < 32; ++c)
        s = fmaf(gbuf[g * 32 + c], wc[c * 3 + j], s);
    out[t] = s;
}

extern "C" void kernel_launch(void* const* d_in, const int* in_sizes, int n_in,
                              void* d_out, int out_size, void* d_ws, size_t ws_size,
                              hipStream_t stream) {
    const float* pos = (const float*)d_in[0];
    const float* w1a = (const float*)d_in[1];
    const float* b1a = (const float*)d_in[2];
    const float* w1b = (const float*)d_in[3];
    const float* b1b = (const float*)d_in[4];
    const float* w2a = (const float*)d_in[5];
    const float* b2a = (const float*)d_in[6];
    const float* w2b = (const float*)d_in[7];
    const float* b2b = (const float*)d_in[8];
    const float* wc  = (const float*)d_in[9];
    const float* bc  = (const float*)d_in[10];
    const int* ei    = (const int*)d_in[11];
    const int* batch = (const int*)d_in[12];

    const int N = in_sizes[12];
    const int E = in_sizes[11] / 2;
    const int G = out_size / 3;
    const size_t NC = (size_t)N * 32;
    const int NB = (N + BDSTS - 1) >> BSHIFT;
    const int SMAX = (E + 15 * ((N < E) ? N : E) + 255) & ~255;  // padded bound
    const int TMAX = SMAX >> 4;

    int* btot    = (int*)d_ws;          // 256
    int* bbase   = btot + 256;
    int* bcur    = bbase + 256;
    int* pcur    = bcur + 256;          // 256 (1 used)
    int* csr_src = pcur + 256;          // SMAX
    int* tile_dst = csr_src + SMAX;     // TMAX
    unsigned* Abf = (unsigned*)(tile_dst + TMAX);   // N*16
    unsigned* Bbf = Abf + (size_t)N * 16;           // N*16
    float* h1    = (float*)(Bbf + (size_t)N * 16);
    float* h2    = h1 + NC;
    float* gbuf  = h2 + NC;
    int* csr_tmp = (int*)Abf;           // aliases Abf+Bbf (N*32 ints >= E)

    int npBlocks = ((int)(N * 16) + 255) / 256;
    int ebBlocks = (E + CHUNK - 1) / CHUNK;
    int edBlocks = (SMAX + 255) / 256;

    hipMemsetAsync(btot, 0, 1024 * sizeof(int), stream);   // btot + scan bufs + pcur
    hipMemsetAsync(gbuf, 0, (size_t)G * 32 * sizeof(float), stream);
    hipMemsetAsync(tile_dst, 0xFF, (size_t)TMAX * sizeof(int), stream);

    bucket_count_kernel<<<ebBlocks, 256, 0, stream>>>(ei, btot, E, NB);
    scan_bucket_kernel<<<1, 256, 0, stream>>>(btot, bbase, bcur, NB);
    bucket_scatter_kernel<<<ebBlocks, 256, 0, stream>>>(ei, bcur, csr_tmp, E, NB);
    place_kernel<<<NB, 256, 0, stream>>>(csr_tmp, bbase, bcur, pcur,
                                         csr_src, tile_dst, N);

    pre1_kernel<<<npBlocks, 256, 0, stream>>>(pos, w1a, b1a, Abf, Bbf, h1, N);
    edge_layer_kernel<<<edBlocks, 256, 0, stream>>>(csr_src, tile_dst, Abf, Bbf,
                                                    w1b, b1b, (unsigned int*)h1);
    pre2_kernel<<<npBlocks, 256, 0, stream>>>(pos, h1, w2a, b2a, Abf, Bbf, h2, N);
    edge_layer_kernel<<<edBlocks, 256, 0, stream>>>(csr_src, tile_dst, Abf, Bbf,
                                                    w2b, b2b, (unsigned int*)h2);
    pool_kernel<<<dim3(G, 16), 256, 0, stream>>>(h2, batch,
                                                 (unsigned int*)gbuf, N);
    out_kernel<<<1, 192, 0, stream>>>(gbuf, wc, bc, (float*)d_out, G);
}

// Round 15
// 362.703 us; speedup vs baseline: 1.2580x; 1.0210x over previous
//
#include <hip/hip_runtime.h>
#include <hip/hip_bf16.h>

// Workspace layout (4B units):
// [btot:1024][pcur:256][bbase:1024][bcur:1024][wfbuf:1024]
// [csr_src:SMAX][tile_dst:SMAX/16][Abf:N*16][Bbf:N*16][h1:N*32][h2:N*32][gbuf:G*32]
// A/B stored as packed bf16 (2 channels per uint). csr_tmp (E ints) ALIASES
// Abf+Bbf (N*32 ints = E; CSR build completes before pre1 writes them).
// csr_src pads = -1; unused tiles dst = -1. h1/h2/gbuf hold non-negative float
// bit patterns (global atomicMax on uint).
// wfbuf: per-lane MFMA B-operand W fragments, [layer(2)][frag(2)][lane(64)] x uint4.

#define NEG_BIG (-3.0e38f)
#define BSHIFT 7
#define BDSTS (1 << BSHIFT)      // 128 dsts per bucket
#define NBMAX 1024
#define CHUNK 4096               // edges per block in count/scatter passes

typedef __attribute__((ext_vector_type(8))) short short8;
typedef __attribute__((ext_vector_type(4))) float f32x4;
typedef __attribute__((ext_vector_type(4))) unsigned uint4v;

__device__ __forceinline__ short bf16r(float f) {
    unsigned u = __float_as_uint(f);
    unsigned r = (u + 0x7FFFu + ((u >> 16) & 1u)) >> 16;
    return (short)r;
}
__device__ __forceinline__ unsigned pack_bf16(float lo, float hi) {
    return ((unsigned)(unsigned short)bf16r(lo)) |
           (((unsigned)(unsigned short)bf16r(hi)) << 16);
}

// Build per-lane W fragments for both layers. t: l=t>>7, frag=(t>>6)&1, lane=t&63.
__global__ __launch_bounds__(256) void wprep_kernel(
    const float* __restrict__ w1b, const float* __restrict__ w2b,
    unsigned* __restrict__ wfbuf)
{
    int t = threadIdx.x;
    int l = t >> 7, frag = (t >> 6) & 1, lane = t & 63;
    const float* w = l ? w2b : w1b;
    int m16 = lane & 15, kq = (lane >> 4) * 8;
    int cb = frag * 16 + m16;
    unsigned out[4];
#pragma unroll
    for (int p = 0; p < 4; ++p)
        out[p] = pack_bf16(w[(kq + 2 * p) * 32 + cb], w[(kq + 2 * p + 1) * 32 + cb]);
    *(uint4v*)(wfbuf + (size_t)t * 4) =
        (uint4v){out[0], out[1], out[2], out[3]};
}

// thread t in [0,N*16): n = t>>4, channels c0=2*(t&15), c1=c0+1.
__global__ __launch_bounds__(256) void pre1_kernel(
    const float* __restrict__ pos, const float* __restrict__ w1a,
    const float* __restrict__ b1a, unsigned* __restrict__ Abf,
    unsigned* __restrict__ Bbf, float* __restrict__ h1, int N)
{
    int t = blockIdx.x * 256 + threadIdx.x;
    if (t >= N * 16) return;
    int n = t >> 4, c0 = (t & 15) * 2;
    float px = pos[2 * n], py = pos[2 * n + 1];
    float a[2], b[2];
#pragma unroll
    for (int i = 0; i < 2; ++i) {
        int c = c0 + i;
        float w0 = w1a[c], w1 = w1a[32 + c], w2 = w1a[64 + c], w3 = w1a[96 + c];
        a[i] = fmaf(px, w0 + w2, fmaf(py, w1 + w3, b1a[c]));
        b[i] = -(px * w2 + py * w3);
    }
    Abf[t] = pack_bf16(a[0], a[1]);
    Bbf[t] = pack_bf16(b[0], b[1]);
    *(float2*)(h1 + 2 * (size_t)t) = make_float2(0.0f, 0.0f);
}

__global__ __launch_bounds__(256) void pre2_kernel(
    const float* __restrict__ pos, const float* __restrict__ h1,
    const float* __restrict__ w2a, const float* __restrict__ b2a,
    unsigned* __restrict__ Abf, unsigned* __restrict__ Bbf,
    float* __restrict__ h2, int N)
{
    int t = blockIdx.x * 256 + threadIdx.x;
    if (t >= N * 16) return;
    int n = t >> 4, c0 = (t & 15) * 2;
    float px = pos[2 * n], py = pos[2 * n + 1];
    const float* hrow = h1 + (size_t)n * 32;
    float a[2], b[2];
#pragma unroll
    for (int i = 0; i < 2; ++i) {
        int c = c0 + i;
        float wx = w2a[32 * 32 + c], wy = w2a[33 * 32 + c];
        float s = fmaf(px, wx, fmaf(py, wy, b2a[c]));
#pragma unroll
        for (int k = 0; k < 32; ++k) s = fmaf(hrow[k], w2a[k * 32 + c], s);
        a[i] = s;
        b[i] = -(px * wx + py * wy);
    }
    Abf[t] = pack_bf16(a[0], a[1]);
    Bbf[t] = pack_bf16(b[0], b[1]);
    *(float2*)(h2 + 2 * (size_t)t) = make_float2(0.0f, 0.0f);
}

__global__ __launch_bounds__(256) void bucket_count_kernel(
    const int* __restrict__ ei, int* __restrict__ btot, int E, int NB)
{
    __shared__ int bh[NBMAX];
    int tid = threadIdx.x;
    for (int i = tid; i < NB; i += 256) bh[i] = 0;
    __syncthreads();
    const int* dsts = ei + E;
    int base0 = blockIdx.x * CHUNK;
    for (int i = tid * 4; i < CHUNK; i += 1024) {
        int e = base0 + i;
        if (e + 3 < E) {
            int4 d = *(const int4*)(dsts + e);
            atomicAdd(&bh[d.x >> BSHIFT], 1);
            atomicAdd(&bh[d.y >> BSHIFT], 1);
            atomicAdd(&bh[d.z >> BSHIFT], 1);
            atomicAdd(&bh[d.w >> BSHIFT], 1);
        } else {
            for (int k = e; k < E && k < e + 4; ++k)
                atomicAdd(&bh[dsts[k] >> BSHIFT], 1);
        }
    }
    __syncthreads();
    for (int i = tid; i < NB; i += 256)
        if (bh[i]) atomicAdd(btot + i, bh[i]);
}

// Multi-chunk exclusive scan (single block, 256/chunk with carry).
__global__ __launch_bounds__(256) void scan_bucket_kernel(
    const int* __restrict__ tot, int* __restrict__ base_,
    int* __restrict__ cur_, int NB)
{
    __shared__ int ws_[4], wo[4];
    __shared__ int carry_s;
    int tid = threadIdx.x, lane = tid & 63, wv = tid >> 6;
    if (tid == 0) carry_s = 0;
    __syncthreads();
    for (int c0 = 0; c0 < NB; c0 += 256) {
        int i = c0 + tid;
        int v = (i < NB) ? tot[i] : 0;
        int x = v;
#pragma unroll
        for (int d = 1; d < 64; d <<= 1) {
            int t = __shfl_up(x, d, 64);
            if (lane >= d) x += t;
        }
        if (lane == 63) ws_[wv] = x;
        __syncthreads();
        if (tid == 0) { int r = 0; for (int w = 0; w < 4; ++w) { wo[w] = r; r += ws_[w]; } ws_[0] = r; }
        __syncthreads();
        int carry = carry_s;
        int ex = carry + wo[wv] + x - v;
        if (i < NB) { base_[i] = ex; cur_[i] = ex; }
        int tot_c = ws_[0];
        __syncthreads();
        if (tid == 0) carry_s = carry + tot_c;
        __syncthreads();
    }
}

__global__ __launch_bounds__(256) void bucket_scatter_kernel(
    const int* __restrict__ ei, int* __restrict__ bcur,
    int* __restrict__ csr_tmp, int E, int NB)
{
    __shared__ int lh[NBMAX];
    __shared__ int lb[NBMAX];
    int tid = threadIdx.x;
    for (int i = tid; i < NB; i += 256) lh[i] = 0;
    __syncthreads();
    const int* dsts = ei + E;
    int base0 = blockIdx.x * CHUNK;
    for (int i = tid * 4; i < CHUNK; i += 1024) {
        int e = base0 + i;
        if (e + 3 < E) {
            int4 d = *(const int4*)(dsts + e);
            atomicAdd(&lh[d.x >> BSHIFT], 1);
            atomicAdd(&lh[d.y >> BSHIFT], 1);
            atomicAdd(&lh[d.z >> BSHIFT], 1);
            atomicAdd(&lh[d.w >> BSHIFT], 1);
        } else {
            for (int k = e; k < E && k < e + 4; ++k)
                atomicAdd(&lh[dsts[k] >> BSHIFT], 1);
        }
    }
    __syncthreads();
    for (int i = tid; i < NB; i += 256) {
        int c = lh[i];
        lb[i] = c ? atomicAdd(bcur + i, c) : 0;
    }
    __syncthreads();
    for (int i = tid; i < NB; i += 256) lh[i] = 0;
    __syncthreads();
    for (int i = tid * 4; i < CHUNK; i += 1024) {
        int e = base0 + i;
        if (e + 3 < E) {
            int4 s = *(const int4*)(ei + e);
            int4 d = *(const int4*)(dsts + e);
            int b, o;
            b = d.x >> BSHIFT; o = atomicAdd(&lh[b], 1);
            csr_tmp[lb[b] + o] = s.x | ((d.x & (BDSTS - 1)) << 20);
            b = d.y >> BSHIFT; o = atomicAdd(&lh[b], 1);
            csr_tmp[lb[b] + o] = s.y | ((d.y & (BDSTS - 1)) << 20);
            b = d.z >> BSHIFT; o = atomicAdd(&lh[b], 1);
            csr_tmp[lb[b] + o] = s.z | ((d.z & (BDSTS - 1)) << 20);
            b = d.w >> BSHIFT; o = atomicAdd(&lh[b], 1);
            csr_tmp[lb[b] + o] = s.w | ((d.w & (BDSTS - 1)) << 20);
        } else {
            for (int k = e; k < E && k < e + 4; ++k) {
                int dd = dsts[k];
                int b = dd >> BSHIFT;
                int o = atomicAdd(&lh[b], 1);
                csr_tmp[lb[b] + o] = ei[k] | ((dd & (BDSTS - 1)) << 20);
            }
        }
    }
}

// Count per-dst (128), pad to x16, self-reserve padded window via global
// cursor, place csr_src, emit tile_dst, fill pads. Scan fits one wave.
__global__ __launch_bounds__(256) void place_kernel(
    const int* __restrict__ csr_tmp, const int* __restrict__ bbase,
    const int* __restrict__ bcur, int* __restrict__ pcur,
    int* __restrict__ csr_src, int* __restrict__ tile_dst, int N)
{
    __shared__ int cnt[BDSTS], pre[BDSTS], cur[BDSTS];
    __shared__ int pstart_s;
    int b = blockIdx.x, tid = threadIdx.x;
    int d0 = b << BSHIFT;
    int start = bbase[b], end = bcur[b];
    if (tid < BDSTS) cnt[tid] = 0;
    __syncthreads();
    for (int i = start + tid; i < end; i += 256)
        atomicAdd(&cnt[csr_tmp[i] >> 20], 1);
    __syncthreads();
    if (tid < 64) {
        int lane = tid;
        int a0 = (cnt[2 * lane] + 15) & ~15;
        int a1 = (cnt[2 * lane + 1] + 15) & ~15;
        int s = a0 + a1;
        int x = s;
#pragma unroll
        for (int d = 1; d < 64; d <<= 1) {
            int t = __shfl_up(x, d, 64);
            if (lane >= d) x += t;
        }
        int total = __shfl(x, 63, 64);
        if (lane == 0) pstart_s = total ? atomicAdd(pcur, total) : 0;
        int ex = x - s;
        pre[2 * lane] = ex;      pre[2 * lane + 1] = ex + a0;
        cur[2 * lane] = ex;      cur[2 * lane + 1] = ex + a0;
    }
    __syncthreads();
    int pstart = pstart_s;
    for (int i = start + tid; i < end; i += 256) {
        int rec = csr_tmp[i];
        int p = atomicAdd(&cur[rec >> 20], 1);
        csr_src[pstart + p] = rec & 0xFFFFF;
    }
    if (tid < BDSTS) {
        int d = d0 + tid;
        if (d < N) {
            int c = cnt[tid], pc = (c + 15) & ~15;
            int base = pstart + pre[tid];
            for (int k = c; k < pc; ++k) csr_src[base + k] = -1;
            int tb = base >> 4, nt = pc >> 4;
            for (int k = 0; k < nt; ++k) tile_dst[tb + k] = d;
        }
    }
}

// MFMA edge layer over the PADDED slot list, bf16 A/B. Weight fragments
// pre-built in wfbuf (2 coalesced uint4 loads). Register-only reduce with
// wave-uniform full-tile fast path; filtered atomicMax at flush (fp32 bias).
__global__ __launch_bounds__(256, 4) void edge_layer_kernel(
    const int* __restrict__ csr_src, const int* __restrict__ tile_dst,
    const unsigned* __restrict__ Abf, const unsigned* __restrict__ Bbf,
    const unsigned* __restrict__ wf, const float* __restrict__ bias,
    unsigned int* __restrict__ hout)
{
    int tid = threadIdx.x;
    int lane = tid & 63;
    int wv = tid >> 6;
    int wbase = blockIdx.x * 256 + wv * 64;
    int m16 = lane & 15;
    int q = lane >> 4;
    int kq = q * 8;
    int ch = (lane < 16) ? m16 : (16 + m16);

    int td[4];
#pragma unroll
    for (int eg = 0; eg < 4; ++eg) td[eg] = tile_dst[(wbase >> 4) + eg];
    if (td[0] < 0 && td[1] < 0 && td[2] < 0 && td[3] < 0) return;

    short8 bf0 = __builtin_bit_cast(short8, *(const uint4v*)(wf + (size_t)lane * 4));
    short8 bf1 = __builtin_bit_cast(short8, *(const uint4v*)(wf + (size_t)(64 + lane) * 4));
    float myb = bias[ch];

    int src[4];
#pragma unroll
    for (int eg = 0; eg < 4; ++eg) {
        int sidx = wbase + eg * 16 + m16;
        src[eg] = (td[eg] >= 0) ? csr_src[sidx] : -1;
    }

    uint4v ua4[4], ub4[4];
#pragma unroll
    for (int eg = 0; eg < 4; ++eg) {
        int brow = (td[eg] >= 0) ? td[eg] : 0;
        int arow = (src[eg] >= 0) ? src[eg] : brow;
        ua4[eg] = *(const uint4v*)(Abf + (size_t)arow * 16 + (kq >> 1));
        ub4[eg] = *(const uint4v*)(Bbf + (size_t)brow * 16 + (kq >> 1));
    }

    f32x4 zero = {0.0f, 0.0f, 0.0f, 0.0f};
    float cv0 = NEG_BIG, cv1 = NEG_BIG;
    int cdst = -1;
#pragma unroll
    for (int eg = 0; eg < 4; ++eg) {
        unsigned long long bal = __ballot(src[eg] >= 0);
        uint4v pk;
#pragma unroll
        for (int d = 0; d < 4; ++d) {
            unsigned uad = ua4[eg][d], ubd = ub4[eg][d];
            float a0 = __uint_as_float(uad << 16);
            float a1 = __uint_as_float(uad & 0xFFFF0000u);
            float b0 = __uint_as_float(ubd << 16);
            float b1 = __uint_as_float(ubd & 0xFFFF0000u);
            float r0 = fmaxf(a0 + b0, 0.0f);
            float r1 = fmaxf(a1 + b1, 0.0f);
            pk[d] = __builtin_amdgcn_perm(__float_as_uint(r1),
                                          __float_as_uint(r0), 0x07060302u);
        }
        short8 af = __builtin_bit_cast(short8, pk);
        f32x4 d0 = __builtin_amdgcn_mfma_f32_16x16x32_bf16(af, bf0, zero, 0, 0, 0);
        f32x4 d1 = __builtin_amdgcn_mfma_f32_16x16x32_bf16(af, bf1, zero, 0, 0, 0);
        float v0, v1;
        if (bal == ~0ull) {          // full tile (wave-uniform): no masking
            v0 = fmaxf(fmaxf(d0[0], d0[1]), fmaxf(d0[2], d0[3]));
            v1 = fmaxf(fmaxf(d1[0], d1[1]), fmaxf(d1[2], d1[3]));
        } else {
            v0 = NEG_BIG; v1 = NEG_BIG;
#pragma unroll
            for (int r = 0; r < 4; ++r) {
                bool ok = (bal >> (q * 4 + r)) & 1ull;
                v0 = fmaxf(v0, ok ? d0[r] : NEG_BIG);
                v1 = fmaxf(v1, ok ? d1[r] : NEG_BIG);
            }
        }
        v0 = fmaxf(v0, __shfl_xor(v0, 16, 64));
        v0 = fmaxf(v0, __shfl_xor(v0, 32, 64));
        v1 = fmaxf(v1, __shfl_xor(v1, 16, 64));
        v1 = fmaxf(v1, __shfl_xor(v1, 32, 64));
        int d = td[eg];
        if (d != cdst) {
            if (cdst >= 0 && lane < 32) {
                float x = ((lane < 16) ? cv0 : cv1) + myb;
                if (x > 0.0f)
                    atomicMax(hout + (size_t)cdst * 32 + ch, __float_as_uint(x));
            }
            cdst = d; cv0 = v0; cv1 = v1;
        } else {
            cv0 = fmaxf(cv0, v0); cv1 = fmaxf(cv1, v1);
        }
    }
    if (cdst >= 0 && lane < 32) {
        float x = ((lane < 16) ? cv0 : cv1) + myb;
        if (x > 0.0f)
            atomicMax(hout + (size_t)cdst * 32 + ch, __float_as_uint(x));
    }
}

__global__ __launch_bounds__(256) void pool_kernel(
    const float* __restrict__ h2, const int* __restrict__ batch,
    unsigned int* __restrict__ gbuf, int N)
{
    int g = blockIdx.x, p = blockIdx.y;
    __shared__ int sbound[2];
    __shared__ float red[256];
    if (threadIdx.x < 2) {
        int target = g + (int)threadIdx.x;
        int lo = 0, hi = N;
        while (lo < hi) {
            int mid = (lo + hi) >> 1;
            if (batch[mid] < target) lo = mid + 1; else hi = mid;
        }
        sbound[threadIdx.x] = lo;
    }
    __syncthreads();
    int start = sbound[0], end = sbound[1];
    int c = threadIdx.x & 31, r = threadIdx.x >> 5;
    float mx = 0.0f;
    for (int n = start + p * 8 + r; n < end; n += 128)
        mx = fmaxf(mx, h2[(size_t)n * 32 + c]);
    red[threadIdx.x] = mx;
    __syncthreads();
    if (r < 4) red[threadIdx.x] = fmaxf(red[threadIdx.x], red[threadIdx.x + 128]);
    __syncthreads();
    if (r < 2) red[threadIdx.x] = fmaxf(red[threadIdx.x], red[threadIdx.x + 64]);
    __syncthreads();
    if (r == 0) {
        float v = fmaxf(red[threadIdx.x], red[threadIdx.x + 32]);
        if (v > 0.0f) atomicMax(gbuf + g * 32 + c, __float_as_uint(v));
    }
}

__global__ __launch_bounds__(192) void out_kernel(
    const float* __restrict__ gbuf, const float* __restrict__ wc,
    const float* __restrict__ bc, float* __restrict__ out, int G)
{
    int t = threadIdx.x;
    if (t >= G * 3) return;
    int g = t / 3, j = t % 3;
    float s = bc[j];
#pragma unroll
    for (int c = 0; c < 32; ++c)
        s = fmaf(gbuf[g * 32 + c], wc[c * 3 + j], s);
    out[t] = s;
}

extern "C" void kernel_launch(void* const* d_in, const int* in_sizes, int n_in,
                              void* d_out, int out_size, void* d_ws, size_t ws_size,
                              hipStream_t stream) {
    const float* pos = (const float*)d_in[0];
    const float* w1a = (const float*)d_in[1];
    const float* b1a = (const float*)d_in[2];
    const float* w1b = (const float*)d_in[3];
    const float* b1b = (const float*)d_in[4];
    const float* w2a = (const float*)d_in[5];
    const float* b2a = (const float*)d_in[6];
    const float* w2b = (const float*)d_in[7];
    const float* b2b = (const float*)d_in[8];
    const float* wc  = (const float*)d_in[9];
    const float* bc  = (const float*)d_in[10];
    const int* ei    = (const int*)d_in[11];
    const int* batch = (const int*)d_in[12];

    const int N = in_sizes[12];
    const int E = in_sizes[11] / 2;
    const int G = out_size / 3;
    const size_t NC = (size_t)N * 32;
    const int NB = (N + BDSTS - 1) >> BSHIFT;
    const int SMAX = (E + 15 * ((N < E) ? N : E) + 255) & ~255;  // padded bound
    const int TMAX = SMAX >> 4;

    int* btot    = (int*)d_ws;          // 1024
    int* pcur    = btot + 1024;         // 256 (1 used)
    int* bbase   = pcur + 256;          // 1024
    int* bcur    = bbase + 1024;        // 1024
    unsigned* wfbuf = (unsigned*)(bcur + 1024);     // 1024
    int* csr_src = (int*)(wfbuf + 1024);            // SMAX
    int* tile_dst = csr_src + SMAX;     // TMAX
    unsigned* Abf = (unsigned*)(tile_dst + TMAX);   // N*16
    unsigned* Bbf = Abf + (size_t)N * 16;           // N*16
    float* h1    = (float*)(Bbf + (size_t)N * 16);
    float* h2    = h1 + NC;
    float* gbuf  = h2 + NC;
    int* csr_tmp = (int*)Abf;           // aliases Abf+Bbf (N*32 ints >= E)

    int npBlocks = ((int)(N * 16) + 255) / 256;
    int ebBlocks = (E + CHUNK - 1) / CHUNK;
    int edBlocks = (SMAX + 255) / 256;

    hipMemsetAsync(btot, 0, 1280 * sizeof(int), stream);   // btot + pcur
    hipMemsetAsync(gbuf, 0, (size_t)G * 32 * sizeof(float), stream);
    hipMemsetAsync(tile_dst, 0xFF, (size_t)TMAX * sizeof(int), stream);

    wprep_kernel<<<1, 256, 0, stream>>>(w1b, w2b, wfbuf);
    bucket_count_kernel<<<ebBlocks, 256, 0, stream>>>(ei, btot, E, NB);
    scan_bucket_kernel<<<1, 256, 0, stream>>>(btot, bbase, bcur, NB);
    bucket_scatter_kernel<<<ebBlocks, 256, 0, stream>>>(ei, bcur, csr_tmp, E, NB);
    place_kernel<<<NB, 256, 0, stream>>>(csr_tmp, bbase, bcur, pcur,
                                         csr_src, tile_dst, N);

    pre1_kernel<<<npBlocks, 256, 0, stream>>>(pos, w1a, b1a, Abf, Bbf, h1, N);
    edge_layer_kernel<<<edBlocks, 256, 0, stream>>>(csr_src, tile_dst, Abf, Bbf,
                                                    wfbuf, b1b, (unsigned int*)h1);
    pre2_kernel<<<npBlocks, 256, 0, stream>>>(pos, h1, w2a, b2a, Abf, Bbf, h2, N);
    edge_layer_kernel<<<edBlocks, 256, 0, stream>>>(csr_src, tile_dst, Abf, Bbf,
                                                    wfbuf + 512, b2b,
                                                    (unsigned int*)h2);
    pool_kernel<<<dim3(G, 16), 256, 0, stream>>>(h2, batch,
                                                 (unsigned int*)gbuf, N);
    out_kernel<<<1, 192, 0, stream>>>(gbuf, wc, bc, (float*)d_out, G);
}

// Round 16
// 342.941 us; speedup vs baseline: 1.3305x; 1.0576x over previous
//
#include <hip/hip_runtime.h>
#include <hip/hip_bf16.h>

// Workspace layout (4B units):
// [btot:256][pcur:256][bbase:256][bcur:256][wfbuf:1024]
// [csr_src:SMAX][tile_dst:SMAX/16][Abf:N*16][Bbf:N*16][h1:N*32][h2:N*32][gbuf:G*32]
// A/B stored as packed bf16 (2 channels per uint). csr_tmp (E ints) ALIASES
// Abf+Bbf. Record = src(20b) | doff9(9b)<<20, doff9 = dst & 511 (coarse bucket
// = dst>>9). Place runs at 128-dst granularity: 4 fine blocks filter one
// coarse bucket by doff9>>7. csr_src pads = -1; unused tiles dst = -1.
// h1/h2/gbuf hold non-negative float bit patterns (global atomicMax on uint).

#define NEG_BIG (-3.0e38f)
#define BSHIFT 9                 // coarse scatter bucket: 512 dsts
#define NBMAX 256
#define CHUNKC 4096              // edges per block in count
#define CHUNKS 16384             // edges per block in scatter (64 rec/bucket)

typedef __attribute__((ext_vector_type(8))) short short8;
typedef __attribute__((ext_vector_type(4))) float f32x4;
typedef __attribute__((ext_vector_type(4))) unsigned uint4v;

__device__ __forceinline__ short bf16r(float f) {
    unsigned u = __float_as_uint(f);
    unsigned r = (u + 0x7FFFu + ((u >> 16) & 1u)) >> 16;
    return (short)r;
}
__device__ __forceinline__ unsigned pack_bf16(float lo, float hi) {
    return ((unsigned)(unsigned short)bf16r(lo)) |
           (((unsigned)(unsigned short)bf16r(hi)) << 16);
}

// Build per-lane W fragments for both layers. t: l=t>>7, frag=(t>>6)&1, lane=t&63.
__global__ __launch_bounds__(256) void wprep_kernel(
    const float* __restrict__ w1b, const float* __restrict__ w2b,
    unsigned* __restrict__ wfbuf)
{
    int t = threadIdx.x;
    int l = t >> 7, frag = (t >> 6) & 1, lane = t & 63;
    const float* w = l ? w2b : w1b;
    int m16 = lane & 15, kq = (lane >> 4) * 8;
    int cb = frag * 16 + m16;
    unsigned out[4];
#pragma unroll
    for (int p = 0; p < 4; ++p)
        out[p] = pack_bf16(w[(kq + 2 * p) * 32 + cb], w[(kq + 2 * p + 1) * 32 + cb]);
    *(uint4v*)(wfbuf + (size_t)t * 4) = (uint4v){out[0], out[1], out[2], out[3]};
}

// thread t in [0,N*16): n = t>>4, channels c0=2*(t&15), c1=c0+1.
__global__ __launch_bounds__(256) void pre1_kernel(
    const float* __restrict__ pos, const float* __restrict__ w1a,
    const float* __restrict__ b1a, unsigned* __restrict__ Abf,
    unsigned* __restrict__ Bbf, int N)
{
    int t = blockIdx.x * 256 + threadIdx.x;
    if (t >= N * 16) return;
    int n = t >> 4, c0 = (t & 15) * 2;
    float px = pos[2 * n], py = pos[2 * n + 1];
    float a[2], b[2];
#pragma unroll
    for (int i = 0; i < 2; ++i) {
        int c = c0 + i;
        float w0 = w1a[c], w1 = w1a[32 + c], w2 = w1a[64 + c], w3 = w1a[96 + c];
        a[i] = fmaf(px, w0 + w2, fmaf(py, w1 + w3, b1a[c]));
        b[i] = -(px * w2 + py * w3);
    }
    Abf[t] = pack_bf16(a[0], a[1]);
    Bbf[t] = pack_bf16(b[0], b[1]);
}

// One thread per node: hrow read once, 32 channels in registers.
__global__ __launch_bounds__(256) void pre2_kernel(
    const float* __restrict__ pos, const float* __restrict__ h1,
    const float* __restrict__ w2a, const float* __restrict__ b2a,
    unsigned* __restrict__ Abf, unsigned* __restrict__ Bbf, int N)
{
    int n = blockIdx.x * 256 + threadIdx.x;
    if (n >= N) return;
    float px = pos[2 * n], py = pos[2 * n + 1];
    const float4* hq = (const float4*)(h1 + (size_t)n * 32);
    float4 hv[8];
#pragma unroll
    for (int q = 0; q < 8; ++q) hv[q] = hq[q];
    float acc[32];
#pragma unroll
    for (int c = 0; c < 32; ++c)
        acc[c] = fmaf(px, w2a[1024 + c], fmaf(py, w2a[1056 + c], b2a[c]));
    const float* hf = (const float*)hv;
#pragma unroll
    for (int k = 0; k < 32; ++k) {
        float hk = hf[k];
#pragma unroll
        for (int c = 0; c < 32; ++c) acc[c] = fmaf(hk, w2a[k * 32 + c], acc[c]);
    }
    unsigned* Arow = Abf + (size_t)n * 16;
    unsigned* Brow = Bbf + (size_t)n * 16;
#pragma unroll
    for (int p = 0; p < 16; ++p) {
        Arow[p] = pack_bf16(acc[2 * p], acc[2 * p + 1]);
        Brow[p] = pack_bf16(-(px * w2a[1024 + 2 * p] + py * w2a[1056 + 2 * p]),
                            -(px * w2a[1025 + 2 * p] + py * w2a[1057 + 2 * p]));
    }
}

__global__ __launch_bounds__(256) void bucket_count_kernel(
    const int* __restrict__ ei, int* __restrict__ btot, int E, int NB)
{
    __shared__ int bh[NBMAX];
    int tid = threadIdx.x;
    for (int i = tid; i < NB; i += 256) bh[i] = 0;
    __syncthreads();
    const int* dsts = ei + E;
    int base0 = blockIdx.x * CHUNKC;
    for (int i = tid * 4; i < CHUNKC; i += 1024) {
        int e = base0 + i;
        if (e + 3 < E) {
            int4 d = *(const int4*)(dsts + e);
            atomicAdd(&bh[d.x >> BSHIFT], 1);
            atomicAdd(&bh[d.y >> BSHIFT], 1);
            atomicAdd(&bh[d.z >> BSHIFT], 1);
            atomicAdd(&bh[d.w >> BSHIFT], 1);
        } else {
            for (int k = e; k < E && k < e + 4; ++k)
                atomicAdd(&bh[dsts[k] >> BSHIFT], 1);
        }
    }
    __syncthreads();
    for (int i = tid; i < NB; i += 256)
        if (bh[i]) atomicAdd(btot + i, bh[i]);
}

// exclusive scan (<=256 entries, single block).
__global__ __launch_bounds__(256) void scan_bucket_kernel(
    const int* __restrict__ tot, int* __restrict__ base_,
    int* __restrict__ cur_, int NB)
{
    __shared__ int ws_[4], wo[4];
    int tid = threadIdx.x, lane = tid & 63, wv = tid >> 6;
    int v = (tid < NB) ? tot[tid] : 0;
    int x = v;
#pragma unroll
    for (int d = 1; d < 64; d <<= 1) {
        int t = __shfl_up(x, d, 64);
        if (lane >= d) x += t;
    }
    if (lane == 63) ws_[wv] = x;
    __syncthreads();
    if (tid == 0) { int r = 0; for (int w = 0; w < 4; ++w) { wo[w] = r; r += ws_[w]; } }
    __syncthreads();
    int ex = wo[wv] + x - v;
    if (tid < NB) { base_[tid] = ex; cur_[tid] = ex; }
}

__global__ __launch_bounds__(256) void bucket_scatter_kernel(
    const int* __restrict__ ei, int* __restrict__ bcur,
    int* __restrict__ csr_tmp, int E, int NB)
{
    __shared__ int lh[NBMAX];
    __shared__ int lb[NBMAX];
    int tid = threadIdx.x;
    for (int i = tid; i < NB; i += 256) lh[i] = 0;
    __syncthreads();
    const int* dsts = ei + E;
    int base0 = blockIdx.x * CHUNKS;
    for (int i = tid * 4; i < CHUNKS; i += 1024) {
        int e = base0 + i;
        if (e + 3 < E) {
            int4 d = *(const int4*)(dsts + e);
            atomicAdd(&lh[d.x >> BSHIFT], 1);
            atomicAdd(&lh[d.y >> BSHIFT], 1);
            atomicAdd(&lh[d.z >> BSHIFT], 1);
            atomicAdd(&lh[d.w >> BSHIFT], 1);
        } else {
            for (int k = e; k < E && k < e + 4; ++k)
                atomicAdd(&lh[dsts[k] >> BSHIFT], 1);
        }
    }
    __syncthreads();
    for (int i = tid; i < NB; i += 256) {
        int c = lh[i];
        lb[i] = c ? atomicAdd(bcur + i, c) : 0;
    }
    __syncthreads();
    for (int i = tid; i < NB; i += 256) lh[i] = 0;
    __syncthreads();
    for (int i = tid * 4; i < CHUNKS; i += 1024) {
        int e = base0 + i;
        if (e + 3 < E) {
            int4 s = *(const int4*)(ei + e);
            int4 d = *(const int4*)(dsts + e);
            int b, o;
            b = d.x >> BSHIFT; o = atomicAdd(&lh[b], 1);
            csr_tmp[lb[b] + o] = s.x | ((d.x & 511) << 20);
            b = d.y >> BSHIFT; o = atomicAdd(&lh[b], 1);
            csr_tmp[lb[b] + o] = s.y | ((d.y & 511) << 20);
            b = d.z >> BSHIFT; o = atomicAdd(&lh[b], 1);
            csr_tmp[lb[b] + o] = s.z | ((d.z & 511) << 20);
            b = d.w >> BSHIFT; o = atomicAdd(&lh[b], 1);
            csr_tmp[lb[b] + o] = s.w | ((d.w & 511) << 20);
        } else {
            for (int k = e; k < E && k < e + 4; ++k) {
                int dd = dsts[k];
                int b = dd >> BSHIFT;
                int o = atomicAdd(&lh[b], 1);
                csr_tmp[lb[b] + o] = ei[k] | ((dd & 511) << 20);
            }
        }
    }
}

// Fine-grained place: block fb = (coarse bucket fb>>2, quarter fb&3), owns
// dsts [fb*128, fb*128+128). Scans the coarse bucket's record range, filters
// by doff9>>7 == quarter. Self-reserves padded window via global cursor.
__global__ __launch_bounds__(256) void place_kernel(
    const int* __restrict__ csr_tmp, const int* __restrict__ bbase,
    const int* __restrict__ bcur, int* __restrict__ pcur,
    int* __restrict__ csr_src, int* __restrict__ tile_dst, int N)
{
    __shared__ int cnt[128], pre[128], cur[128];
    __shared__ int pstart_s;
    int fb = blockIdx.x, tid = threadIdx.x;
    int cb = fb >> 2, qq = fb & 3;
    int d0 = fb << 7;
    int start = bbase[cb], end = bcur[cb];
    if (tid < 128) cnt[tid] = 0;
    __syncthreads();
    for (int i = start + tid; i < end; i += 256) {
        int rec = csr_tmp[i];
        if (((rec >> 27) & 3) == qq) atomicAdd(&cnt[(rec >> 20) & 127], 1);
    }
    __syncthreads();
    if (tid < 64) {
        int lane = tid;
        int a0 = (cnt[2 * lane] + 15) & ~15;
        int a1 = (cnt[2 * lane + 1] + 15) & ~15;
        int s = a0 + a1;
        int x = s;
#pragma unroll
        for (int d = 1; d < 64; d <<= 1) {
            int t = __shfl_up(x, d, 64);
            if (lane >= d) x += t;
        }
        int total = __shfl(x, 63, 64);
        if (lane == 0) pstart_s = total ? atomicAdd(pcur, total) : 0;
        int ex = x - s;
        pre[2 * lane] = ex;      pre[2 * lane + 1] = ex + a0;
        cur[2 * lane] = ex;      cur[2 * lane + 1] = ex + a0;
    }
    __syncthreads();
    int pstart = pstart_s;
    for (int i = start + tid; i < end; i += 256) {
        int rec = csr_tmp[i];
        if (((rec >> 27) & 3) == qq) {
            int p = atomicAdd(&cur[(rec >> 20) & 127], 1);
            csr_src[pstart + p] = rec & 0xFFFFF;
        }
    }
    if (tid < 128) {
        int d = d0 + tid;
        if (d < N) {
            int c = cnt[tid], pc = (c + 15) & ~15;
            int base = pstart + pre[tid];
            for (int k = c; k < pc; ++k) csr_src[base + k] = -1;
            int tb = base >> 4, nt = pc >> 4;
            for (int k = 0; k < nt; ++k) tile_dst[tb + k] = d;
        }
    }
}

// MFMA edge layer over the PADDED slot list, bf16 A/B. Weight fragments
// pre-built in wfbuf. Register-only reduce with full-tile fast path;
// filtered atomicMax at flush (fp32 bias).
__global__ __launch_bounds__(256, 4) void edge_layer_kernel(
    const int* __restrict__ csr_src, const int* __restrict__ tile_dst,
    const unsigned* __restrict__ Abf, const unsigned* __restrict__ Bbf,
    const unsigned* __restrict__ wf, const float* __restrict__ bias,
    unsigned int* __restrict__ hout)
{
    int tid = threadIdx.x;
    int lane = tid & 63;
    int wv = tid >> 6;
    int wbase = blockIdx.x * 256 + wv * 64;
    int m16 = lane & 15;
    int q = lane >> 4;
    int kq = q * 8;
    int ch = (lane < 16) ? m16 : (16 + m16);

    int td[4];
#pragma unroll
    for (int eg = 0; eg < 4; ++eg) td[eg] = tile_dst[(wbase >> 4) + eg];
    if (td[0] < 0 && td[1] < 0 && td[2] < 0 && td[3] < 0) return;

    short8 bf0 = __builtin_bit_cast(short8, *(const uint4v*)(wf + (size_t)lane * 4));
    short8 bf1 = __builtin_bit_cast(short8, *(const uint4v*)(wf + (size_t)(64 + lane) * 4));
    float myb = bias[ch];

    int src[4];
#pragma unroll
    for (int eg = 0; eg < 4; ++eg) {
        int sidx = wbase + eg * 16 + m16;
        src[eg] = (td[eg] >= 0) ? csr_src[sidx] : -1;
    }

    uint4v ua4[4], ub4[4];
#pragma unroll
    for (int eg = 0; eg < 4; ++eg) {
        int brow = (td[eg] >= 0) ? td[eg] : 0;
        int arow = (src[eg] >= 0) ? src[eg] : brow;
        ua4[eg] = *(const uint4v*)(Abf + (size_t)arow * 16 + (kq >> 1));
        ub4[eg] = *(const uint4v*)(Bbf + (size_t)brow * 16 + (kq >> 1));
    }

    f32x4 zero = {0.0f, 0.0f, 0.0f, 0.0f};
    float cv0 = NEG_BIG, cv1 = NEG_BIG;
    int cdst = -1;
#pragma unroll
    for (int eg = 0; eg < 4; ++eg) {
        unsigned long long bal = __ballot(src[eg] >= 0);
        uint4v pk;
#pragma unroll
        for (int d = 0; d < 4; ++d) {
            unsigned uad = ua4[eg][d], ubd = ub4[eg][d];
            float a0 = __uint_as_float(uad << 16);
            float a1 = __uint_as_float(uad & 0xFFFF0000u);
            float b0 = __uint_as_float(ubd << 16);
            float b1 = __uint_as_float(ubd & 0xFFFF0000u);
            float r0 = fmaxf(a0 + b0, 0.0f);
            float r1 = fmaxf(a1 + b1, 0.0f);
            pk[d] = __builtin_amdgcn_perm(__float_as_uint(r1),
                                          __float_as_uint(r0), 0x07060302u);
        }
        short8 af = __builtin_bit_cast(short8, pk);
        f32x4 d0 = __builtin_amdgcn_mfma_f32_16x16x32_bf16(af, bf0, zero, 0, 0, 0);
        f32x4 d1 = __builtin_amdgcn_mfma_f32_16x16x32_bf16(af, bf1, zero, 0, 0, 0);
        float v0, v1;
        if (bal == ~0ull) {
            v0 = fmaxf(fmaxf(d0[0], d0[1]), fmaxf(d0[2], d0[3]));
            v1 = fmaxf(fmaxf(d1[0], d1[1]), fmaxf(d1[2], d1[3]));
        } else {
            v0 = NEG_BIG; v1 = NEG_BIG;
#pragma unroll
            for (int r = 0; r < 4; ++r) {
                bool ok = (bal >> (q * 4 + r)) & 1ull;
                v0 = fmaxf(v0, ok ? d0[r] : NEG_BIG);
                v1 = fmaxf(v1, ok ? d1[r] : NEG_BIG);
            }
        }
        v0 = fmaxf(v0, __shfl_xor(v0, 16, 64));
        v0 = fmaxf(v0, __shfl_xor(v0, 32, 64));
        v1 = fmaxf(v1, __shfl_xor(v1, 16, 64));
        v1 = fmaxf(v1, __shfl_xor(v1, 32, 64));
        int d = td[eg];
        if (d != cdst) {
            if (cdst >= 0 && lane < 32) {
                float x = ((lane < 16) ? cv0 : cv1) + myb;
                if (x > 0.0f)
                    atomicMax(hout + (size_t)cdst * 32 + ch, __float_as_uint(x));
            }
            cdst = d; cv0 = v0; cv1 = v1;
        } else {
            cv0 = fmaxf(cv0, v0); cv1 = fmaxf(cv1, v1);
        }
    }
    if (cdst >= 0 && lane < 32) {
        float x = ((lane < 16) ? cv0 : cv1) + myb;
        if (x > 0.0f)
            atomicMax(hout + (size_t)cdst * 32 + ch, __float_as_uint(x));
    }
}

__global__ __launch_bounds__(256) void pool_kernel(
    const float* __restrict__ h2, const int* __restrict__ batch,
    unsigned int* __restrict__ gbuf, int N)
{
    int g = blockIdx.x, p = blockIdx.y;
    __shared__ int sbound[2];
    __shared__ float red[256];
    if (threadIdx.x < 2) {
        int target = g + (int)threadIdx.x;
        int lo = 0, hi = N;
        while (lo < hi) {
            int mid = (lo + hi) >> 1;
            if (batch[mid] < target) lo = mid + 1; else hi = mid;
        }
        sbound[threadIdx.x] = lo;
    }
    __syncthreads();
    int start = sbound[0], end = sbound[1];
    int c = threadIdx.x & 31, r = threadIdx.x >> 5;
    float mx = 0.0f;
    for (int n = start + p * 8 + r; n < end; n += 128)
        mx = fmaxf(mx, h2[(size_t)n * 32 + c]);
    red[threadIdx.x] = mx;
    __syncthreads();
    if (r < 4) red[threadIdx.x] = fmaxf(red[threadIdx.x], red[threadIdx.x + 128]);
    __syncthreads();
    if (r < 2) red[threadIdx.x] = fmaxf(red[threadIdx.x], red[threadIdx.x + 64]);
    __syncthreads();
    if (r == 0) {
        float v = fmaxf(red[threadIdx.x], red[threadIdx.x + 32]);
        if (v > 0.0f) atomicMax(gbuf + g * 32 + c, __float_as_uint(v));
    }
}

__global__ __launch_bounds__(192) void out_kernel(
    const float* __restrict__ gbuf, const float* __restrict__ wc,
    const float* __restrict__ bc, float* __restrict__ out, int G)
{
    int t = threadIdx.x;
    if (t >= G * 3) return;
    int g = t / 3, j = t % 3;
    float s = bc[j];
#pragma unroll
    for (int c = 0; c < 32; ++c)
        s = fmaf(gbuf[g * 32 + c], wc[c * 3 + j], s);
    out[t] = s;
}

extern "C" void kernel_launch(void* const* d_in, const int* in_sizes, int n_in,
                              void* d_out, int out_size, void* d_ws, size_t ws_size,
                              hipStream_t stream) {
    const float* pos = (const float*)d_in[0];
    const float* w1a = (const float*)d_in[1];
    const float* b1a = (const float*)d_in[2];
    const float* w1b = (const float*)d_in[3];
    const float* b1b = (const float*)d_in[4];
    const float* w2a = (const float*)d_in[5];
    const float* b2a = (const float*)d_in[6];
    const float* w2b = (const float*)d_in[7];
    const float* b2b = (const float*)d_in[8];
    const float* wc  = (const float*)d_in[9];
    const float* bc  = (const float*)d_in[10];
    const int* ei    = (const int*)d_in[11];
    const int* batch = (const int*)d_in[12];

    const int N = in_sizes[12];
    const int E = in_sizes[11] / 2;
    const int G = out_size / 3;
    const size_t NC = (size_t)N * 32;
    const int NB = (N + 511) >> BSHIFT;             // coarse buckets
    const int NF = NB * 4;                          // fine place blocks
    const int SMAX = (E + 15 * ((N < E) ? N : E) + 255) & ~255;
    const int TMAX = SMAX >> 4;

    int* btot    = (int*)d_ws;          // 256
    int* pcur    = btot + 256;          // 256 (1 used)
    int* bbase   = pcur + 256;          // 256
    int* bcur    = bbase + 256;         // 256
    unsigned* wfbuf = (unsigned*)(bcur + 256);      // 1024
    int* csr_src = (int*)(wfbuf + 1024);            // SMAX
    int* tile_dst = csr_src + SMAX;     // TMAX
    unsigned* Abf = (unsigned*)(tile_dst + TMAX);   // N*16
    unsigned* Bbf = Abf + (size_t)N * 16;           // N*16
    float* h1    = (float*)(Bbf + (size_t)N * 16);
    float* h2    = h1 + NC;
    float* gbuf  = h2 + NC;
    int* csr_tmp = (int*)Abf;           // aliases Abf+Bbf (N*32 ints >= E)

    int npBlocks = ((int)(N * 16) + 255) / 256;
    int nBlocks  = (N + 255) / 256;
    int cBlocks  = (E + CHUNKC - 1) / CHUNKC;
    int sBlocks  = (E + CHUNKS - 1) / CHUNKS;
    int edBlocks = (SMAX + 255) / 256;

    hipMemsetAsync(btot, 0, 512 * sizeof(int), stream);   // btot + pcur
    hipMemsetAsync(gbuf, 0, (size_t)G * 32 * sizeof(float), stream);
    hipMemsetAsync(tile_dst, 0xFF, (size_t)TMAX * sizeof(int), stream);
    hipMemsetAsync(h1, 0, 2 * NC * sizeof(float), stream);  // h1 + h2

    wprep_kernel<<<1, 256, 0, stream>>>(w1b, w2b, wfbuf);
    bucket_count_kernel<<<cBlocks, 256, 0, stream>>>(ei, btot, E, NB);
    scan_bucket_kernel<<<1, 256, 0, stream>>>(btot, bbase, bcur, NB);
    bucket_scatter_kernel<<<sBlocks, 256, 0, stream>>>(ei, bcur, csr_tmp, E, NB);
    place_kernel<<<NF, 256, 0, stream>>>(csr_tmp, bbase, bcur, pcur,
                                         csr_src, tile_dst, N);

    pre1_kernel<<<npBlocks, 256, 0, stream>>>(pos, w1a, b1a, Abf, Bbf, N);
    edge_layer_kernel<<<edBlocks, 256, 0, stream>>>(csr_src, tile_dst, Abf, Bbf,
                                                    wfbuf, b1b, (unsigned int*)h1);
    pre2_kernel<<<nBlocks, 256, 0, stream>>>(pos, h1, w2a, b2a, Abf, Bbf, N);
    edge_layer_kernel<<<edBlocks, 256, 0, stream>>>(csr_src, tile_dst, Abf, Bbf,
                                                    wfbuf + 512, b2b,
                                                    (unsigned int*)h2);
    pool_kernel<<<dim3(G, 16), 256, 0, stream>>>(h2, batch,
                                                 (unsigned int*)gbuf, N);
    out_kernel<<<1, 192, 0, stream>>>(gbuf, wc, bc, (float*)d_out, G);
}

// Round 17
// 314.154 us; speedup vs baseline: 1.4524x; 1.0916x over previous
//
#include <hip/hip_runtime.h>
#include <hip/hip_bf16.h>

// Workspace layout (4B units):
// [btot:256][pcur:256][bbase:256][bcur:256][wfbuf:1024]
// [csr_src:SMAX][tile_dst:SMAX/16][Abf:N*16][Bbf:N*16][h1:N*32][h2:N*32][gbuf:G*32]
// A/B stored as packed bf16 (2 channels per uint). csr_tmp (E ints) ALIASES
// Abf+Bbf. Record = src(20b) | doff9(9b)<<20, doff9 = dst & 511 (coarse bucket
// = dst>>9). Place: one 1024-thread block per coarse bucket, records cached in
// 64KB LDS (global read once). csr_src pads = -1; unused tiles dst = -1.
// h1/h2/gbuf hold non-negative float bit patterns (global atomicMax on uint).

#define NEG_BIG (-3.0e38f)
#define BSHIFT 9                 // coarse scatter bucket: 512 dsts
#define NBMAX 256
#define CHUNKC 4096              // edges per block in count
#define CHUNKS 16384             // edges per block in scatter (64 rec/bucket)
#define RCAP 16384               // LDS record cache per place block (64 KB)

typedef __attribute__((ext_vector_type(8))) short short8;
typedef __attribute__((ext_vector_type(4))) float f32x4;
typedef __attribute__((ext_vector_type(4))) unsigned uint4v;

__device__ __forceinline__ short bf16r(float f) {
    unsigned u = __float_as_uint(f);
    unsigned r = (u + 0x7FFFu + ((u >> 16) & 1u)) >> 16;
    return (short)r;
}
__device__ __forceinline__ unsigned pack_bf16(float lo, float hi) {
    return ((unsigned)(unsigned short)bf16r(lo)) |
           (((unsigned)(unsigned short)bf16r(hi)) << 16);
}

// Build per-lane W fragments for both layers. t: l=t>>7, frag=(t>>6)&1, lane=t&63.
__global__ __launch_bounds__(256) void wprep_kernel(
    const float* __restrict__ w1b, const float* __restrict__ w2b,
    unsigned* __restrict__ wfbuf)
{
    int t = threadIdx.x;
    int l = t >> 7, frag = (t >> 6) & 1, lane = t & 63;
    const float* w = l ? w2b : w1b;
    int m16 = lane & 15, kq = (lane >> 4) * 8;
    int cb = frag * 16 + m16;
    unsigned out[4];
#pragma unroll
    for (int p = 0; p < 4; ++p)
        out[p] = pack_bf16(w[(kq + 2 * p) * 32 + cb], w[(kq + 2 * p + 1) * 32 + cb]);
    *(uint4v*)(wfbuf + (size_t)t * 4) = (uint4v){out[0], out[1], out[2], out[3]};
}

// thread t in [0,N*16): n = t>>4, channels c0=2*(t&15), c1=c0+1.
__global__ __launch_bounds__(256) void pre1_kernel(
    const float* __restrict__ pos, const float* __restrict__ w1a,
    const float* __restrict__ b1a, unsigned* __restrict__ Abf,
    unsigned* __restrict__ Bbf, int N)
{
    int t = blockIdx.x * 256 + threadIdx.x;
    if (t >= N * 16) return;
    int n = t >> 4, c0 = (t & 15) * 2;
    float px = pos[2 * n], py = pos[2 * n + 1];
    float a[2], b[2];
#pragma unroll
    for (int i = 0; i < 2; ++i) {
        int c = c0 + i;
        float w0 = w1a[c], w1 = w1a[32 + c], w2 = w1a[64 + c], w3 = w1a[96 + c];
        a[i] = fmaf(px, w0 + w2, fmaf(py, w1 + w3, b1a[c]));
        b[i] = -(px * w2 + py * w3);
    }
    Abf[t] = pack_bf16(a[0], a[1]);
    Bbf[t] = pack_bf16(b[0], b[1]);
}

// One thread per node: hrow read once, 32 channels in registers.
__global__ __launch_bounds__(256) void pre2_kernel(
    const float* __restrict__ pos, const float* __restrict__ h1,
    const float* __restrict__ w2a, const float* __restrict__ b2a,
    unsigned* __restrict__ Abf, unsigned* __restrict__ Bbf, int N)
{
    int n = blockIdx.x * 256 + threadIdx.x;
    if (n >= N) return;
    float px = pos[2 * n], py = pos[2 * n + 1];
    const float4* hq = (const float4*)(h1 + (size_t)n * 32);
    float4 hv[8];
#pragma unroll
    for (int q = 0; q < 8; ++q) hv[q] = hq[q];
    float acc[32];
#pragma unroll
    for (int c = 0; c < 32; ++c)
        acc[c] = fmaf(px, w2a[1024 + c], fmaf(py, w2a[1056 + c], b2a[c]));
    const float* hf = (const float*)hv;
#pragma unroll
    for (int k = 0; k < 32; ++k) {
        float hk = hf[k];
#pragma unroll
        for (int c = 0; c < 32; ++c) acc[c] = fmaf(hk, w2a[k * 32 + c], acc[c]);
    }
    unsigned* Arow = Abf + (size_t)n * 16;
    unsigned* Brow = Bbf + (size_t)n * 16;
#pragma unroll
    for (int p = 0; p < 16; ++p) {
        Arow[p] = pack_bf16(acc[2 * p], acc[2 * p + 1]);
        Brow[p] = pack_bf16(-(px * w2a[1024 + 2 * p] + py * w2a[1056 + 2 * p]),
                            -(px * w2a[1025 + 2 * p] + py * w2a[1057 + 2 * p]));
    }
}

__global__ __launch_bounds__(256) void bucket_count_kernel(
    const int* __restrict__ ei, int* __restrict__ btot, int E, int NB)
{
    __shared__ int bh[NBMAX];
    int tid = threadIdx.x;
    for (int i = tid; i < NB; i += 256) bh[i] = 0;
    __syncthreads();
    const int* dsts = ei + E;
    int base0 = blockIdx.x * CHUNKC;
    for (int i = tid * 4; i < CHUNKC; i += 1024) {
        int e = base0 + i;
        if (e + 3 < E) {
            int4 d = *(const int4*)(dsts + e);
            atomicAdd(&bh[d.x >> BSHIFT], 1);
            atomicAdd(&bh[d.y >> BSHIFT], 1);
            atomicAdd(&bh[d.z >> BSHIFT], 1);
            atomicAdd(&bh[d.w >> BSHIFT], 1);
        } else {
            for (int k = e; k < E && k < e + 4; ++k)
                atomicAdd(&bh[dsts[k] >> BSHIFT], 1);
        }
    }
    __syncthreads();
    for (int i = tid; i < NB; i += 256)
        if (bh[i]) atomicAdd(btot + i, bh[i]);
}

// exclusive scan (<=256 entries, single block).
__global__ __launch_bounds__(256) void scan_bucket_kernel(
    const int* __restrict__ tot, int* __restrict__ base_,
    int* __restrict__ cur_, int NB)
{
    __shared__ int ws_[4], wo[4];
    int tid = threadIdx.x, lane = tid & 63, wv = tid >> 6;
    int v = (tid < NB) ? tot[tid] : 0;
    int x = v;
#pragma unroll
    for (int d = 1; d < 64; d <<= 1) {
        int t = __shfl_up(x, d, 64);
        if (lane >= d) x += t;
    }
    if (lane == 63) ws_[wv] = x;
    __syncthreads();
    if (tid == 0) { int r = 0; for (int w = 0; w < 4; ++w) { wo[w] = r; r += ws_[w]; } }
    __syncthreads();
    int ex = wo[wv] + x - v;
    if (tid < NB) { base_[tid] = ex; cur_[tid] = ex; }
}

__global__ __launch_bounds__(256) void bucket_scatter_kernel(
    const int* __restrict__ ei, int* __restrict__ bcur,
    int* __restrict__ csr_tmp, int E, int NB)
{
    __shared__ int lh[NBMAX];
    __shared__ int lb[NBMAX];
    int tid = threadIdx.x;
    for (int i = tid; i < NB; i += 256) lh[i] = 0;
    __syncthreads();
    const int* dsts = ei + E;
    int base0 = blockIdx.x * CHUNKS;
    for (int i = tid * 4; i < CHUNKS; i += 1024) {
        int e = base0 + i;
        if (e + 3 < E) {
            int4 d = *(const int4*)(dsts + e);
            atomicAdd(&lh[d.x >> BSHIFT], 1);
            atomicAdd(&lh[d.y >> BSHIFT], 1);
            atomicAdd(&lh[d.z >> BSHIFT], 1);
            atomicAdd(&lh[d.w >> BSHIFT], 1);
        } else {
            for (int k = e; k < E && k < e + 4; ++k)
                atomicAdd(&lh[dsts[k] >> BSHIFT], 1);
        }
    }
    __syncthreads();
    for (int i = tid; i < NB; i += 256) {
        int c = lh[i];
        lb[i] = c ? atomicAdd(bcur + i, c) : 0;
    }
    __syncthreads();
    for (int i = tid; i < NB; i += 256) lh[i] = 0;
    __syncthreads();
    for (int i = tid * 4; i < CHUNKS; i += 1024) {
        int e = base0 + i;
        if (e + 3 < E) {
            int4 s = *(const int4*)(ei + e);
            int4 d = *(const int4*)(dsts + e);
            int b, o;
            b = d.x >> BSHIFT; o = atomicAdd(&lh[b], 1);
            csr_tmp[lb[b] + o] = s.x | ((d.x & 511) << 20);
            b = d.y >> BSHIFT; o = atomicAdd(&lh[b], 1);
            csr_tmp[lb[b] + o] = s.y | ((d.y & 511) << 20);
            b = d.z >> BSHIFT; o = atomicAdd(&lh[b], 1);
            csr_tmp[lb[b] + o] = s.z | ((d.z & 511) << 20);
            b = d.w >> BSHIFT; o = atomicAdd(&lh[b], 1);
            csr_tmp[lb[b] + o] = s.w | ((d.w & 511) << 20);
        } else {
            for (int k = e; k < E && k < e + 4; ++k) {
                int dd = dsts[k];
                int b = dd >> BSHIFT;
                int o = atomicAdd(&lh[b], 1);
                csr_tmp[lb[b] + o] = ei[k] | ((dd & 511) << 20);
            }
        }
    }
}

// Place: one 1024-thread block per coarse bucket. Pass A streams the bucket's
// records from global ONCE into a 64KB LDS cache while counting per-dst (512).
// One-wave scan (64 lanes x 8) -> padded offsets; self-reserve window via
// global cursor. Pass B re-reads from LDS (global fallback past RCAP),
// places csr_src, fills pads + tile_dst.
__global__ __launch_bounds__(1024) void place_kernel(
    const int* __restrict__ csr_tmp, const int* __restrict__ bbase,
    const int* __restrict__ bcur, int* __restrict__ pcur,
    int* __restrict__ csr_src, int* __restrict__ tile_dst, int N)
{
    __shared__ int rec_cache[RCAP];
    __shared__ int cnt[512], pre[512], cur[512];
    __shared__ int pstart_s;
    int b = blockIdx.x, tid = threadIdx.x;
    int d0 = b << BSHIFT;
    int start = bbase[b], end = bcur[b];
    int len = end - start;
    if (tid < 512) cnt[tid] = 0;
    __syncthreads();
    for (int i = tid; i < len; i += 1024) {
        int rec = csr_tmp[start + i];
        if (i < RCAP) rec_cache[i] = rec;
        atomicAdd(&cnt[rec >> 20], 1);
    }
    __syncthreads();
    if (tid < 64) {
        int lane = tid;
        int a[8];
        int s = 0;
#pragma unroll
        for (int j = 0; j < 8; ++j) {
            a[j] = (cnt[8 * lane + j] + 15) & ~15;
            s += a[j];
        }
        int x = s;
#pragma unroll
        for (int d = 1; d < 64; d <<= 1) {
            int t = __shfl_up(x, d, 64);
            if (lane >= d) x += t;
        }
        int total = __shfl(x, 63, 64);
        if (lane == 0) pstart_s = total ? atomicAdd(pcur, total) : 0;
        int run = x - s;
#pragma unroll
        for (int j = 0; j < 8; ++j) {
            pre[8 * lane + j] = run;
            cur[8 * lane + j] = run;
            run += a[j];
        }
    }
    __syncthreads();
    int pstart = pstart_s;
    for (int i = tid; i < len; i += 1024) {
        int rec = (i < RCAP) ? rec_cache[i] : csr_tmp[start + i];
        int p = atomicAdd(&cur[rec >> 20], 1);
        csr_src[pstart + p] = rec & 0xFFFFF;
    }
    if (tid < 512) {
        int d = d0 + tid;
        if (d < N) {
            int c = cnt[tid], pc = (c + 15) & ~15;
            int base = pstart + pre[tid];
            for (int k = c; k < pc; ++k) csr_src[base + k] = -1;
            int tb = base >> 4, nt = pc >> 4;
            for (int k = 0; k < nt; ++k) tile_dst[tb + k] = d;
        }
    }
}

// MFMA edge layer over the PADDED slot list, bf16 A/B. Weight fragments
// pre-built in wfbuf. Register-only reduce with full-tile fast path;
// filtered atomicMax at flush (fp32 bias).
__global__ __launch_bounds__(256, 4) void edge_layer_kernel(
    const int* __restrict__ csr_src, const int* __restrict__ tile_dst,
    const unsigned* __restrict__ Abf, const unsigned* __restrict__ Bbf,
    const unsigned* __restrict__ wf, const float* __restrict__ bias,
    unsigned int* __restrict__ hout)
{
    int tid = threadIdx.x;
    int lane = tid & 63;
    int wv = tid >> 6;
    int wbase = blockIdx.x * 256 + wv * 64;
    int m16 = lane & 15;
    int q = lane >> 4;
    int kq = q * 8;
    int ch = (lane < 16) ? m16 : (16 + m16);

    int td[4];
#pragma unroll
    for (int eg = 0; eg < 4; ++eg) td[eg] = tile_dst[(wbase >> 4) + eg];
    if (td[0] < 0 && td[1] < 0 && td[2] < 0 && td[3] < 0) return;

    short8 bf0 = __builtin_bit_cast(short8, *(const uint4v*)(wf + (size_t)lane * 4));
    short8 bf1 = __builtin_bit_cast(short8, *(const uint4v*)(wf + (size_t)(64 + lane) * 4));
    float myb = bias[ch];

    int src[4];
#pragma unroll
    for (int eg = 0; eg < 4; ++eg) {
        int sidx = wbase + eg * 16 + m16;
        src[eg] = (td[eg] >= 0) ? csr_src[sidx] : -1;
    }

    uint4v ua4[4], ub4[4];
#pragma unroll
    for (int eg = 0; eg < 4; ++eg) {
        int brow = (td[eg] >= 0) ? td[eg] : 0;
        int arow = (src[eg] >= 0) ? src[eg] : brow;
        ua4[eg] = *(const uint4v*)(Abf + (size_t)arow * 16 + (kq >> 1));
        ub4[eg] = *(const uint4v*)(Bbf + (size_t)brow * 16 + (kq >> 1));
    }

    f32x4 zero = {0.0f, 0.0f, 0.0f, 0.0f};
    float cv0 = NEG_BIG, cv1 = NEG_BIG;
    int cdst = -1;
#pragma unroll
    for (int eg = 0; eg < 4; ++eg) {
        unsigned long long bal = __ballot(src[eg] >= 0);
        uint4v pk;
#pragma unroll
        for (int d = 0; d < 4; ++d) {
            unsigned uad = ua4[eg][d], ubd = ub4[eg][d];
            float a0 = __uint_as_float(uad << 16);
            float a1 = __uint_as_float(uad & 0xFFFF0000u);
            float b0 = __uint_as_float(ubd << 16);
            float b1 = __uint_as_float(ubd & 0xFFFF0000u);
            float r0 = fmaxf(a0 + b0, 0.0f);
            float r1 = fmaxf(a1 + b1, 0.0f);
            pk[d] = __builtin_amdgcn_perm(__float_as_uint(r1),
                                          __float_as_uint(r0), 0x07060302u);
        }
        short8 af = __builtin_bit_cast(short8, pk);
        f32x4 d0 = __builtin_amdgcn_mfma_f32_16x16x32_bf16(af, bf0, zero, 0, 0, 0);
        f32x4 d1 = __builtin_amdgcn_mfma_f32_16x16x32_bf16(af, bf1, zero, 0, 0, 0);
        float v0, v1;
        if (bal == ~0ull) {
            v0 = fmaxf(fmaxf(d0[0], d0[1]), fmaxf(d0[2], d0[3]));
            v1 = fmaxf(fmaxf(d1[0], d1[1]), fmaxf(d1[2], d1[3]));
        } else {
            v0 = NEG_BIG; v1 = NEG_BIG;
#pragma unroll
            for (int r = 0; r < 4; ++r) {
                bool ok = (bal >> (q * 4 + r)) & 1ull;
                v0 = fmaxf(v0, ok ? d0[r] : NEG_BIG);
                v1 = fmaxf(v1, ok ? d1[r] : NEG_BIG);
            }
        }
        v0 = fmaxf(v0, __shfl_xor(v0, 16, 64));
        v0 = fmaxf(v0, __shfl_xor(v0, 32, 64));
        v1 = fmaxf(v1, __shfl_xor(v1, 16, 64));
        v1 = fmaxf(v1, __shfl_xor(v1, 32, 64));
        int d = td[eg];
        if (d != cdst) {
            if (cdst >= 0 && lane < 32) {
                float x = ((lane < 16) ? cv0 : cv1) + myb;
                if (x > 0.0f)
                    atomicMax(hout + (size_t)cdst * 32 + ch, __float_as_uint(x));
            }
            cdst = d; cv0 = v0; cv1 = v1;
        } else {
            cv0 = fmaxf(cv0, v0); cv1 = fmaxf(cv1, v1);
        }
    }
    if (cdst >= 0 && lane < 32) {
        float x = ((lane < 16) ? cv0 : cv1) + myb;
        if (x > 0.0f)
            atomicMax(hout + (size_t)cdst * 32 + ch, __float_as_uint(x));
    }
}

__global__ __launch_bounds__(256) void pool_kernel(
    const float* __restrict__ h2, const int* __restrict__ batch,
    unsigned int* __restrict__ gbuf, int N)
{
    int g = blockIdx.x, p = blockIdx.y;
    __shared__ int sbound[2];
    __shared__ float red[256];
    if (threadIdx.x < 2) {
        int target = g + (int)threadIdx.x;
        int lo = 0, hi = N;
        while (lo < hi) {
            int mid = (lo + hi) >> 1;
            if (batch[mid] < target) lo = mid + 1; else hi = mid;
        }
        sbound[threadIdx.x] = lo;
    }
    __syncthreads();
    int start = sbound[0], end = sbound[1];
    int c = threadIdx.x & 31, r = threadIdx.x >> 5;
    float mx = 0.0f;
    for (int n = start + p * 8 + r; n < end; n += 128)
        mx = fmaxf(mx, h2[(size_t)n * 32 + c]);
    red[threadIdx.x] = mx;
    __syncthreads();
    if (r < 4) red[threadIdx.x] = fmaxf(red[threadIdx.x], red[threadIdx.x + 128]);
    __syncthreads();
    if (r < 2) red[threadIdx.x] = fmaxf(red[threadIdx.x], red[threadIdx.x + 64]);
    __syncthreads();
    if (r == 0) {
        float v = fmaxf(red[threadIdx.x], red[threadIdx.x + 32]);
        if (v > 0.0f) atomicMax(gbuf + g * 32 + c, __float_as_uint(v));
    }
}

__global__ __launch_bounds__(192) void out_kernel(
    const float* __restrict__ gbuf, const float* __restrict__ wc,
    const float* __restrict__ bc, float* __restrict__ out, int G)
{
    int t = threadIdx.x;
    if (t >= G * 3) return;
    int g = t / 3, j = t % 3;
    float s = bc[j];
#pragma unroll
    for (int c = 0; c < 32; ++c)
        s = fmaf(gbuf[g * 32 + c], wc[c * 3 + j], s);
    out[t] = s;
}

extern "C" void kernel_launch(void* const* d_in, const int* in_sizes, int n_in,
                              void* d_out, int out_size, void* d_ws, size_t ws_size,
                              hipStream_t stream) {
    const float* pos = (const float*)d_in[0];
    const float* w1a = (const float*)d_in[1];
    const float* b1a = (const float*)d_in[2];
    const float* w1b = (const float*)d_in[3];
    const float* b1b = (const float*)d_in[4];
    const float* w2a = (const float*)d_in[5];
    const float* b2a = (const float*)d_in[6];
    const float* w2b = (const float*)d_in[7];
    const float* b2b = (const float*)d_in[8];
    const float* wc  = (const float*)d_in[9];
    const float* bc  = (const float*)d_in[10];
    const int* ei    = (const int*)d_in[11];
    const int* batch = (const int*)d_in[12];

    const int N = in_sizes[12];
    const int E = in_sizes[11] / 2;
    const int G = out_size / 3;
    const size_t NC = (size_t)N * 32;
    const int NB = (N + 511) >> BSHIFT;             // coarse buckets
    const int SMAX = (E + 15 * ((N < E) ? N : E) + 255) & ~255;
    const int TMAX = SMAX >> 4;

    int* btot    = (int*)d_ws;          // 256
    int* pcur    = btot + 256;          // 256 (1 used)
    int* bbase   = pcur + 256;          // 256
    int* bcur    = bbase + 256;         // 256
    unsigned* wfbuf = (unsigned*)(bcur + 256);      // 1024
    int* csr_src = (int*)(wfbuf + 1024);            // SMAX
    int* tile_dst = csr_src + SMAX;     // TMAX
    unsigned* Abf = (unsigned*)(tile_dst + TMAX);   // N*16
    unsigned* Bbf = Abf + (size_t)N * 16;           // N*16
    float* h1    = (float*)(Bbf + (size_t)N * 16);
    float* h2    = h1 + NC;
    float* gbuf  = h2 + NC;
    int* csr_tmp = (int*)Abf;           // aliases Abf+Bbf (N*32 ints >= E)

    int npBlocks = ((int)(N * 16) + 255) / 256;
    int nBlocks  = (N + 255) / 256;
    int cBlocks  = (E + CHUNKC - 1) / CHUNKC;
    int sBlocks  = (E + CHUNKS - 1) / CHUNKS;
    int edBlocks = (SMAX + 255) / 256;

    hipMemsetAsync(btot, 0, 512 * sizeof(int), stream);   // btot + pcur
    hipMemsetAsync(gbuf, 0, (size_t)G * 32 * sizeof(float), stream);
    hipMemsetAsync(tile_dst, 0xFF, (size_t)TMAX * sizeof(int), stream);
    hipMemsetAsync(h1, 0, 2 * NC * sizeof(float), stream);  // h1 + h2

    wprep_kernel<<<1, 256, 0, stream>>>(w1b, w2b, wfbuf);
    bucket_count_kernel<<<cBlocks, 256, 0, stream>>>(ei, btot, E, NB);
    scan_bucket_kernel<<<1, 256, 0, stream>>>(btot, bbase, bcur, NB);
    bucket_scatter_kernel<<<sBlocks, 256, 0, stream>>>(ei, bcur, csr_tmp, E, NB);
    place_kernel<<<NB, 1024, 0, stream>>>(csr_tmp, bbase, bcur, pcur,
                                          csr_src, tile_dst, N);

    pre1_kernel<<<npBlocks, 256, 0, stream>>>(pos, w1a, b1a, Abf, Bbf, N);
    edge_layer_kernel<<<edBlocks, 256, 0, stream>>>(csr_src, tile_dst, Abf, Bbf,
                                                    wfbuf, b1b, (unsigned int*)h1);
    pre2_kernel<<<nBlocks, 256, 0, stream>>>(pos, h1, w2a, b2a, Abf, Bbf, N);
    edge_layer_kernel<<<edBlocks, 256, 0, stream>>>(csr_src, tile_dst, Abf, Bbf,
                                                    wfbuf + 512, b2b,
                                                    (unsigned int*)h2);
    pool_kernel<<<dim3(G, 16), 256, 0, stream>>>(h2, batch,
                                                 (unsigned int*)gbuf, N);
    out_kernel<<<1, 192, 0, stream>>>(gbuf, wc, bc, (float*)d_out, G);
}

// Round 18
// 284.702 us; speedup vs baseline: 1.6026x; 1.1034x over previous
//
#include <hip/hip_runtime.h>
#include <hip/hip_bf16.h>

// Workspace layout (4B units):
// [bcnt:256][pcur:256][gbuf:G*32][wfbuf:1024][csr_src:SMAX][tile_dst:SMAX/16]
// [Abf:N*16][Bbf:N*16][h1:N*32][h2:N*32]
// A/B stored as packed bf16 (2 channels per uint). csr_tmp ALIASES h1+h2
// (6.4M ints >= NB*CAP; h zeroed AFTER place). Record = src(20b)|doff9<<20.
// Fixed bucket windows: bucket b owns csr_tmp[b*CAP, b*CAP+CAP); bcnt[b] is
// its append count (no count/scan pass). csr_src pads = -1; unused tiles
// dst = -1. h1/h2/gbuf hold non-negative float bit patterns (atomicMax uint).

#define NEG_BIG (-3.0e38f)
#define BSHIFT 9                 // bucket: 512 dsts
#define NBMAX 256
#define CHUNKS 16384             // edges per scatter block
#define CAP 32512                // records per bucket window (mean+127 sigma)
#define RCAP 16384               // LDS record cache per place block (64 KB)

typedef __attribute__((ext_vector_type(8))) short short8;
typedef __attribute__((ext_vector_type(4))) float f32x4;
typedef __attribute__((ext_vector_type(4))) unsigned uint4v;

__device__ __forceinline__ short bf16r(float f) {
    unsigned u = __float_as_uint(f);
    unsigned r = (u + 0x7FFFu + ((u >> 16) & 1u)) >> 16;
    return (short)r;
}
__device__ __forceinline__ unsigned pack_bf16(float lo, float hi) {
    return ((unsigned)(unsigned short)bf16r(lo)) |
           (((unsigned)(unsigned short)bf16r(hi)) << 16);
}

// Build per-lane W fragments for both layers. t: l=t>>7, frag=(t>>6)&1, lane=t&63.
__global__ __launch_bounds__(256) void wprep_kernel(
    const float* __restrict__ w1b, const float* __restrict__ w2b,
    unsigned* __restrict__ wfbuf)
{
    int t = threadIdx.x;
    int l = t >> 7, frag = (t >> 6) & 1, lane = t & 63;
    const float* w = l ? w2b : w1b;
    int m16 = lane & 15, kq = (lane >> 4) * 8;
    int cb = frag * 16 + m16;
    unsigned out[4];
#pragma unroll
    for (int p = 0; p < 4; ++p)
        out[p] = pack_bf16(w[(kq + 2 * p) * 32 + cb], w[(kq + 2 * p + 1) * 32 + cb]);
    *(uint4v*)(wfbuf + (size_t)t * 4) = (uint4v){out[0], out[1], out[2], out[3]};
}

// thread t in [0,N*16): n = t>>4, channels c0=2*(t&15), c1=c0+1.
__global__ __launch_bounds__(256) void pre1_kernel(
    const float* __restrict__ pos, const float* __restrict__ w1a,
    const float* __restrict__ b1a, unsigned* __restrict__ Abf,
    unsigned* __restrict__ Bbf, int N)
{
    int t = blockIdx.x * 256 + threadIdx.x;
    if (t >= N * 16) return;
    int n = t >> 4, c0 = (t & 15) * 2;
    float px = pos[2 * n], py = pos[2 * n + 1];
    float a[2], b[2];
#pragma unroll
    for (int i = 0; i < 2; ++i) {
        int c = c0 + i;
        float w0 = w1a[c], w1 = w1a[32 + c], w2 = w1a[64 + c], w3 = w1a[96 + c];
        a[i] = fmaf(px, w0 + w2, fmaf(py, w1 + w3, b1a[c]));
        b[i] = -(px * w2 + py * w3);
    }
    Abf[t] = pack_bf16(a[0], a[1]);
    Bbf[t] = pack_bf16(b[0], b[1]);
}

// One thread per node: hrow read once, 32 channels in registers.
__global__ __launch_bounds__(256) void pre2_kernel(
    const float* __restrict__ pos, const float* __restrict__ h1,
    const float* __restrict__ w2a, const float* __restrict__ b2a,
    unsigned* __restrict__ Abf, unsigned* __restrict__ Bbf, int N)
{
    int n = blockIdx.x * 256 + threadIdx.x;
    if (n >= N) return;
    float px = pos[2 * n], py = pos[2 * n + 1];
    const float4* hq = (const float4*)(h1 + (size_t)n * 32);
    float4 hv[8];
#pragma unroll
    for (int q = 0; q < 8; ++q) hv[q] = hq[q];
    float acc[32];
#pragma unroll
    for (int c = 0; c < 32; ++c)
        acc[c] = fmaf(px, w2a[1024 + c], fmaf(py, w2a[1056 + c], b2a[c]));
    const float* hf = (const float*)hv;
#pragma unroll
    for (int k = 0; k < 32; ++k) {
        float hk = hf[k];
#pragma unroll
        for (int c = 0; c < 32; ++c) acc[c] = fmaf(hk, w2a[k * 32 + c], acc[c]);
    }
    unsigned* Arow = Abf + (size_t)n * 16;
    unsigned* Brow = Bbf + (size_t)n * 16;
#pragma unroll
    for (int p = 0; p < 16; ++p) {
        Arow[p] = pack_bf16(acc[2 * p], acc[2 * p + 1]);
        Brow[p] = pack_bf16(-(px * w2a[1024 + 2 * p] + py * w2a[1056 + 2 * p]),
                            -(px * w2a[1025 + 2 * p] + py * w2a[1057 + 2 * p]));
    }
}

// Scatter into fixed per-bucket windows; per-block LDS hist -> one global
// atomicAdd per (block,bucket) -> packed records to contiguous chunks.
__global__ __launch_bounds__(1024) void bucket_scatter_kernel(
    const int* __restrict__ ei, int* __restrict__ bcnt,
    int* __restrict__ csr_tmp, int E, int NB)
{
    __shared__ int lh[NBMAX];
    __shared__ int lb[NBMAX];
    int tid = threadIdx.x;
    for (int i = tid; i < NB; i += 1024) lh[i] = 0;
    __syncthreads();
    const int* dsts = ei + E;
    int base0 = blockIdx.x * CHUNKS;
    for (int i = tid * 4; i < CHUNKS; i += 4096) {
        int e = base0 + i;
        if (e + 3 < E) {
            int4 d = *(const int4*)(dsts + e);
            atomicAdd(&lh[d.x >> BSHIFT], 1);
            atomicAdd(&lh[d.y >> BSHIFT], 1);
            atomicAdd(&lh[d.z >> BSHIFT], 1);
            atomicAdd(&lh[d.w >> BSHIFT], 1);
        } else {
            for (int k = e; k < E && k < e + 4; ++k)
                atomicAdd(&lh[dsts[k] >> BSHIFT], 1);
        }
    }
    __syncthreads();
    for (int i = tid; i < NB; i += 1024) {
        int c = lh[i];
        if (c) {
            int o = atomicAdd(bcnt + i, c);
            if (o > CAP - c) o = CAP - c;   // overflow clamp (never in practice)
            lb[i] = i * CAP + o;
        } else lb[i] = 0;
    }
    __syncthreads();
    for (int i = tid; i < NB; i += 1024) lh[i] = 0;
    __syncthreads();
    for (int i = tid * 4; i < CHUNKS; i += 4096) {
        int e = base0 + i;
        if (e + 3 < E) {
            int4 s = *(const int4*)(ei + e);
            int4 d = *(const int4*)(dsts + e);
            int b, o;
            b = d.x >> BSHIFT; o = atomicAdd(&lh[b], 1);
            csr_tmp[lb[b] + o] = s.x | ((d.x & 511) << 20);
            b = d.y >> BSHIFT; o = atomicAdd(&lh[b], 1);
            csr_tmp[lb[b] + o] = s.y | ((d.y & 511) << 20);
            b = d.z >> BSHIFT; o = atomicAdd(&lh[b], 1);
            csr_tmp[lb[b] + o] = s.z | ((d.z & 511) << 20);
            b = d.w >> BSHIFT; o = atomicAdd(&lh[b], 1);
            csr_tmp[lb[b] + o] = s.w | ((d.w & 511) << 20);
        } else {
            for (int k = e; k < E && k < e + 4; ++k) {
                int dd = dsts[k];
                int b = dd >> BSHIFT;
                int o = atomicAdd(&lh[b], 1);
                csr_tmp[lb[b] + o] = ei[k] | ((dd & 511) << 20);
            }
        }
    }
}

// Place: one 1024-thread block per bucket. Pass A streams the bucket window
// from global ONCE into a 64KB LDS cache while counting per-dst (512). One-
// wave scan -> padded offsets; self-reserve output window via global cursor.
// Pass B re-reads from LDS (global fallback past RCAP), places csr_src,
// fills pads + tile_dst.
__global__ __launch_bounds__(1024) void place_kernel(
    const int* __restrict__ csr_tmp, const int* __restrict__ bcnt,
    int* __restrict__ pcur, int* __restrict__ csr_src,
    int* __restrict__ tile_dst, int N)
{
    __shared__ int rec_cache[RCAP];
    __shared__ int cnt[512], pre[512], cur[512];
    __shared__ int pstart_s;
    int b = blockIdx.x, tid = threadIdx.x;
    int d0 = b << BSHIFT;
    int start = b * CAP;
    int len = bcnt[b];
    if (len > CAP) len = CAP;
    if (tid < 512) cnt[tid] = 0;
    __syncthreads();
    for (int i = tid; i < len; i += 1024) {
        int rec = csr_tmp[start + i];
        if (i < RCAP) rec_cache[i] = rec;
        atomicAdd(&cnt[rec >> 20], 1);
    }
    __syncthreads();
    if (tid < 64) {
        int lane = tid;
        int a[8];
        int s = 0;
#pragma unroll
        for (int j = 0; j < 8; ++j) {
            a[j] = (cnt[8 * lane + j] + 15) & ~15;
            s += a[j];
        }
        int x = s;
#pragma unroll
        for (int d = 1; d < 64; d <<= 1) {
            int t = __shfl_up(x, d, 64);
            if (lane >= d) x += t;
        }
        int total = __shfl(x, 63, 64);
        if (lane == 0) pstart_s = total ? atomicAdd(pcur, total) : 0;
        int run = x - s;
#pragma unroll
        for (int j = 0; j < 8; ++j) {
            pre[8 * lane + j] = run;
            cur[8 * lane + j] = run;
            run += a[j];
        }
    }
    __syncthreads();
    int pstart = pstart_s;
    for (int i = tid; i < len; i += 1024) {
        int rec = (i < RCAP) ? rec_cache[i] : csr_tmp[start + i];
        int p = atomicAdd(&cur[rec >> 20], 1);
        csr_src[pstart + p] = rec & 0xFFFFF;
    }
    if (tid < 512) {
        int d = d0 + tid;
        if (d < N) {
            int c = cnt[tid], pc = (c + 15) & ~15;
            int base = pstart + pre[tid];
            for (int k = c; k < pc; ++k) csr_src[base + k] = -1;
            int tb = base >> 4, nt = pc >> 4;
            for (int k = 0; k < nt; ++k) tile_dst[tb + k] = d;
        }
    }
}

// MFMA edge layer over the PADDED slot list, bf16 A/B. Weight fragments
// pre-built in wfbuf. Register-only reduce with full-tile fast path;
// filtered atomicMax at flush (fp32 bias).
__global__ __launch_bounds__(256, 4) void edge_layer_kernel(
    const int* __restrict__ csr_src, const int* __restrict__ tile_dst,
    const unsigned* __restrict__ Abf, const unsigned* __restrict__ Bbf,
    const unsigned* __restrict__ wf, const float* __restrict__ bias,
    unsigned int* __restrict__ hout)
{
    int tid = threadIdx.x;
    int lane = tid & 63;
    int wv = tid >> 6;
    int wbase = blockIdx.x * 256 + wv * 64;
    int m16 = lane & 15;
    int q = lane >> 4;
    int kq = q * 8;
    int ch = (lane < 16) ? m16 : (16 + m16);

    int td[4];
#pragma unroll
    for (int eg = 0; eg < 4; ++eg) td[eg] = tile_dst[(wbase >> 4) + eg];
    if (td[0] < 0 && td[1] < 0 && td[2] < 0 && td[3] < 0) return;

    short8 bf0 = __builtin_bit_cast(short8, *(const uint4v*)(wf + (size_t)lane * 4));
    short8 bf1 = __builtin_bit_cast(short8, *(const uint4v*)(wf + (size_t)(64 + lane) * 4));
    float myb = bias[ch];

    int src[4];
#pragma unroll
    for (int eg = 0; eg < 4; ++eg) {
        int sidx = wbase + eg * 16 + m16;
        src[eg] = (td[eg] >= 0) ? csr_src[sidx] : -1;
    }

    uint4v ua4[4], ub4[4];
#pragma unroll
    for (int eg = 0; eg < 4; ++eg) {
        int brow = (td[eg] >= 0) ? td[eg] : 0;
        int arow = (src[eg] >= 0) ? src[eg] : brow;
        ua4[eg] = *(const uint4v*)(Abf + (size_t)arow * 16 + (kq >> 1));
        ub4[eg] = *(const uint4v*)(Bbf + (size_t)brow * 16 + (kq >> 1));
    }

    f32x4 zero = {0.0f, 0.0f, 0.0f, 0.0f};
    float cv0 = NEG_BIG, cv1 = NEG_BIG;
    int cdst = -1;
#pragma unroll
    for (int eg = 0; eg < 4; ++eg) {
        unsigned long long bal = __ballot(src[eg] >= 0);
        uint4v pk;
#pragma unroll
        for (int d = 0; d < 4; ++d) {
            unsigned uad = ua4[eg][d], ubd = ub4[eg][d];
            float a0 = __uint_as_float(uad << 16);
            float a1 = __uint_as_float(uad & 0xFFFF0000u);
            float b0 = __uint_as_float(ubd << 16);
            float b1 = __uint_as_float(ubd & 0xFFFF0000u);
            float r0 = fmaxf(a0 + b0, 0.0f);
            float r1 = fmaxf(a1 + b1, 0.0f);
            pk[d] = __builtin_amdgcn_perm(__float_as_uint(r1),
                                          __float_as_uint(r0), 0x07060302u);
        }
        short8 af = __builtin_bit_cast(short8, pk);
        f32x4 d0 = __builtin_amdgcn_mfma_f32_16x16x32_bf16(af, bf0, zero, 0, 0, 0);
        f32x4 d1 = __builtin_amdgcn_mfma_f32_16x16x32_bf16(af, bf1, zero, 0, 0, 0);
        float v0, v1;
        if (bal == ~0ull) {
            v0 = fmaxf(fmaxf(d0[0], d0[1]), fmaxf(d0[2], d0[3]));
            v1 = fmaxf(fmaxf(d1[0], d1[1]), fmaxf(d1[2], d1[3]));
        } else {
            v0 = NEG_BIG; v1 = NEG_BIG;
#pragma unroll
            for (int r = 0; r < 4; ++r) {
                bool ok = (bal >> (q * 4 + r)) & 1ull;
                v0 = fmaxf(v0, ok ? d0[r] : NEG_BIG);
                v1 = fmaxf(v1, ok ? d1[r] : NEG_BIG);
            }
        }
        v0 = fmaxf(v0, __shfl_xor(v0, 16, 64));
        v0 = fmaxf(v0, __shfl_xor(v0, 32, 64));
        v1 = fmaxf(v1, __shfl_xor(v1, 16, 64));
        v1 = fmaxf(v1, __shfl_xor(v1, 32, 64));
        int d = td[eg];
        if (d != cdst) {
            if (cdst >= 0 && lane < 32) {
                float x = ((lane < 16) ? cv0 : cv1) + myb;
                if (x > 0.0f)
                    atomicMax(hout + (size_t)cdst * 32 + ch, __float_as_uint(x));
            }
            cdst = d; cv0 = v0; cv1 = v1;
        } else {
            cv0 = fmaxf(cv0, v0); cv1 = fmaxf(cv1, v1);
        }
    }
    if (cdst >= 0 && lane < 32) {
        float x = ((lane < 16) ? cv0 : cv1) + myb;
        if (x > 0.0f)
            atomicMax(hout + (size_t)cdst * 32 + ch, __float_as_uint(x));
    }
}

__global__ __launch_bounds__(256) void pool_kernel(
    const float* __restrict__ h2, const int* __restrict__ batch,
    unsigned int* __restrict__ gbuf, int N)
{
    int g = blockIdx.x, p = blockIdx.y;
    __shared__ int sbound[2];
    __shared__ float red[256];
    if (threadIdx.x < 2) {
        int target = g + (int)threadIdx.x;
        int lo = 0, hi = N;
        while (lo < hi) {
            int mid = (lo + hi) >> 1;
            if (batch[mid] < target) lo = mid + 1; else hi = mid;
        }
        sbound[threadIdx.x] = lo;
    }
    __syncthreads();
    int start = sbound[0], end = sbound[1];
    int c = threadIdx.x & 31, r = threadIdx.x >> 5;
    float mx = 0.0f;
    for (int n = start + p * 8 + r; n < end; n += 128)
        mx = fmaxf(mx, h2[(size_t)n * 32 + c]);
    red[threadIdx.x] = mx;
    __syncthreads();
    if (r < 4) red[threadIdx.x] = fmaxf(red[threadIdx.x], red[threadIdx.x + 128]);
    __syncthreads();
    if (r < 2) red[threadIdx.x] = fmaxf(red[threadIdx.x], red[threadIdx.x + 64]);
    __syncthreads();
    if (r == 0) {
        float v = fmaxf(red[threadIdx.x], red[threadIdx.x + 32]);
        if (v > 0.0f) atomicMax(gbuf + g * 32 + c, __float_as_uint(v));
    }
}

__global__ __launch_bounds__(192) void out_kernel(
    const float* __restrict__ gbuf, const float* __restrict__ wc,
    const float* __restrict__ bc, float* __restrict__ out, int G)
{
    int t = threadIdx.x;
    if (t >= G * 3) return;
    int g = t / 3, j = t % 3;
    float s = bc[j];
#pragma unroll
    for (int c = 0; c < 32; ++c)
        s = fmaf(gbuf[g * 32 + c], wc[c * 3 + j], s);
    out[t] = s;
}

extern "C" void kernel_launch(void* const* d_in, const int* in_sizes, int n_in,
                              void* d_out, int out_size, void* d_ws, size_t ws_size,
                              hipStream_t stream) {
    const float* pos = (const float*)d_in[0];
    const float* w1a = (const float*)d_in[1];
    const float* b1a = (const float*)d_in[2];
    const float* w1b = (const float*)d_in[3];
    const float* b1b = (const float*)d_in[4];
    const float* w2a = (const float*)d_in[5];
    const float* b2a = (const float*)d_in[6];
    const float* w2b = (const float*)d_in[7];
    const float* b2b = (const float*)d_in[8];
    const float* wc  = (const float*)d_in[9];
    const float* bc  = (const float*)d_in[10];
    const int* ei    = (const int*)d_in[11];
    const int* batch = (const int*)d_in[12];

    const int N = in_sizes[12];
    const int E = in_sizes[11] / 2;
    const int G = out_size / 3;
    const size_t NC = (size_t)N * 32;
    const int NB = (N + 511) >> BSHIFT;
    const int SMAX = (E + 15 * ((N < E) ? N : E) + 255) & ~255;
    const int TMAX = SMAX >> 4;

    int* bcnt    = (int*)d_ws;          // 256
    int* pcur    = bcnt + 256;          // 256 (1 used)
    float* gbuf  = (float*)(pcur + 256);            // G*32 (<=2048)
    unsigned* wfbuf = (unsigned*)(gbuf + 2048);     // 1024
    int* csr_src = (int*)(wfbuf + 1024);            // SMAX
    int* tile_dst = csr_src + SMAX;     // TMAX
    unsigned* Abf = (unsigned*)(tile_dst + TMAX);   // N*16
    unsigned* Bbf = Abf + (size_t)N * 16;           // N*16
    float* h1    = (float*)(Bbf + (size_t)N * 16);
    float* h2    = h1 + NC;
    int* csr_tmp = (int*)h1;            // aliases h1+h2 (N*64 ints >= NB*CAP)

    int npBlocks = ((int)(N * 16) + 255) / 256;
    int nBlocks  = (N + 255) / 256;
    int sBlocks  = (E + CHUNKS - 1) / CHUNKS;
    int edBlocks = (SMAX + 255) / 256;

    // meta (bcnt+pcur) + gbuf zeroed in one shot; tile_dst = 0xFF
    hipMemsetAsync(bcnt, 0, (512 + 2048) * sizeof(int), stream);
    hipMemsetAsync(tile_dst, 0xFF, (size_t)TMAX * sizeof(int), stream);

    wprep_kernel<<<1, 256, 0, stream>>>(w1b, w2b, wfbuf);
    bucket_scatter_kernel<<<sBlocks, 1024, 0, stream>>>(ei, bcnt, csr_tmp, E, NB);
    place_kernel<<<NB, 1024, 0, stream>>>(csr_tmp, bcnt, pcur,
                                          csr_src, tile_dst, N);
    // h1+h2 zeroed AFTER place (csr_tmp aliases them)
    hipMemsetAsync(h1, 0, 2 * NC * sizeof(float), stream);

    pre1_kernel<<<npBlocks, 256, 0, stream>>>(pos, w1a, b1a, Abf, Bbf, N);
    edge_layer_kernel<<<edBlocks, 256, 0, stream>>>(csr_src, tile_dst, Abf, Bbf,
                                                    wfbuf, b1b, (unsigned int*)h1);
    pre2_kernel<<<nBlocks, 256, 0, stream>>>(pos, h1, w2a, b2a, Abf, Bbf, N);
    edge_layer_kernel<<<edBlocks, 256, 0, stream>>>(csr_src, tile_dst, Abf, Bbf,
                                                    wfbuf + 512, b2b,
                                                    (unsigned int*)h2);
    pool_kernel<<<dim3(G, 16), 256, 0, stream>>>(h2, batch,
                                                 (unsigned int*)gbuf, N);
    out_kernel<<<1, 192, 0, stream>>>(gbuf, wc, bc, (float*)d_out, G);
}

// Round 19
// 280.114 us; speedup vs baseline: 1.6289x; 1.0164x over previous
//
#include <hip/hip_runtime.h>
#include <hip/hip_bf16.h>

// Workspace layout (4B units):
// [bcnt:256][pcur:256][gbuf:G*32][wfbuf:1024][csr_src:SMAX][tile_dst:SMAX/16]
// [Abf:N*16][Bbf:N*16][h1:N*32][h2:N*32]
// A/B stored as packed bf16 (2 channels per uint). csr_tmp ALIASES h1+h2
// (h zeroed by pre1 AFTER place). Record = src(20b)|doff9<<20.
// Fixed bucket windows: bucket b owns csr_tmp[b*CAP, b*CAP+CAP); bcnt[b] is
// its append count. csr_src pads = -1; unused tiles dst = -1. h1/h2/gbuf hold
// non-negative float bit patterns (atomicMax uint).

#define NEG_BIG (-3.0e38f)
#define BSHIFT 9                 // bucket: 512 dsts
#define NBMAX 256
#define CHUNKS 16384             // edges per scatter block (16/thread)
#define CAP 32512                // records per bucket window
#define RCAP 16384               // LDS record cache per place block (64 KB)

typedef __attribute__((ext_vector_type(8))) short short8;
typedef __attribute__((ext_vector_type(4))) float f32x4;
typedef __attribute__((ext_vector_type(4))) unsigned uint4v;

__device__ __forceinline__ short bf16r(float f) {
    unsigned u = __float_as_uint(f);
    unsigned r = (u + 0x7FFFu + ((u >> 16) & 1u)) >> 16;
    return (short)r;
}
__device__ __forceinline__ unsigned pack_bf16(float lo, float hi) {
    return ((unsigned)(unsigned short)bf16r(lo)) |
           (((unsigned)(unsigned short)bf16r(hi)) << 16);
}

// pre1: per (node, channel-pair) A/B build + h1/h2 zeroing.
// Last block instead builds the per-lane W fragments for both layers.
__global__ __launch_bounds__(256) void pre1_kernel(
    const float* __restrict__ pos, const float* __restrict__ w1a,
    const float* __restrict__ b1a, const float* __restrict__ w1b,
    const float* __restrict__ w2b, unsigned* __restrict__ Abf,
    unsigned* __restrict__ Bbf, unsigned* __restrict__ wfbuf,
    float* __restrict__ h1, float* __restrict__ h2, int N)
{
    if (blockIdx.x == gridDim.x - 1) {
        int t = threadIdx.x;
        int l = t >> 7, frag = (t >> 6) & 1, lane = t & 63;
        const float* w = l ? w2b : w1b;
        int m16 = lane & 15, kq = (lane >> 4) * 8;
        int cb = frag * 16 + m16;
        unsigned out[4];
#pragma unroll
        for (int p = 0; p < 4; ++p)
            out[p] = pack_bf16(w[(kq + 2 * p) * 32 + cb],
                               w[(kq + 2 * p + 1) * 32 + cb]);
        *(uint4v*)(wfbuf + (size_t)t * 4) = (uint4v){out[0], out[1], out[2], out[3]};
        return;
    }
    int t = blockIdx.x * 256 + threadIdx.x;
    if (t >= N * 16) return;
    int n = t >> 4, c0 = (t & 15) * 2;
    float px = pos[2 * n], py = pos[2 * n + 1];
    float a[2], b[2];
#pragma unroll
    for (int i = 0; i < 2; ++i) {
        int c = c0 + i;
        float w0 = w1a[c], w1 = w1a[32 + c], w2 = w1a[64 + c], w3 = w1a[96 + c];
        a[i] = fmaf(px, w0 + w2, fmaf(py, w1 + w3, b1a[c]));
        b[i] = -(px * w2 + py * w3);
    }
    Abf[t] = pack_bf16(a[0], a[1]);
    Bbf[t] = pack_bf16(b[0], b[1]);
    *(float2*)(h1 + 2 * (size_t)t) = make_float2(0.0f, 0.0f);
    *(float2*)(h2 + 2 * (size_t)t) = make_float2(0.0f, 0.0f);
}

// One thread per node: hrow read once, 32 channels in registers.
__global__ __launch_bounds__(256) void pre2_kernel(
    const float* __restrict__ pos, const float* __restrict__ h1,
    const float* __restrict__ w2a, const float* __restrict__ b2a,
    unsigned* __restrict__ Abf, unsigned* __restrict__ Bbf, int N)
{
    int n = blockIdx.x * 256 + threadIdx.x;
    if (n >= N) return;
    float px = pos[2 * n], py = pos[2 * n + 1];
    const float4* hq = (const float4*)(h1 + (size_t)n * 32);
    float4 hv[8];
#pragma unroll
    for (int q = 0; q < 8; ++q) hv[q] = hq[q];
    float acc[32];
#pragma unroll
    for (int c = 0; c < 32; ++c)
        acc[c] = fmaf(px, w2a[1024 + c], fmaf(py, w2a[1056 + c], b2a[c]));
    const float* hf = (const float*)hv;
#pragma unroll
    for (int k = 0; k < 32; ++k) {
        float hk = hf[k];
#pragma unroll
        for (int c = 0; c < 32; ++c) acc[c] = fmaf(hk, w2a[k * 32 + c], acc[c]);
    }
    unsigned* Arow = Abf + (size_t)n * 16;
    unsigned* Brow = Bbf + (size_t)n * 16;
#pragma unroll
    for (int p = 0; p < 16; ++p) {
        Arow[p] = pack_bf16(acc[2 * p], acc[2 * p + 1]);
        Brow[p] = pack_bf16(-(px * w2a[1024 + 2 * p] + py * w2a[1056 + 2 * p]),
                            -(px * w2a[1025 + 2 * p] + py * w2a[1057 + 2 * p]));
    }
}

// Scatter into fixed per-bucket windows. Edge quads loaded ONCE into regs
// (16 edges/thread), reused across hist -> reserve -> write. Tail uses -1.
__global__ __launch_bounds__(1024) void bucket_scatter_kernel(
    const int* __restrict__ ei, int* __restrict__ bcnt,
    int* __restrict__ csr_tmp, int E, int NB)
{
    __shared__ int lh[NBMAX];
    __shared__ int lb[NBMAX];
    int tid = threadIdx.x;
    for (int i = tid; i < NB; i += 1024) lh[i] = 0;
    __syncthreads();
    const int* dsts = ei + E;
    int base0 = blockIdx.x * CHUNKS;
    int4 sv[4], dv[4];
#pragma unroll
    for (int j = 0; j < 4; ++j) {
        int e = base0 + tid * 4 + j * 4096;
        if (e + 3 < E) {
            sv[j] = *(const int4*)(ei + e);
            dv[j] = *(const int4*)(dsts + e);
        } else {
            int s0 = 0, s1 = 0, s2 = 0, s3 = 0;
            int d0 = -1, d1 = -1, d2 = -1, d3 = -1;
            if (e < E)     { s0 = ei[e];     d0 = dsts[e]; }
            if (e + 1 < E) { s1 = ei[e + 1]; d1 = dsts[e + 1]; }
            if (e + 2 < E) { s2 = ei[e + 2]; d2 = dsts[e + 2]; }
            sv[j] = make_int4(s0, s1, s2, s3);
            dv[j] = make_int4(d0, d1, d2, d3);
        }
        if (dv[j].x >= 0) atomicAdd(&lh[dv[j].x >> BSHIFT], 1);
        if (dv[j].y >= 0) atomicAdd(&lh[dv[j].y >> BSHIFT], 1);
        if (dv[j].z >= 0) atomicAdd(&lh[dv[j].z >> BSHIFT], 1);
        if (dv[j].w >= 0) atomicAdd(&lh[dv[j].w >> BSHIFT], 1);
    }
    __syncthreads();
    for (int i = tid; i < NB; i += 1024) {
        int c = lh[i];
        if (c) {
            int o = atomicAdd(bcnt + i, c);
            if (o > CAP - c) o = CAP - c;   // overflow clamp (never in practice)
            lb[i] = i * CAP + o;
        }
    }
    __syncthreads();
    for (int i = tid; i < NB; i += 1024) lh[i] = 0;
    __syncthreads();
#pragma unroll
    for (int j = 0; j < 4; ++j) {
        int s, d, b, o;
        s = sv[j].x; d = dv[j].x;
        if (d >= 0) { b = d >> BSHIFT; o = atomicAdd(&lh[b], 1);
                      csr_tmp[lb[b] + o] = s | ((d & 511) << 20); }
        s = sv[j].y; d = dv[j].y;
        if (d >= 0) { b = d >> BSHIFT; o = atomicAdd(&lh[b], 1);
                      csr_tmp[lb[b] + o] = s | ((d & 511) << 20); }
        s = sv[j].z; d = dv[j].z;
        if (d >= 0) { b = d >> BSHIFT; o = atomicAdd(&lh[b], 1);
                      csr_tmp[lb[b] + o] = s | ((d & 511) << 20); }
        s = sv[j].w; d = dv[j].w;
        if (d >= 0) { b = d >> BSHIFT; o = atomicAdd(&lh[b], 1);
                      csr_tmp[lb[b] + o] = s | ((d & 511) << 20); }
    }
}

// Place: one 1024-thread block per bucket. Pass A streams the bucket window
// from global ONCE into a 64KB LDS cache while counting per-dst (512). One-
// wave scan -> padded offsets; self-reserve output window via global cursor.
// Pass B re-reads from LDS (global fallback past RCAP), places csr_src,
// fills pads + tile_dst.
__global__ __launch_bounds__(1024) void place_kernel(
    const int* __restrict__ csr_tmp, const int* __restrict__ bcnt,
    int* __restrict__ pcur, int* __restrict__ csr_src,
    int* __restrict__ tile_dst, int N)
{
    __shared__ int rec_cache[RCAP];
    __shared__ int cnt[512], pre[512], cur[512];
    __shared__ int pstart_s;
    int b = blockIdx.x, tid = threadIdx.x;
    int d0 = b << BSHIFT;
    int start = b * CAP;
    int len = bcnt[b];
    if (len > CAP) len = CAP;
    if (tid < 512) cnt[tid] = 0;
    __syncthreads();
    for (int i = tid; i < len; i += 1024) {
        int rec = csr_tmp[start + i];
        if (i < RCAP) rec_cache[i] = rec;
        atomicAdd(&cnt[rec >> 20], 1);
    }
    __syncthreads();
    if (tid < 64) {
        int lane = tid;
        int a[8];
        int s = 0;
#pragma unroll
        for (int j = 0; j < 8; ++j) {
            a[j] = (cnt[8 * lane + j] + 15) & ~15;
            s += a[j];
        }
        int x = s;
#pragma unroll
        for (int d = 1; d < 64; d <<= 1) {
            int t = __shfl_up(x, d, 64);
            if (lane >= d) x += t;
        }
        int total = __shfl(x, 63, 64);
        if (lane == 0) pstart_s = total ? atomicAdd(pcur, total) : 0;
        int run = x - s;
#pragma unroll
        for (int j = 0; j < 8; ++j) {
            pre[8 * lane + j] = run;
            cur[8 * lane + j] = run;
            run += a[j];
        }
    }
    __syncthreads();
    int pstart = pstart_s;
    for (int i = tid; i < len; i += 1024) {
        int rec = (i < RCAP) ? rec_cache[i] : csr_tmp[start + i];
        int p = atomicAdd(&cur[rec >> 20], 1);
        csr_src[pstart + p] = rec & 0xFFFFF;
    }
    if (tid < 512) {
        int d = d0 + tid;
        if (d < N) {
            int c = cnt[tid], pc = (c + 15) & ~15;
            int base = pstart + pre[tid];
            for (int k = c; k < pc; ++k) csr_src[base + k] = -1;
            int tb = base >> 4, nt = pc >> 4;
            for (int k = 0; k < nt; ++k) tile_dst[tb + k] = d;
        }
    }
}

// MFMA edge layer over the PADDED slot list, bf16 A/B. Weight fragments
// pre-built in wfbuf. Register-only reduce with full-tile fast path;
// filtered atomicMax at flush (fp32 bias).
__global__ __launch_bounds__(256, 4) void edge_layer_kernel(
    const int* __restrict__ csr_src, const int* __restrict__ tile_dst,
    const unsigned* __restrict__ Abf, const unsigned* __restrict__ Bbf,
    const unsigned* __restrict__ wf, const float* __restrict__ bias,
    unsigned int* __restrict__ hout)
{
    int tid = threadIdx.x;
    int lane = tid & 63;
    int wv = tid >> 6;
    int wbase = blockIdx.x * 256 + wv * 64;
    int m16 = lane & 15;
    int q = lane >> 4;
    int kq = q * 8;
    int ch = (lane < 16) ? m16 : (16 + m16);

    int td[4];
#pragma unroll
    for (int eg = 0; eg < 4; ++eg) td[eg] = tile_dst[(wbase >> 4) + eg];
    if (td[0] < 0 && td[1] < 0 && td[2] < 0 && td[3] < 0) return;

    short8 bf0 = __builtin_bit_cast(short8, *(const uint4v*)(wf + (size_t)lane * 4));
    short8 bf1 = __builtin_bit_cast(short8, *(const uint4v*)(wf + (size_t)(64 + lane) * 4));
    float myb = bias[ch];
    unsigned int* hch = hout + ch;

    int src[4];
#pragma unroll
    for (int eg = 0; eg < 4; ++eg) {
        int sidx = wbase + eg * 16 + m16;
        src[eg] = (td[eg] >= 0) ? csr_src[sidx] : -1;
    }

    uint4v ua4[4], ub4[4];
#pragma unroll
    for (int eg = 0; eg < 4; ++eg) {
        int brow = (td[eg] >= 0) ? td[eg] : 0;
        int arow = (src[eg] >= 0) ? src[eg] : brow;
        ua4[eg] = *(const uint4v*)(Abf + (size_t)arow * 16 + (kq >> 1));
        ub4[eg] = *(const uint4v*)(Bbf + (size_t)brow * 16 + (kq >> 1));
    }

    f32x4 zero = {0.0f, 0.0f, 0.0f, 0.0f};
    float cv0 = NEG_BIG, cv1 = NEG_BIG;
    int cdst = -1;
#pragma unroll
    for (int eg = 0; eg < 4; ++eg) {
        unsigned long long bal = __ballot(src[eg] >= 0);
        uint4v pk;
#pragma unroll
        for (int d = 0; d < 4; ++d) {
            unsigned uad = ua4[eg][d], ubd = ub4[eg][d];
            float a0 = __uint_as_float(uad << 16);
            float a1 = __uint_as_float(uad & 0xFFFF0000u);
            float b0 = __uint_as_float(ubd << 16);
            float b1 = __uint_as_float(ubd & 0xFFFF0000u);
            float r0 = fmaxf(a0 + b0, 0.0f);
            float r1 = fmaxf(a1 + b1, 0.0f);
            pk[d] = __builtin_amdgcn_perm(__float_as_uint(r1),
                                          __float_as_uint(r0), 0x07060302u);
        }
        short8 af = __builtin_bit_cast(short8, pk);
        f32x4 d0 = __builtin_amdgcn_mfma_f32_16x16x32_bf16(af, bf0, zero, 0, 0, 0);
        f32x4 d1 = __builtin_amdgcn_mfma_f32_16x16x32_bf16(af, bf1, zero, 0, 0, 0);
        float v0, v1;
        if (bal == ~0ull) {
            v0 = fmaxf(fmaxf(d0[0], d0[1]), fmaxf(d0[2], d0[3]));
            v1 = fmaxf(fmaxf(d1[0], d1[1]), fmaxf(d1[2], d1[3]));
        } else {
            v0 = NEG_BIG; v1 = NEG_BIG;
#pragma unroll
            for (int r = 0; r < 4; ++r) {
                bool ok = (bal >> (q * 4 + r)) & 1ull;
                v0 = fmaxf(v0, ok ? d0[r] : NEG_BIG);
                v1 = fmaxf(v1, ok ? d1[r] : NEG_BIG);
            }
        }
        v0 = fmaxf(v0, __shfl_xor(v0, 16, 64));
        v0 = fmaxf(v0, __shfl_xor(v0, 32, 64));
        v1 = fmaxf(v1, __shfl_xor(v1, 16, 64));
        v1 = fmaxf(v1, __shfl_xor(v1, 32, 64));
        int d = td[eg];
        if (d != cdst) {
            if (cdst >= 0 && lane < 32) {
                float x = ((lane < 16) ? cv0 : cv1) + myb;
                if (x > 0.0f)
                    atomicMax(hch + (size_t)cdst * 32, __float_as_uint(x));
            }
            cdst = d; cv0 = v0; cv1 = v1;
        } else {
            cv0 = fmaxf(cv0, v0); cv1 = fmaxf(cv1, v1);
        }
    }
    if (cdst >= 0 && lane < 32) {
        float x = ((lane < 16) ? cv0 : cv1) + myb;
        if (x > 0.0f)
            atomicMax(hch + (size_t)cdst * 32, __float_as_uint(x));
    }
}

__global__ __launch_bounds__(256) void pool_kernel(
    const float* __restrict__ h2, const int* __restrict__ batch,
    unsigned int* __restrict__ gbuf, int N)
{
    int g = blockIdx.x, p = blockIdx.y;
    __shared__ int sbound[2];
    __shared__ float red[256];
    if (threadIdx.x < 2) {
        int target = g + (int)threadIdx.x;
        int lo = 0, hi = N;
        while (lo < hi) {
            int mid = (lo + hi) >> 1;
            if (batch[mid] < target) lo = mid + 1; else hi = mid;
        }
        sbound[threadIdx.x] = lo;
    }
    __syncthreads();
    int start = sbound[0], end = sbound[1];
    int c = threadIdx.x & 31, r = threadIdx.x >> 5;
    float mx = 0.0f;
    for (int n = start + p * 8 + r; n < end; n += 128)
        mx = fmaxf(mx, h2[(size_t)n * 32 + c]);
    red[threadIdx.x] = mx;
    __syncthreads();
    if (r < 4) red[threadIdx.x] = fmaxf(red[threadIdx.x], red[threadIdx.x + 128]);
    __syncthreads();
    if (r < 2) red[threadIdx.x] = fmaxf(red[threadIdx.x], red[threadIdx.x + 64]);
    __syncthreads();
    if (r == 0) {
        float v = fmaxf(red[threadIdx.x], red[threadIdx.x + 32]);
        if (v > 0.0f) atomicMax(gbuf + g * 32 + c, __float_as_uint(v));
    }
}

__global__ __launch_bounds__(192) void out_kernel(
    const float* __restrict__ gbuf, const float* __restrict__ wc,
    const float* __restrict__ bc, float* __restrict__ out, int G)
{
    int t = threadIdx.x;
    if (t >= G * 3) return;
    int g = t / 3, j = t % 3;
    float s = bc[j];
#pragma unroll
    for (int c = 0; c < 32; ++c)
        s = fmaf(gbuf[g * 32 + c], wc[c * 3 + j], s);
    out[t] = s;
}

extern "C" void kernel_launch(void* const* d_in, const int* in_sizes, int n_in,
                              void* d_out, int out_size, void* d_ws, size_t ws_size,
                              hipStream_t stream) {
    const float* pos = (const float*)d_in[0];
    const float* w1a = (const float*)d_in[1];
    const float* b1a = (const float*)d_in[2];
    const float* w1b = (const float*)d_in[3];
    const float* b1b = (const float*)d_in[4];
    const float* w2a = (const float*)d_in[5];
    const float* b2a = (const float*)d_in[6];
    const float* w2b = (const float*)d_in[7];
    const float* b2b = (const float*)d_in[8];
    const float* wc  = (const float*)d_in[9];
    const float* bc  = (const float*)d_in[10];
    const int* ei    = (const int*)d_in[11];
    const int* batch = (const int*)d_in[12];

    const int N = in_sizes[12];
    const int E = in_sizes[11] / 2;
    const int G = out_size / 3;
    const size_t NC = (size_t)N * 32;
    const int NB = (N + 511) >> BSHIFT;
    const int SMAX = (E + 15 * ((N < E) ? N : E) + 255) & ~255;
    const int TMAX = SMAX >> 4;

    int* bcnt    = (int*)d_ws;          // 256
    int* pcur    = bcnt + 256;          // 256 (1 used)
    float* gbuf  = (float*)(pcur + 256);            // G*32 (<=2048)
    unsigned* wfbuf = (unsigned*)(gbuf + 2048);     // 1024
    int* csr_src = (int*)(wfbuf + 1024);            // SMAX
    int* tile_dst = csr_src + SMAX;     // TMAX
    unsigned* Abf = (unsigned*)(tile_dst + TMAX);   // N*16
    unsigned* Bbf = Abf + (size_t)N * 16;           // N*16
    float* h1    = (float*)(Bbf + (size_t)N * 16);
    float* h2    = h1 + NC;
    int* csr_tmp = (int*)h1;            // aliases h1+h2 (N*64 ints >= NB*CAP)

    int npBlocks = ((int)(N * 16) + 255) / 256 + 1;   // +1: wprep block
    int nBlocks  = (N + 255) / 256;
    int sBlocks  = (E + CHUNKS - 1) / CHUNKS;
    int edBlocks = (SMAX + 255) / 256;

    // meta (bcnt+pcur) + gbuf zeroed in one shot; tile_dst = 0xFF
    hipMemsetAsync(bcnt, 0, (512 + 2048) * sizeof(int), stream);
    hipMemsetAsync(tile_dst, 0xFF, (size_t)TMAX * sizeof(int), stream);

    bucket_scatter_kernel<<<sBlocks, 1024, 0, stream>>>(ei, bcnt, csr_tmp, E, NB);
    place_kernel<<<NB, 1024, 0, stream>>>(csr_tmp, bcnt, pcur,
                                          csr_src, tile_dst, N);
    // pre1 zeroes h1/h2 itself (after place: csr_tmp aliases them) and
    // builds wfbuf in its trailing block.
    pre1_kernel<<<npBlocks, 256, 0, stream>>>(pos, w1a, b1a, w1b, w2b,
                                              Abf, Bbf, wfbuf, h1, h2, N);
    edge_layer_kernel<<<edBlocks, 256, 0, stream>>>(csr_src, tile_dst, Abf, Bbf,
                                                    wfbuf, b1b, (unsigned int*)h1);
    pre2_kernel<<<nBlocks, 256, 0, stream>>>(pos, h1, w2a, b2a, Abf, Bbf, N);
    edge_layer_kernel<<<edBlocks, 256, 0, stream>>>(csr_src, tile_dst, Abf, Bbf,
                                                    wfbuf + 512, b2b,
                                                    (unsigned int*)h2);
    pool_kernel<<<dim3(G, 16), 256, 0, stream>>>(h2, batch,
                                                 (unsigned int*)gbuf, N);
    out_kernel<<<1, 192, 0, stream>>>(gbuf, wc, bc, (float*)d_out, G);
}